// Round 16
// baseline (573.821 us; speedup 1.0000x reference)
//
#include <hip/hip_runtime.h>
#include <hip/hip_bf16.h>
#include <math.h>

#define S_LEN 2048
#define HID   1024
#define NHEAD 16
#define KVH   4
#define HD    64
#define FF    1024
#define NE    8
#define NL    2

// ---- workspace layout (float offsets) ----
#define OFF_H    0
#define OFF_Q    (OFF_H + S_LEN*HID)
#define OFF_K    (OFF_Q + S_LEN*HID)
#define OFF_V    (OFF_K + S_LEN*KVH*HD)
#define OFF_COS  (OFF_V + S_LEN*KVH*HD)
#define OFF_SIN  (OFF_COS + S_LEN*32)
#define OFF_WT   (OFF_SIN + S_LEN*32)
#define OFF_INT  (OFF_WT + NE*S_LEN)
#define OFF_TOPE (OFF_INT + NE*S_LEN + 16)
#define OFF_TOPW (OFF_TOPE + S_LEN)
#define OFF_XH   (OFF_TOPW + 2*S_LEN)
#define OFF_AOH  (OFF_XH + S_LEN*HID/2)
#define OFF_ABH  (OFF_AOH + S_LEN*HID/2)
#define OFF_Q16  (OFF_ABH + NE*S_LEN*FF/2)
#define OFF_K16  (OFF_Q16 + S_LEN*HID/2)
#define OFF_VT16 (OFF_K16 + S_LEN*KVH*HD/2)
#define OFF_PO   (OFF_VT16 + S_LEN*KVH*HD/2)
#define OFF_PM   (OFF_PO + 80*NHEAD*64*64)
#define OFF_PL   (OFF_PM + 80*NHEAD*64)
#define OFF_WCVT (OFF_PL + 80*NHEAD*64)

typedef __attribute__((ext_vector_type(8))) _Float16 f16x8;
typedef __attribute__((ext_vector_type(8))) short  s16x8;
typedef __attribute__((ext_vector_type(4))) float  f32x4;

__device__ __forceinline__ short f2h(float f) {
    union { _Float16 h; short s; } u;
    u.h = (_Float16)f;
    return u.s;
}

__device__ __forceinline__ s16x8 cvt8(float4 a, float4 b) {
    s16x8 w;
    w[0]=f2h(a.x); w[1]=f2h(a.y); w[2]=f2h(a.z); w[3]=f2h(a.w);
    w[4]=f2h(b.x); w[5]=f2h(b.y); w[6]=f2h(b.z); w[7]=f2h(b.w);
    return w;
}

// ---------------- fp32 -> fp16 convert ----------------
__global__ __launch_bounds__(256) void cvt16_kernel(const float* __restrict__ src,
                                                    short* __restrict__ dst, int n8) {
    int gid = blockIdx.x * 256 + threadIdx.x;
    if (gid >= n8) return;
    const float4* s = (const float4*)src + (size_t)gid * 2;
    *(s16x8*)(dst + (size_t)gid * 8) = cvt8(s[0], s[1]);
}

// ---------------- RoPE tables ----------------
__global__ void rope_tables_kernel(float* __restrict__ cosb, float* __restrict__ sinb) {
    int gid = blockIdx.x * 256 + threadIdx.x;
    int t = gid >> 5, i = gid & 31;
    float invf = powf(1.0e6f, -(float)i / 32.0f);
    float ang = (float)t * invf;
    cosb[gid] = cosf(ang);
    sinb[gid] = sinf(ang);
}

// ---------------- RMSNorm -> fp16 only ----------------
__global__ __launch_bounds__(256) void rmsnorm_h16_kernel(const float* __restrict__ x,
                                                          const float* __restrict__ w,
                                                          short* __restrict__ oh) {
    int row = blockIdx.x;
    const float4* xr = (const float4*)(x + (size_t)row * HID);
    float4 xv = xr[threadIdx.x];
    float ss = xv.x*xv.x + xv.y*xv.y + xv.z*xv.z + xv.w*xv.w;
    for (int off = 32; off; off >>= 1) ss += __shfl_xor(ss, off);
    __shared__ float sred[4];
    if ((threadIdx.x & 63) == 0) sred[threadIdx.x >> 6] = ss;
    __syncthreads();
    float tot = sred[0] + sred[1] + sred[2] + sred[3];
    float scale = rsqrtf(tot * (1.0f / (float)HID) + 1e-5f);
    float4 wv = ((const float4*)w)[threadIdx.x];
    float4 o;
    o.x = xv.x * scale * wv.x; o.y = xv.y * scale * wv.y;
    o.z = xv.z * scale * wv.z; o.w = xv.w * scale * wv.w;
    union { short s[4]; float2 f2; } hh;
    hh.s[0]=f2h(o.x); hh.s[1]=f2h(o.y); hh.s[2]=f2h(o.z); hh.s[3]=f2h(o.w);
    ((float2*)(oh + (size_t)row * HID))[threadIdx.x] = hh.f2;
}

// ---------------- RMSNorm + gate top-2 (NO atomics) ----------------
__global__ __launch_bounds__(256) void rmsnorm_gate_kernel(const float* __restrict__ x,
                                                           const float* __restrict__ w,
                                                           const float* __restrict__ gw,
                                                           short* __restrict__ oh,
                                                           int* __restrict__ tope,
                                                           float2* __restrict__ topw) {
    int row = blockIdx.x;
    const float4* xr = (const float4*)(x + (size_t)row * HID);
    float4 xv = xr[threadIdx.x];
    float ss = xv.x*xv.x + xv.y*xv.y + xv.z*xv.z + xv.w*xv.w;
    for (int off = 32; off; off >>= 1) ss += __shfl_xor(ss, off);
    __shared__ float sred[4];
    __shared__ float gred[4][NE];
    if ((threadIdx.x & 63) == 0) sred[threadIdx.x >> 6] = ss;
    __syncthreads();
    float tot = sred[0] + sred[1] + sred[2] + sred[3];
    float scale = rsqrtf(tot * (1.0f / (float)HID) + 1e-5f);
    float4 wv = ((const float4*)w)[threadIdx.x];
    float4 o;
    o.x = xv.x * scale * wv.x; o.y = xv.y * scale * wv.y;
    o.z = xv.z * scale * wv.z; o.w = xv.w * scale * wv.w;
    union { short s[4]; float2 f2; } hh;
    hh.s[0]=f2h(o.x); hh.s[1]=f2h(o.y); hh.s[2]=f2h(o.z); hh.s[3]=f2h(o.w);
    ((float2*)(oh + (size_t)row * HID))[threadIdx.x] = hh.f2;
    const float4* gr = (const float4*)gw;
    float acc[NE];
    #pragma unroll
    for (int e = 0; e < NE; ++e) {
        float4 g4 = gr[e * 256 + threadIdx.x];
        acc[e] = o.x*g4.x + o.y*g4.y + o.z*g4.z + o.w*g4.w;
    }
    #pragma unroll
    for (int e = 0; e < NE; ++e)
        for (int off = 32; off; off >>= 1) acc[e] += __shfl_xor(acc[e], off);
    if ((threadIdx.x & 63) == 0) {
        #pragma unroll
        for (int e = 0; e < NE; ++e) gred[threadIdx.x >> 6][e] = acc[e];
    }
    __syncthreads();
    if (threadIdx.x == 0) {
        float lg[NE];
        #pragma unroll
        for (int e = 0; e < NE; ++e)
            lg[e] = gred[0][e] + gred[1][e] + gred[2][e] + gred[3][e];
        float mx = lg[0];
        #pragma unroll
        for (int e = 1; e < NE; ++e) mx = fmaxf(mx, lg[e]);
        float p[NE];
        #pragma unroll
        for (int e = 0; e < NE; ++e) p[e] = __expf(lg[e] - mx);
        int i0 = 0;
        #pragma unroll
        for (int e = 1; e < NE; ++e) if (p[e] > p[i0]) i0 = e;
        int i1 = -1;
        #pragma unroll
        for (int e = 0; e < NE; ++e) if (e != i0 && (i1 < 0 || p[e] > p[i1])) i1 = e;
        float w0 = p[i0], w1 = p[i1];
        float inv = 1.0f / (w0 + w1);
        tope[row] = i0 | (i1 << 8);
        topw[row] = make_float2(w0 * inv, w1 * inv);
    }
}

// ---------------- build per-expert token lists (ballot prefix-scan, no atomics) ----------
__global__ __launch_bounds__(1024) void route_build_kernel(const int* __restrict__ tope,
                                                           const float2* __restrict__ topw,
                                                           int* __restrict__ cnt,
                                                           int* __restrict__ idx,
                                                           float* __restrict__ wt) {
    const int e = blockIdx.x;
    const int lane = threadIdx.x & 63, wv = threadIdx.x >> 6;
    __shared__ int wtot[16];
    __shared__ int sbase;
    if (threadIdx.x == 0) sbase = 0;
    __syncthreads();
    for (int t0 = 0; t0 < S_LEN; t0 += 1024) {
        int t = t0 + threadIdx.x;
        int pk = tope[t];
        int e0 = pk & 0xff, e1 = (pk >> 8) & 0xff;
        bool sel = (e0 == e) || (e1 == e);
        unsigned long long mask = __ballot(sel);
        int prefix = __popcll(mask & ((1ULL << lane) - 1ULL));
        if (lane == 0) wtot[wv] = __popcll(mask);
        __syncthreads();
        if (sel) {
            int off = sbase;
            for (int i = 0; i < wv; ++i) off += wtot[i];
            float2 wpair = topw[t];
            float wsel = (e0 == e) ? wpair.x : wpair.y;
            int slot = off + prefix;
            idx[e * S_LEN + slot] = t;
            wt[e * S_LEN + slot] = wsel;
        }
        __syncthreads();
        if (threadIdx.x == 0) {
            int s = 0;
            #pragma unroll
            for (int i = 0; i < 16; ++i) s += wtot[i];
            sbase += s;
        }
    }
    __syncthreads();
    if (threadIdx.x == 0) cnt[e] = sbase;
}

// plain rmsnorm for final output (fp32)
__global__ __launch_bounds__(256) void rmsnorm_kernel(const float* __restrict__ x,
                                                      const float* __restrict__ w,
                                                      float* __restrict__ out) {
    int row = blockIdx.x;
    const float4* xr = (const float4*)(x + (size_t)row * HID);
    float4 xv = xr[threadIdx.x];
    float ss = xv.x*xv.x + xv.y*xv.y + xv.z*xv.z + xv.w*xv.w;
    for (int off = 32; off; off >>= 1) ss += __shfl_xor(ss, off);
    __shared__ float sred[4];
    if ((threadIdx.x & 63) == 0) sred[threadIdx.x >> 6] = ss;
    __syncthreads();
    float tot = sred[0] + sred[1] + sred[2] + sred[3];
    float scale = rsqrtf(tot * (1.0f / (float)HID) + 1e-5f);
    float4 wv = ((const float4*)w)[threadIdx.x];
    float4 o;
    o.x = xv.x * scale * wv.x; o.y = xv.y * scale * wv.y;
    o.z = xv.z * scale * wv.z; o.w = xv.w * scale * wv.w;
    ((float4*)(out + (size_t)row * HID))[threadIdx.x] = o;
}

// ---------------- RoPE apply + fp16 convert (q scaled by 1/8, k unscaled) ------------
__global__ void rope_cvt_kernel(const float* __restrict__ p, const float* __restrict__ cosb,
                                const float* __restrict__ sinb, short* __restrict__ o16,
                                int nh, int total, float qscale) {
    int gid = blockIdx.x * 256 + threadIdx.x;
    if (gid >= total) return;
    int per = nh * 32;
    int t = gid / per, r = gid % per;
    int hh = r >> 5, i = r & 31;
    float c = cosb[t*32 + i], s = sinb[t*32 + i];
    const float* base = p + (size_t)t * (nh * HD) + hh * HD + i;
    float a = base[0], b = base[32];
    short* ob = o16 + (size_t)t * (nh * HD) + hh * HD + i;
    ob[0]  = f2h((a * c - b * s) * qscale);
    ob[32] = f2h((b * c + a * s) * qscale);
}

// ---------------- V transpose + fp16 ----------------
__global__ __launch_bounds__(256) void vtrans_kernel(const float* __restrict__ vb,
                                                     short* __restrict__ vt16) {
    __shared__ float tile[64][65];
    const int t0 = blockIdx.x * 64, d0 = blockIdx.y * 64;
    const int tr = threadIdx.x >> 2;
    const int dc = (threadIdx.x & 3) * 16;
    const float4* src = (const float4*)(vb + (size_t)(t0 + tr) * (KVH*HD) + d0 + dc);
    float4 v0 = src[0], v1 = src[1], v2 = src[2], v3 = src[3];
    tile[tr][dc+ 0]=v0.x; tile[tr][dc+ 1]=v0.y; tile[tr][dc+ 2]=v0.z; tile[tr][dc+ 3]=v0.w;
    tile[tr][dc+ 4]=v1.x; tile[tr][dc+ 5]=v1.y; tile[tr][dc+ 6]=v1.z; tile[tr][dc+ 7]=v1.w;
    tile[tr][dc+ 8]=v2.x; tile[tr][dc+ 9]=v2.y; tile[tr][dc+10]=v2.z; tile[tr][dc+11]=v2.w;
    tile[tr][dc+12]=v3.x; tile[tr][dc+13]=v3.y; tile[tr][dc+14]=v3.z; tile[tr][dc+15]=v3.w;
    __syncthreads();
    const int dr = threadIdx.x >> 2;
    const int tc = (threadIdx.x & 3) * 16;
    s16x8 w0, w1;
    #pragma unroll
    for (int i = 0; i < 8; ++i) {
        w0[i] = f2h(tile[tc + i][dr]);
        w1[i] = f2h(tile[tc + 8 + i][dr]);
    }
    short* dst = vt16 + (size_t)(d0 + dr) * S_LEN + t0 + tc;
    *(s16x8*)dst = w0;
    *(s16x8*)(dst + 8) = w1;
}

// ------ double-buffered fp16 64x128 GEMM core: ONE barrier per K-step ------
__device__ __forceinline__ void gemm64_core(
        const short* pA0, const short* pB0, const short* pB1,
        int Kd, int tid, short* As, short* Bs, f32x4 (&acc)[2][4]) {
    const int lane = tid & 63, lo = lane & 15, hi = lane >> 4;
    const int wid = tid >> 6, wr = wid >> 1, wc = wid & 1;
    const int srow = tid >> 2, scol = (tid & 3) * 8;
    s16x8 a0 = *(const s16x8*)pA0;
    s16x8 b0 = *(const s16x8*)pB0;
    s16x8 b1 = *(const s16x8*)pB1;
    *(s16x8*)&As[srow*40 + scol] = a0;
    *(s16x8*)&Bs[srow*40 + scol] = b0;
    *(s16x8*)&Bs[(64+srow)*40 + scol] = b1;
    __syncthreads();
    int p = 0;
    for (int k0 = 0; k0 < Kd; k0 += 32) {
        const bool more = (k0 + 32 < Kd);
        if (more) {
            a0 = *(const s16x8*)(pA0 + k0 + 32);
            b0 = *(const s16x8*)(pB0 + k0 + 32);
            b1 = *(const s16x8*)(pB1 + k0 + 32);
        }
        const short* Asp = As + p * (64*40);
        const short* Bsp = Bs + p * (128*40);
        f16x8 aF[2], bF[4];
        #pragma unroll
        for (int m = 0; m < 2; ++m) aF[m] = *(const f16x8*)&Asp[(wr*32 + m*16 + lo)*40 + hi*8];
        #pragma unroll
        for (int n = 0; n < 4; ++n) bF[n] = *(const f16x8*)&Bsp[(wc*64 + n*16 + lo)*40 + hi*8];
        #pragma unroll
        for (int m = 0; m < 2; ++m)
            #pragma unroll
            for (int n = 0; n < 4; ++n)
                acc[m][n] = __builtin_amdgcn_mfma_f32_16x16x32_f16(aF[m], bF[n], acc[m][n], 0, 0, 0);
        if (more) {
            short* Asn = As + (p ^ 1) * (64*40);
            short* Bsn = Bs + (p ^ 1) * (128*40);
            *(s16x8*)&Asn[srow*40 + scol] = a0;
            *(s16x8*)&Bsn[srow*40 + scol] = b0;
            *(s16x8*)&Bsn[(64+srow)*40 + scol] = b1;
        }
        __syncthreads();
        p ^= 1;
    }
}

// ---------------- generic fp16 GEMM: C = A@B^T (+resid), 64-row tiles ----------------
__global__ __launch_bounds__(256) void gemm_h16_kernel(const short* __restrict__ Ag,
        const short* __restrict__ Bg, float* __restrict__ C,
        const float* __restrict__ resid, int N, int Kd) {
    __shared__ __align__(16) short As[2*64*40], Bs[2*128*40];
    const int tid = threadIdx.x;
    const int lane = tid & 63, lo = lane & 15, hi = lane >> 4;
    const int wid = tid >> 6, wr = wid >> 1, wc = wid & 1;
    const int m0 = blockIdx.y * 64, n0 = blockIdx.x * 128;
    const int srow = tid >> 2, scol = (tid & 3) * 8;
    f32x4 acc[2][4];
    #pragma unroll
    for (int m = 0; m < 2; ++m)
        #pragma unroll
        for (int n = 0; n < 4; ++n) { acc[m][n][0]=0.f; acc[m][n][1]=0.f; acc[m][n][2]=0.f; acc[m][n][3]=0.f; }
    gemm64_core(Ag + (size_t)(m0+srow)*Kd + scol,
                Bg + (size_t)(n0+srow)*Kd + scol, Bg + (size_t)(n0+64+srow)*Kd + scol,
                Kd, tid, As, Bs, acc);
    #pragma unroll
    for (int m = 0; m < 2; ++m)
        #pragma unroll
        for (int n = 0; n < 4; ++n)
            #pragma unroll
            for (int r = 0; r < 4; ++r) {
                int row = m0 + wr*32 + m*16 + hi*4 + r;
                int col = n0 + wc*64 + n*16 + lo;
                float val = acc[m][n][r];
                if (resid) val += resid[(size_t)row * N + col];
                C[(size_t)row * N + col] = val;
            }
}

// ---------------- fused QKV GEMM (fp16, 64-row tiles) ----------------
__global__ __launch_bounds__(256) void qkv_h16_kernel(const short* __restrict__ Xh,
        const short* __restrict__ qw16, const short* __restrict__ kw16,
        const short* __restrict__ vw16,
        float* __restrict__ qo, float* __restrict__ ko, float* __restrict__ vo) {
    __shared__ __align__(16) short As[2*64*40], Bs[2*128*40];
    const int bx = blockIdx.x;
    const short* Bp; float* Cp; int Nc, n0;
    if (bx < 8)       { Bp = qw16; Cp = qo; Nc = 1024; n0 = bx * 128; }
    else if (bx < 10) { Bp = kw16; Cp = ko; Nc = 256;  n0 = (bx - 8) * 128; }
    else              { Bp = vw16; Cp = vo; Nc = 256;  n0 = (bx - 10) * 128; }
    const int tid = threadIdx.x;
    const int lane = tid & 63, lo = lane & 15, hi = lane >> 4;
    const int wid = tid >> 6, wr = wid >> 1, wc = wid & 1;
    const int m0 = blockIdx.y * 64;
    const int srow = tid >> 2, scol = (tid & 3) * 8;
    f32x4 acc[2][4];
    #pragma unroll
    for (int m = 0; m < 2; ++m)
        #pragma unroll
        for (int n = 0; n < 4; ++n) { acc[m][n][0]=0.f; acc[m][n][1]=0.f; acc[m][n][2]=0.f; acc[m][n][3]=0.f; }
    gemm64_core(Xh + (size_t)(m0+srow)*HID + scol,
                Bp + (size_t)(n0+srow)*HID + scol, Bp + (size_t)(n0+64+srow)*HID + scol,
                HID, tid, As, Bs, acc);
    #pragma unroll
    for (int m = 0; m < 2; ++m)
        #pragma unroll
        for (int n = 0; n < 4; ++n)
            #pragma unroll
            for (int r = 0; r < 4; ++r) {
                int row = m0 + wr*32 + m*16 + hi*4 + r;
                int col = n0 + wc*64 + n*16 + lo;
                Cp[(size_t)row * Nc + col] = acc[m][n][r];
            }
}

// -------- split-K fp16 flash attention, BARRIER-FREE (K/V direct from L2) --------
// q16 pre-scaled by 1/8; defer-max (THR=8). Per-wave P strip in LDS only.
__global__ __launch_bounds__(256) void attn_mfma_kernel(const short* __restrict__ q16,
                                                        const short* __restrict__ k16,
                                                        const short* __restrict__ vt16,
                                                        float* __restrict__ pO,
                                                        float* __restrict__ pm,
                                                        float* __restrict__ pl) {
    __shared__ __align__(16) short Ps[4][16][72];
    const int wid = threadIdx.x >> 6, lane = threadIdx.x & 63;
    const int lo = lane & 15, hi = lane >> 4;
    const int head = blockIdx.y;
    const int s = 79 - blockIdx.x;            // long chunks dispatched first
    int qi, c;
    if (s < 8)       { qi = s;                     c = 0; }
    else if (s < 24) { int t = s - 8;  qi = 8  + (t >> 1); c = t & 1; }
    else if (s < 48) { int t = s - 24; qi = 16 + t / 3;    c = t % 3; }
    else             { int t = s - 48; qi = 24 + (t >> 2); c = t & 3; }
    const int t_beg = c * 8;
    const int t_end = min(t_beg + 8, qi + 1);
    const int q0 = qi * 64;
    const int kvh = head >> 2;

    f16x8 qf[2];
    {
        const short* qr = q16 + (size_t)(q0 + wid*16 + lo) * HID + head*HD;
        qf[0] = *(const f16x8*)(qr + hi*8);
        qf[1] = *(const f16x8*)(qr + 32 + hi*8);
    }

    f32x4 acc[4];
    float m[4], l[4];
    #pragma unroll
    for (int r = 0; r < 4; ++r) {
        m[r] = -1e30f; l[r] = 0.f;
        acc[0][r] = 0.f; acc[1][r] = 0.f; acc[2][r] = 0.f; acc[3][r] = 0.f;
    }

    // per-wave fragment base addresses (K row-major, V^T row-major)
    const short* kfb = k16 + (size_t)lo * (KVH*HD) + kvh*HD + hi*8;   // + (k0+f*16)*KVH*HD
    const short* vfb = vt16 + (size_t)(kvh*HD + lo) * S_LEN + hi*8;   // + f*16*S_LEN + k0

    for (int t = t_beg; t < t_end; ++t) {
        const int k0 = t * 64;
        // ---- QK^T: K fragments straight from global (L2-resident) ----
        f32x4 sc[4];
        #pragma unroll
        for (int f = 0; f < 4; ++f) {
            const short* kp = kfb + (size_t)(k0 + f*16) * (KVH*HD);
            f16x8 bk0 = *(const f16x8*)kp;
            f16x8 bk1 = *(const f16x8*)(kp + 32);
            f32x4 sf; sf[0]=0.f; sf[1]=0.f; sf[2]=0.f; sf[3]=0.f;
            sf = __builtin_amdgcn_mfma_f32_16x16x32_f16(qf[0], bk0, sf, 0, 0, 0);
            sf = __builtin_amdgcn_mfma_f32_16x16x32_f16(qf[1], bk1, sf, 0, 0, 0);
            sc[f] = sf;
        }
        if (t == qi) {   // diagonal tile: causal mask
            int qrow = q0 + wid*16 + hi*4;
            #pragma unroll
            for (int f = 0; f < 4; ++f)
                #pragma unroll
                for (int r = 0; r < 4; ++r)
                    if (k0 + f*16 + lo > qrow + r) sc[f][r] = -1e30f;
        }
        float pmax[4];
        #pragma unroll
        for (int r = 0; r < 4; ++r) {
            float x = fmaxf(fmaxf(sc[0][r], sc[1][r]), fmaxf(sc[2][r], sc[3][r]));
            x = fmaxf(x, __shfl_xor(x, 1));
            x = fmaxf(x, __shfl_xor(x, 2));
            x = fmaxf(x, __shfl_xor(x, 4));
            x = fmaxf(x, __shfl_xor(x, 8));
            pmax[r] = x;
        }
        bool ok = (pmax[0] <= m[0] + 8.f) && (pmax[1] <= m[1] + 8.f) &&
                  (pmax[2] <= m[2] + 8.f) && (pmax[3] <= m[3] + 8.f);
        if (!__all(ok)) {
            #pragma unroll
            for (int r = 0; r < 4; ++r) {
                float mn = fmaxf(m[r], pmax[r]);
                float sc_ = __expf(m[r] - mn);
                m[r] = mn;
                l[r] *= sc_;
                acc[0][r] *= sc_; acc[1][r] *= sc_;
                acc[2][r] *= sc_; acc[3][r] *= sc_;
            }
        }
        float rs[4] = {0.f, 0.f, 0.f, 0.f};
        #pragma unroll
        for (int f = 0; f < 4; ++f)
            #pragma unroll
            for (int r = 0; r < 4; ++r) {
                float e = __expf(sc[f][r] - m[r]);
                rs[r] += e;
                Ps[wid][hi*4 + r][f*16 + lo] = f2h(e);
            }
        #pragma unroll
        for (int r = 0; r < 4; ++r) {
            float x = rs[r];
            x += __shfl_xor(x, 1); x += __shfl_xor(x, 2);
            x += __shfl_xor(x, 4); x += __shfl_xor(x, 8);
            l[r] += x;
        }
        asm volatile("s_waitcnt lgkmcnt(0)" ::: "memory");
        __builtin_amdgcn_sched_barrier(0);
        f16x8 pa0 = *(const f16x8*)&Ps[wid][lo][hi*8];
        f16x8 pa1 = *(const f16x8*)&Ps[wid][lo][32 + hi*8];
        // ---- O += P @ V: V fragments straight from global (L2-resident) ----
        #pragma unroll
        for (int f = 0; f < 4; ++f) {
            const short* vp = vfb + (size_t)(f*16) * S_LEN + k0;
            f16x8 v0 = *(const f16x8*)vp;
            f16x8 v1 = *(const f16x8*)(vp + 32);
            f32x4 o = acc[f];
            o = __builtin_amdgcn_mfma_f32_16x16x32_f16(pa0, v0, o, 0, 0, 0);
            o = __builtin_amdgcn_mfma_f32_16x16x32_f16(pa1, v1, o, 0, 0, 0);
            acc[f] = o;
        }
    }
    const int pbase = head * 80 + s;
    float* po = pO + (size_t)pbase * 4096;
    #pragma unroll
    for (int r = 0; r < 4; ++r)
        #pragma unroll
        for (int f = 0; f < 4; ++f)
            po[(wid*16 + hi*4 + r) * 64 + f*16 + lo] = acc[f][r];
    if (lo == 0) {
        #pragma unroll
        for (int r = 0; r < 4; ++r) {
            pm[pbase*64 + wid*16 + hi*4 + r] = m[r];
            pl[pbase*64 + wid*16 + hi*4 + r] = l[r];
        }
    }
}

// ---------------- combine partials -> fp16 attention output ----------------
__global__ __launch_bounds__(256) void attn_combine_kernel(const float* __restrict__ pO,
        const float* __restrict__ pm, const float* __restrict__ pl,
        short* __restrict__ aoh) {
    const int qi = blockIdx.x, head = blockIdx.y;
    const int nch = qi / 8 + 1;
    int sbase;
    if (qi < 8)       sbase = qi;
    else if (qi < 16) sbase = 8 + (qi - 8) * 2;
    else if (qi < 24) sbase = 24 + (qi - 16) * 3;
    else              sbase = 48 + (qi - 24) * 4;
    const int row = threadIdx.x >> 2;
    const int d0 = (threadIdx.x & 3) * 16;
    float mv[4], lv[4];
    float mx = -1e30f;
    #pragma unroll
    for (int cd = 0; cd < 4; ++cd) {
        if (cd < nch) {
            int p = head * 80 + sbase + cd;
            mv[cd] = pm[p * 64 + row];
            lv[cd] = pl[p * 64 + row];
            mx = fmaxf(mx, mv[cd]);
        } else { mv[cd] = -1e30f; lv[cd] = 0.f; }
    }
    float w[4];
    float lsum = 0.f;
    #pragma unroll
    for (int cd = 0; cd < 4; ++cd) {
        w[cd] = (cd < nch) ? __expf(mv[cd] - mx) : 0.f;
        lsum += w[cd] * lv[cd];
    }
    float inv = 1.0f / lsum;
    float o[16] = {};
    #pragma unroll
    for (int cd = 0; cd < 4; ++cd) {
        if (cd < nch) {
            const float4* po = (const float4*)(pO + ((size_t)(head * 80 + sbase + cd)) * 4096 + row * 64 + d0);
            float wc = w[cd] * inv;
            #pragma unroll
            for (int j = 0; j < 4; ++j) {
                float4 vv = po[j];
                o[j*4+0] += wc * vv.x; o[j*4+1] += wc * vv.y;
                o[j*4+2] += wc * vv.z; o[j*4+3] += wc * vv.w;
            }
        }
    }
    size_t outb = (size_t)(qi * 64 + row) * HID + head * HD + d0;
    s16x8 w0, w1;
    #pragma unroll
    for (int i = 0; i < 8; ++i) { w0[i] = f2h(o[i]); w1[i] = f2h(o[8+i]); }
    *(s16x8*)(aoh + outb) = w0;
    *(s16x8*)(aoh + outb + 8) = w1;
}

// ---------------- MoE mlp1 (fp16, 64x64 tile, double-buffered 1-barrier loop) ----------
__global__ __launch_bounds__(256) void moe_mlp1_h16(const short* __restrict__ Xh,
        const short* __restrict__ W1h, const short* __restrict__ W3h,
        const int* __restrict__ cnt, const int* __restrict__ idx,
        short* __restrict__ abh) {
    int e = blockIdx.z;
    int ne = cnt[e];
    int m0 = blockIdx.y * 64;
    if (m0 >= ne) return;
    int f0 = blockIdx.x * 64;
    __shared__ __align__(16) short As[2*64*40];
    __shared__ __align__(16) short Gs[2*64*40], Us[2*64*40];
    __shared__ int rows[64];
    const int tid = threadIdx.x;
    if (tid < 64) {
        int slot = m0 + tid;
        rows[tid] = (slot < ne) ? idx[e * S_LEN + slot] : 0;
    }
    __syncthreads();
    const int lane = tid & 63, lo = lane & 15, hi = lane >> 4;
    const int wid = tid >> 6, wr = wid >> 1, wc = wid & 1;
    const int srow = tid >> 2, scol = (tid & 3) * 8;
    const short* pX0 = Xh + (size_t)rows[srow] * HID + scol;
    const short* p1 = W1h + ((size_t)e * FF + f0 + srow) * HID + scol;
    const short* p3 = W3h + ((size_t)e * FF + f0 + srow) * HID + scol;

    f32x4 ag[2][2], au[2][2];
    #pragma unroll
    for (int m = 0; m < 2; ++m)
        #pragma unroll
        for (int n = 0; n < 2; ++n) {
            ag[m][n][0]=0.f; ag[m][n][1]=0.f; ag[m][n][2]=0.f; ag[m][n][3]=0.f;
            au[m][n][0]=0.f; au[m][n][1]=0.f; au[m][n][2]=0.f; au[m][n][3]=0.f;
        }

    s16x8 a0 = *(const s16x8*)pX0;
    s16x8 g0 = *(const s16x8*)p1;
    s16x8 u0 = *(const s16x8*)p3;
    *(s16x8*)&As[srow*40 + scol] = a0;
    *(s16x8*)&Gs[srow*40 + scol] = g0;
    *(s16x8*)&Us[srow*40 + scol] = u0;
    __syncthreads();
    int p = 0;
    for (int k0 = 0; k0 < HID; k0 += 32) {
        const bool more = (k0 + 32 < HID);
        if (more) {
            a0 = *(const s16x8*)(pX0 + k0 + 32);
            g0 = *(const s16x8*)(p1 + k0 + 32);
            u0 = *(const s16x8*)(p3 + k0 + 32);
        }
        const short* Asp = As + p * (64*40);
        const short* Gsp = Gs + p * (64*40);
        const short* Usp = Us + p * (64*40);
        f16x8 aF[2], gF[2], uF[2];
        #pragma unroll
        for (int m = 0; m < 2; ++m) aF[m] = *(const f16x8*)&Asp[(wr*32 + m*16 + lo)*40 + hi*8];
        #pragma unroll
        for (int n = 0; n < 2; ++n) {
            gF[n] = *(const f16x8*)&Gsp[(wc*32 + n*16 + lo)*40 + hi*8];
            uF[n] = *(const f16x8*)&Usp[(wc*32 + n*16 + lo)*40 + hi*8];
        }
        #pragma unroll
        for (int m = 0; m < 2; ++m)
            #pragma unroll
            for (int n = 0; n < 2; ++n) {
                ag[m][n] = __builtin_amdgcn_mfma_f32_16x16x32_f16(aF[m], gF[n], ag[m][n], 0, 0, 0);
                au[m][n] = __builtin_amdgcn_mfma_f32_16x16x32_f16(aF[m], uF[n], au[m][n], 0, 0, 0);
            }
        if (more) {
            short* Asn = As + (p ^ 1) * (64*40);
            short* Gsn = Gs + (p ^ 1) * (64*40);
            short* Usn = Us + (p ^ 1) * (64*40);
            *(s16x8*)&Asn[srow*40 + scol] = a0;
            *(s16x8*)&Gsn[srow*40 + scol] = g0;
            *(s16x8*)&Usn[srow*40 + scol] = u0;
        }
        __syncthreads();
        p ^= 1;
    }
    #pragma unroll
    for (int m = 0; m < 2; ++m)
        #pragma unroll
        for (int n = 0; n < 2; ++n)
            #pragma unroll
            for (int r = 0; r < 4; ++r) {
                int slot = m0 + wr*32 + m*16 + hi*4 + r;
                if (slot >= ne) continue;
                float g = ag[m][n][r], u = au[m][n][r];
                float a = g * (1.0f / (1.0f + __expf(-g))) * u;
                abh[((size_t)e * S_LEN + slot) * FF + f0 + wc*32 + n*16 + lo] = f2h(a);
            }
}

// ------- MoE mlp2 (fp16, 64-row tile, dbuf, split-K over FF): h += wt*(a@w2^T) -------
__global__ __launch_bounds__(256) void moe_mlp2_h16(const short* __restrict__ abh,
        const short* __restrict__ W2h,
        const int* __restrict__ cnt, const int* __restrict__ idx,
        const float* __restrict__ wt, float* __restrict__ hbuf) {
    int e = blockIdx.z >> 1;
    int ks = blockIdx.z & 1;
    int ne = cnt[e];
    int m0 = blockIdx.y * 64;
    if (m0 >= ne) return;
    int n0 = blockIdx.x * 128;
    const int koff = ks * (FF / 2);
    __shared__ __align__(16) short As[2*64*40], Bs[2*128*40];
    const int tid = threadIdx.x;
    const int lane = tid & 63, lo = lane & 15, hi = lane >> 4;
    const int wid = tid >> 6, wr = wid >> 1, wc = wid & 1;
    const int srow = tid >> 2, scol = (tid & 3) * 8;
    f32x4 acc[2][4];
    #pragma unroll
    for (int m = 0; m < 2; ++m)
        #pragma unroll
        for (int n = 0; n < 4; ++n) { acc[m][n][0]=0.f; acc[m][n][1]=0.f; acc[m][n][2]=0.f; acc[m][n][3]=0.f; }
    gemm64_core(abh + ((size_t)e*S_LEN + m0 + srow)*FF + koff + scol,
                W2h + ((size_t)e*HID + n0 + srow)*FF + koff + scol,
                W2h + ((size_t)e*HID + n0 + 64 + srow)*FF + koff + scol,
                FF / 2, tid, As, Bs, acc);
    #pragma unroll
    for (int m = 0; m < 2; ++m) {
        #pragma unroll
        for (int r = 0; r < 4; ++r) {
            int slot = m0 + wr*32 + m*16 + hi*4 + r;
            if (slot >= ne) continue;
            int tok = idx[e * S_LEN + slot];
            float wv = wt[e * S_LEN + slot];
            #pragma unroll
            for (int n = 0; n < 4; ++n)
                atomicAdd(&hbuf[(size_t)tok * HID + n0 + wc*64 + n*16 + lo], acc[m][n][r] * wv);
        }
    }
}

extern "C" void kernel_launch(void* const* d_in, const int* in_sizes, int n_in,
                              void* d_out, int out_size, void* d_ws, size_t ws_size,
                              hipStream_t stream) {
    const float* emb = (const float*)d_in[0];
    const float* ln1 = (const float*)d_in[1];
    const float* ln2 = (const float*)d_in[2];
    const float* fln = (const float*)d_in[3];
    const float* qw  = (const float*)d_in[4];
    const float* kw  = (const float*)d_in[5];
    const float* vw  = (const float*)d_in[6];
    const float* ow  = (const float*)d_in[7];
    const float* gw  = (const float*)d_in[8];
    const float* w1  = (const float*)d_in[9];
    const float* w2  = (const float*)d_in[10];
    const float* w3  = (const float*)d_in[11];

    float* ws   = (float*)d_ws;
    float* h    = ws + OFF_H;
    float* q    = ws + OFF_Q;
    float* kb   = ws + OFF_K;
    float* vb   = ws + OFF_V;
    float* cosb = ws + OFF_COS;
    float* sinb = ws + OFF_SIN;
    float* wt   = ws + OFF_WT;
    int*   cnt  = (int*)(ws + OFF_INT);
    int*   idx  = cnt + 8;
    int*   tope = (int*)(ws + OFF_TOPE);
    float2* topw = (float2*)(ws + OFF_TOPW);
    short* xh   = (short*)(ws + OFF_XH);
    short* aoh  = (short*)(ws + OFF_AOH);
    short* abh  = (short*)(ws + OFF_ABH);
    short* q16  = (short*)(ws + OFF_Q16);
    short* k16  = (short*)(ws + OFF_K16);
    short* vt16 = (short*)(ws + OFF_VT16);
    float* pO   = ws + OFF_PO;
    float* pm   = ws + OFF_PM;
    float* pl   = ws + OFF_PL;
    short* WC   = (short*)(ws + OFF_WCVT);

    short* sq = WC;
    short* sk = sq + HID*HID;
    short* sv = sk + KVH*HD*HID;
    short* so = sv + KVH*HD*HID;
    short* s1 = so + HID*HID;
    short* s3 = s1 + (size_t)NE*FF*HID;
    short* s2 = s3 + (size_t)NE*FF*HID;

    hipMemcpyAsync(h, emb, (size_t)S_LEN * HID * sizeof(float), hipMemcpyDeviceToDevice, stream);
    rope_tables_kernel<<<S_LEN * 32 / 256, 256, 0, stream>>>(cosb, sinb);

    const int n8_qo = HID*HID/8, n8_kv = KVH*HD*HID/8, n8_w = NE*FF*HID/8;

    for (int l = 0; l < NL; ++l) {
        cvt16_kernel<<<n8_qo/256, 256, 0, stream>>>(qw + (size_t)l*HID*HID, sq, n8_qo);
        cvt16_kernel<<<n8_kv/256, 256, 0, stream>>>(kw + (size_t)l*KVH*HD*HID, sk, n8_kv);
        cvt16_kernel<<<n8_kv/256, 256, 0, stream>>>(vw + (size_t)l*KVH*HD*HID, sv, n8_kv);
        cvt16_kernel<<<n8_qo/256, 256, 0, stream>>>(ow + (size_t)l*HID*HID, so, n8_qo);

        rmsnorm_h16_kernel<<<S_LEN, 256, 0, stream>>>(h, ln1 + l * HID, xh);
        qkv_h16_kernel<<<dim3(12, 32), 256, 0, stream>>>(xh, sq, sk, sv, q, kb, vb);
        rope_cvt_kernel<<<(S_LEN * NHEAD * 32) / 256, 256, 0, stream>>>(q, cosb, sinb, q16, NHEAD, S_LEN * NHEAD * 32, 0.125f);
        rope_cvt_kernel<<<(S_LEN * KVH * 32) / 256, 256, 0, stream>>>(kb, cosb, sinb, k16, KVH, S_LEN * KVH * 32, 1.0f);
        vtrans_kernel<<<dim3(S_LEN/64, KVH*HD/64), 256, 0, stream>>>(vb, vt16);
        attn_mfma_kernel<<<dim3(80, NHEAD), 256, 0, stream>>>(q16, k16, vt16, pO, pm, pl);
        attn_combine_kernel<<<dim3(32, NHEAD), 256, 0, stream>>>(pO, pm, pl, aoh);
        gemm_h16_kernel<<<dim3(8, 32), 256, 0, stream>>>(aoh, so, h, h, HID, HID);

        rmsnorm_gate_kernel<<<S_LEN, 256, 0, stream>>>(h, ln2 + l * HID, gw + (size_t)l * NE * HID,
                                                       xh, tope, topw);
        route_build_kernel<<<NE, 1024, 0, stream>>>(tope, topw, cnt, idx, wt);

        cvt16_kernel<<<n8_w/256, 256, 0, stream>>>(w1 + (size_t)l*NE*FF*HID, s1, n8_w);
        cvt16_kernel<<<n8_w/256, 256, 0, stream>>>(w3 + (size_t)l*NE*FF*HID, s3, n8_w);
        moe_mlp1_h16<<<dim3(16, 32, 8), 256, 0, stream>>>(xh, s1, s3, cnt, idx, abh);

        cvt16_kernel<<<n8_w/256, 256, 0, stream>>>(w2 + (size_t)l*NE*HID*FF, s2, n8_w);
        moe_mlp2_h16<<<dim3(8, 32, 16), 256, 0, stream>>>(abh, s2, cnt, idx, wt, h);
    }
    rmsnorm_kernel<<<S_LEN, 256, 0, stream>>>(h, fln, (float*)d_out);
}

// Round 17
// 486.070 us; speedup vs baseline: 1.1805x; 1.1805x over previous
//
#include <hip/hip_runtime.h>
#include <hip/hip_bf16.h>
#include <math.h>

#define S_LEN 2048
#define HID   1024
#define NHEAD 16
#define KVH   4
#define HD    64
#define FF    1024
#define NE    8
#define NL    2
#define NSLOT 144   // sum over qi of ceil((qi+1)/4), qi in [0,32)

// ---- workspace layout (float offsets) ----
#define OFF_H    0
#define OFF_Q    (OFF_H + S_LEN*HID)
#define OFF_K    (OFF_Q + S_LEN*HID)
#define OFF_V    (OFF_K + S_LEN*KVH*HD)
#define OFF_COS  (OFF_V + S_LEN*KVH*HD)
#define OFF_SIN  (OFF_COS + S_LEN*32)
#define OFF_WT   (OFF_SIN + S_LEN*32)
#define OFF_INT  (OFF_WT + NE*S_LEN)
#define OFF_TOPE (OFF_INT + NE*S_LEN + 16)
#define OFF_TOPW (OFF_TOPE + S_LEN)
#define OFF_XH   (OFF_TOPW + 2*S_LEN)
#define OFF_AOH  (OFF_XH + S_LEN*HID/2)
#define OFF_ABH  (OFF_AOH + S_LEN*HID/2)
#define OFF_Q16  (OFF_ABH + NE*S_LEN*FF/2)
#define OFF_K16  (OFF_Q16 + S_LEN*HID/2)
#define OFF_VT16 (OFF_K16 + S_LEN*KVH*HD/2)
#define OFF_PO   (OFF_VT16 + S_LEN*KVH*HD/2)
#define OFF_PM   (OFF_PO + NSLOT*NHEAD*64*64)
#define OFF_PL   (OFF_PM + NSLOT*NHEAD*64)
#define OFF_WCVT (OFF_PL + NSLOT*NHEAD*64)

typedef __attribute__((ext_vector_type(8))) _Float16 f16x8;
typedef __attribute__((ext_vector_type(8))) short  s16x8;
typedef __attribute__((ext_vector_type(4))) float  f32x4;

__device__ __forceinline__ short f2h(float f) {
    union { _Float16 h; short s; } u;
    u.h = (_Float16)f;
    return u.s;
}

__device__ __forceinline__ s16x8 cvt8(float4 a, float4 b) {
    s16x8 w;
    w[0]=f2h(a.x); w[1]=f2h(a.y); w[2]=f2h(a.z); w[3]=f2h(a.w);
    w[4]=f2h(b.x); w[5]=f2h(b.y); w[6]=f2h(b.z); w[7]=f2h(b.w);
    return w;
}

// ---------------- fp32 -> fp16 convert ----------------
__global__ __launch_bounds__(256) void cvt16_kernel(const float* __restrict__ src,
                                                    short* __restrict__ dst, int n8) {
    int gid = blockIdx.x * 256 + threadIdx.x;
    if (gid >= n8) return;
    const float4* s = (const float4*)src + (size_t)gid * 2;
    *(s16x8*)(dst + (size_t)gid * 8) = cvt8(s[0], s[1]);
}

// ---------------- RoPE tables ----------------
__global__ void rope_tables_kernel(float* __restrict__ cosb, float* __restrict__ sinb) {
    int gid = blockIdx.x * 256 + threadIdx.x;
    int t = gid >> 5, i = gid & 31;
    float invf = powf(1.0e6f, -(float)i / 32.0f);
    float ang = (float)t * invf;
    cosb[gid] = cosf(ang);
    sinb[gid] = sinf(ang);
}

// ---------------- RMSNorm -> fp16 only ----------------
__global__ __launch_bounds__(256) void rmsnorm_h16_kernel(const float* __restrict__ x,
                                                          const float* __restrict__ w,
                                                          short* __restrict__ oh) {
    int row = blockIdx.x;
    const float4* xr = (const float4*)(x + (size_t)row * HID);
    float4 xv = xr[threadIdx.x];
    float ss = xv.x*xv.x + xv.y*xv.y + xv.z*xv.z + xv.w*xv.w;
    for (int off = 32; off; off >>= 1) ss += __shfl_xor(ss, off);
    __shared__ float sred[4];
    if ((threadIdx.x & 63) == 0) sred[threadIdx.x >> 6] = ss;
    __syncthreads();
    float tot = sred[0] + sred[1] + sred[2] + sred[3];
    float scale = rsqrtf(tot * (1.0f / (float)HID) + 1e-5f);
    float4 wv = ((const float4*)w)[threadIdx.x];
    float4 o;
    o.x = xv.x * scale * wv.x; o.y = xv.y * scale * wv.y;
    o.z = xv.z * scale * wv.z; o.w = xv.w * scale * wv.w;
    union { short s[4]; float2 f2; } hh;
    hh.s[0]=f2h(o.x); hh.s[1]=f2h(o.y); hh.s[2]=f2h(o.z); hh.s[3]=f2h(o.w);
    ((float2*)(oh + (size_t)row * HID))[threadIdx.x] = hh.f2;
}

// ---------------- RMSNorm + gate top-2 (NO atomics) ----------------
__global__ __launch_bounds__(256) void rmsnorm_gate_kernel(const float* __restrict__ x,
                                                           const float* __restrict__ w,
                                                           const float* __restrict__ gw,
                                                           short* __restrict__ oh,
                                                           int* __restrict__ tope,
                                                           float2* __restrict__ topw) {
    int row = blockIdx.x;
    const float4* xr = (const float4*)(x + (size_t)row * HID);
    float4 xv = xr[threadIdx.x];
    float ss = xv.x*xv.x + xv.y*xv.y + xv.z*xv.z + xv.w*xv.w;
    for (int off = 32; off; off >>= 1) ss += __shfl_xor(ss, off);
    __shared__ float sred[4];
    __shared__ float gred[4][NE];
    if ((threadIdx.x & 63) == 0) sred[threadIdx.x >> 6] = ss;
    __syncthreads();
    float tot = sred[0] + sred[1] + sred[2] + sred[3];
    float scale = rsqrtf(tot * (1.0f / (float)HID) + 1e-5f);
    float4 wv = ((const float4*)w)[threadIdx.x];
    float4 o;
    o.x = xv.x * scale * wv.x; o.y = xv.y * scale * wv.y;
    o.z = xv.z * scale * wv.z; o.w = xv.w * scale * wv.w;
    union { short s[4]; float2 f2; } hh;
    hh.s[0]=f2h(o.x); hh.s[1]=f2h(o.y); hh.s[2]=f2h(o.z); hh.s[3]=f2h(o.w);
    ((float2*)(oh + (size_t)row * HID))[threadIdx.x] = hh.f2;
    const float4* gr = (const float4*)gw;
    float acc[NE];
    #pragma unroll
    for (int e = 0; e < NE; ++e) {
        float4 g4 = gr[e * 256 + threadIdx.x];
        acc[e] = o.x*g4.x + o.y*g4.y + o.z*g4.z + o.w*g4.w;
    }
    #pragma unroll
    for (int e = 0; e < NE; ++e)
        for (int off = 32; off; off >>= 1) acc[e] += __shfl_xor(acc[e], off);
    if ((threadIdx.x & 63) == 0) {
        #pragma unroll
        for (int e = 0; e < NE; ++e) gred[threadIdx.x >> 6][e] = acc[e];
    }
    __syncthreads();
    if (threadIdx.x == 0) {
        float lg[NE];
        #pragma unroll
        for (int e = 0; e < NE; ++e)
            lg[e] = gred[0][e] + gred[1][e] + gred[2][e] + gred[3][e];
        float mx = lg[0];
        #pragma unroll
        for (int e = 1; e < NE; ++e) mx = fmaxf(mx, lg[e]);
        float p[NE];
        #pragma unroll
        for (int e = 0; e < NE; ++e) p[e] = __expf(lg[e] - mx);
        int i0 = 0;
        #pragma unroll
        for (int e = 1; e < NE; ++e) if (p[e] > p[i0]) i0 = e;
        int i1 = -1;
        #pragma unroll
        for (int e = 0; e < NE; ++e) if (e != i0 && (i1 < 0 || p[e] > p[i1])) i1 = e;
        float w0 = p[i0], w1 = p[i1];
        float inv = 1.0f / (w0 + w1);
        tope[row] = i0 | (i1 << 8);
        topw[row] = make_float2(w0 * inv, w1 * inv);
    }
}

// ---------------- build per-expert token lists (ballot prefix-scan, no atomics) ----------
__global__ __launch_bounds__(1024) void route_build_kernel(const int* __restrict__ tope,
                                                           const float2* __restrict__ topw,
                                                           int* __restrict__ cnt,
                                                           int* __restrict__ idx,
                                                           float* __restrict__ wt) {
    const int e = blockIdx.x;
    const int lane = threadIdx.x & 63, wv = threadIdx.x >> 6;
    __shared__ int wtot[16];
    __shared__ int sbase;
    if (threadIdx.x == 0) sbase = 0;
    __syncthreads();
    for (int t0 = 0; t0 < S_LEN; t0 += 1024) {
        int t = t0 + threadIdx.x;
        int pk = tope[t];
        int e0 = pk & 0xff, e1 = (pk >> 8) & 0xff;
        bool sel = (e0 == e) || (e1 == e);
        unsigned long long mask = __ballot(sel);
        int prefix = __popcll(mask & ((1ULL << lane) - 1ULL));
        if (lane == 0) wtot[wv] = __popcll(mask);
        __syncthreads();
        if (sel) {
            int off = sbase;
            for (int i = 0; i < wv; ++i) off += wtot[i];
            float2 wpair = topw[t];
            float wsel = (e0 == e) ? wpair.x : wpair.y;
            int slot = off + prefix;
            idx[e * S_LEN + slot] = t;
            wt[e * S_LEN + slot] = wsel;
        }
        __syncthreads();
        if (threadIdx.x == 0) {
            int s = 0;
            #pragma unroll
            for (int i = 0; i < 16; ++i) s += wtot[i];
            sbase += s;
        }
    }
    __syncthreads();
    if (threadIdx.x == 0) cnt[e] = sbase;
}

// plain rmsnorm for final output (fp32)
__global__ __launch_bounds__(256) void rmsnorm_kernel(const float* __restrict__ x,
                                                      const float* __restrict__ w,
                                                      float* __restrict__ out) {
    int row = blockIdx.x;
    const float4* xr = (const float4*)(x + (size_t)row * HID);
    float4 xv = xr[threadIdx.x];
    float ss = xv.x*xv.x + xv.y*xv.y + xv.z*xv.z + xv.w*xv.w;
    for (int off = 32; off; off >>= 1) ss += __shfl_xor(ss, off);
    __shared__ float sred[4];
    if ((threadIdx.x & 63) == 0) sred[threadIdx.x >> 6] = ss;
    __syncthreads();
    float tot = sred[0] + sred[1] + sred[2] + sred[3];
    float scale = rsqrtf(tot * (1.0f / (float)HID) + 1e-5f);
    float4 wv = ((const float4*)w)[threadIdx.x];
    float4 o;
    o.x = xv.x * scale * wv.x; o.y = xv.y * scale * wv.y;
    o.z = xv.z * scale * wv.z; o.w = xv.w * scale * wv.w;
    ((float4*)(out + (size_t)row * HID))[threadIdx.x] = o;
}

// ---------------- RoPE apply + fp16 convert (q scaled by 1/8, k unscaled) ------------
__global__ void rope_cvt_kernel(const float* __restrict__ p, const float* __restrict__ cosb,
                                const float* __restrict__ sinb, short* __restrict__ o16,
                                int nh, int total, float qscale) {
    int gid = blockIdx.x * 256 + threadIdx.x;
    if (gid >= total) return;
    int per = nh * 32;
    int t = gid / per, r = gid % per;
    int hh = r >> 5, i = r & 31;
    float c = cosb[t*32 + i], s = sinb[t*32 + i];
    const float* base = p + (size_t)t * (nh * HD) + hh * HD + i;
    float a = base[0], b = base[32];
    short* ob = o16 + (size_t)t * (nh * HD) + hh * HD + i;
    ob[0]  = f2h((a * c - b * s) * qscale);
    ob[32] = f2h((b * c + a * s) * qscale);
}

// ---------------- V transpose + fp16 ----------------
__global__ __launch_bounds__(256) void vtrans_kernel(const float* __restrict__ vb,
                                                     short* __restrict__ vt16) {
    __shared__ float tile[64][65];
    const int t0 = blockIdx.x * 64, d0 = blockIdx.y * 64;
    const int tr = threadIdx.x >> 2;
    const int dc = (threadIdx.x & 3) * 16;
    const float4* src = (const float4*)(vb + (size_t)(t0 + tr) * (KVH*HD) + d0 + dc);
    float4 v0 = src[0], v1 = src[1], v2 = src[2], v3 = src[3];
    tile[tr][dc+ 0]=v0.x; tile[tr][dc+ 1]=v0.y; tile[tr][dc+ 2]=v0.z; tile[tr][dc+ 3]=v0.w;
    tile[tr][dc+ 4]=v1.x; tile[tr][dc+ 5]=v1.y; tile[tr][dc+ 6]=v1.z; tile[tr][dc+ 7]=v1.w;
    tile[tr][dc+ 8]=v2.x; tile[tr][dc+ 9]=v2.y; tile[tr][dc+10]=v2.z; tile[tr][dc+11]=v2.w;
    tile[tr][dc+12]=v3.x; tile[tr][dc+13]=v3.y; tile[tr][dc+14]=v3.z; tile[tr][dc+15]=v3.w;
    __syncthreads();
    const int dr = threadIdx.x >> 2;
    const int tc = (threadIdx.x & 3) * 16;
    s16x8 w0, w1;
    #pragma unroll
    for (int i = 0; i < 8; ++i) {
        w0[i] = f2h(tile[tc + i][dr]);
        w1[i] = f2h(tile[tc + 8 + i][dr]);
    }
    short* dst = vt16 + (size_t)(d0 + dr) * S_LEN + t0 + tc;
    *(s16x8*)dst = w0;
    *(s16x8*)(dst + 8) = w1;
}

// ------ double-buffered fp16 64x128 GEMM core: ONE barrier per K-step ------
__device__ __forceinline__ void gemm64_core(
        const short* pA0, const short* pB0, const short* pB1,
        int Kd, int tid, short* As, short* Bs, f32x4 (&acc)[2][4]) {
    const int lane = tid & 63, lo = lane & 15, hi = lane >> 4;
    const int wid = tid >> 6, wr = wid >> 1, wc = wid & 1;
    const int srow = tid >> 2, scol = (tid & 3) * 8;
    s16x8 a0 = *(const s16x8*)pA0;
    s16x8 b0 = *(const s16x8*)pB0;
    s16x8 b1 = *(const s16x8*)pB1;
    *(s16x8*)&As[srow*40 + scol] = a0;
    *(s16x8*)&Bs[srow*40 + scol] = b0;
    *(s16x8*)&Bs[(64+srow)*40 + scol] = b1;
    __syncthreads();
    int p = 0;
    for (int k0 = 0; k0 < Kd; k0 += 32) {
        const bool more = (k0 + 32 < Kd);
        if (more) {
            a0 = *(const s16x8*)(pA0 + k0 + 32);
            b0 = *(const s16x8*)(pB0 + k0 + 32);
            b1 = *(const s16x8*)(pB1 + k0 + 32);
        }
        const short* Asp = As + p * (64*40);
        const short* Bsp = Bs + p * (128*40);
        f16x8 aF[2], bF[4];
        #pragma unroll
        for (int m = 0; m < 2; ++m) aF[m] = *(const f16x8*)&Asp[(wr*32 + m*16 + lo)*40 + hi*8];
        #pragma unroll
        for (int n = 0; n < 4; ++n) bF[n] = *(const f16x8*)&Bsp[(wc*64 + n*16 + lo)*40 + hi*8];
        #pragma unroll
        for (int m = 0; m < 2; ++m)
            #pragma unroll
            for (int n = 0; n < 4; ++n)
                acc[m][n] = __builtin_amdgcn_mfma_f32_16x16x32_f16(aF[m], bF[n], acc[m][n], 0, 0, 0);
        if (more) {
            short* Asn = As + (p ^ 1) * (64*40);
            short* Bsn = Bs + (p ^ 1) * (128*40);
            *(s16x8*)&Asn[srow*40 + scol] = a0;
            *(s16x8*)&Bsn[srow*40 + scol] = b0;
            *(s16x8*)&Bsn[(64+srow)*40 + scol] = b1;
        }
        __syncthreads();
        p ^= 1;
    }
}

// ---------------- generic fp16 GEMM: C = A@B^T (+resid), 64-row tiles ----------------
__global__ __launch_bounds__(256) void gemm_h16_kernel(const short* __restrict__ Ag,
        const short* __restrict__ Bg, float* __restrict__ C,
        const float* __restrict__ resid, int N, int Kd) {
    __shared__ __align__(16) short As[2*64*40], Bs[2*128*40];
    const int tid = threadIdx.x;
    const int lane = tid & 63, lo = lane & 15, hi = lane >> 4;
    const int wid = tid >> 6, wr = wid >> 1, wc = wid & 1;
    const int m0 = blockIdx.y * 64, n0 = blockIdx.x * 128;
    const int srow = tid >> 2, scol = (tid & 3) * 8;
    f32x4 acc[2][4];
    #pragma unroll
    for (int m = 0; m < 2; ++m)
        #pragma unroll
        for (int n = 0; n < 4; ++n) { acc[m][n][0]=0.f; acc[m][n][1]=0.f; acc[m][n][2]=0.f; acc[m][n][3]=0.f; }
    gemm64_core(Ag + (size_t)(m0+srow)*Kd + scol,
                Bg + (size_t)(n0+srow)*Kd + scol, Bg + (size_t)(n0+64+srow)*Kd + scol,
                Kd, tid, As, Bs, acc);
    #pragma unroll
    for (int m = 0; m < 2; ++m)
        #pragma unroll
        for (int n = 0; n < 4; ++n)
            #pragma unroll
            for (int r = 0; r < 4; ++r) {
                int row = m0 + wr*32 + m*16 + hi*4 + r;
                int col = n0 + wc*64 + n*16 + lo;
                float val = acc[m][n][r];
                if (resid) val += resid[(size_t)row * N + col];
                C[(size_t)row * N + col] = val;
            }
}

// ---------------- fused QKV GEMM (fp16, 64-row tiles) ----------------
__global__ __launch_bounds__(256) void qkv_h16_kernel(const short* __restrict__ Xh,
        const short* __restrict__ qw16, const short* __restrict__ kw16,
        const short* __restrict__ vw16,
        float* __restrict__ qo, float* __restrict__ ko, float* __restrict__ vo) {
    __shared__ __align__(16) short As[2*64*40], Bs[2*128*40];
    const int bx = blockIdx.x;
    const short* Bp; float* Cp; int Nc, n0;
    if (bx < 8)       { Bp = qw16; Cp = qo; Nc = 1024; n0 = bx * 128; }
    else if (bx < 10) { Bp = kw16; Cp = ko; Nc = 256;  n0 = (bx - 8) * 128; }
    else              { Bp = vw16; Cp = vo; Nc = 256;  n0 = (bx - 10) * 128; }
    const int tid = threadIdx.x;
    const int lane = tid & 63, lo = lane & 15, hi = lane >> 4;
    const int wid = tid >> 6, wr = wid >> 1, wc = wid & 1;
    const int m0 = blockIdx.y * 64;
    const int srow = tid >> 2, scol = (tid & 3) * 8;
    f32x4 acc[2][4];
    #pragma unroll
    for (int m = 0; m < 2; ++m)
        #pragma unroll
        for (int n = 0; n < 4; ++n) { acc[m][n][0]=0.f; acc[m][n][1]=0.f; acc[m][n][2]=0.f; acc[m][n][3]=0.f; }
    gemm64_core(Xh + (size_t)(m0+srow)*HID + scol,
                Bp + (size_t)(n0+srow)*HID + scol, Bp + (size_t)(n0+64+srow)*HID + scol,
                HID, tid, As, Bs, acc);
    #pragma unroll
    for (int m = 0; m < 2; ++m)
        #pragma unroll
        for (int n = 0; n < 4; ++n)
            #pragma unroll
            for (int r = 0; r < 4; ++r) {
                int row = m0 + wr*32 + m*16 + hi*4 + r;
                int col = n0 + wc*64 + n*16 + lo;
                Cp[(size_t)row * Nc + col] = acc[m][n][r];
            }
}

// -------- split-K fp16 flash attention (LDS-staged, uniform 4-tile chunks) --------
// q16 pre-scaled by 1/8; defer-max (THR=8). NSLOT=144 slots/head.
__global__ __launch_bounds__(256) void attn_mfma_kernel(const short* __restrict__ q16,
                                                        const short* __restrict__ k16,
                                                        const short* __restrict__ vt16,
                                                        float* __restrict__ pO,
                                                        float* __restrict__ pm,
                                                        float* __restrict__ pl) {
    __shared__ __align__(16) short Ks[64][72];
    __shared__ __align__(16) short Vt[64][72];
    __shared__ __align__(16) short Ps[4][16][72];
    const int wid = threadIdx.x >> 6, lane = threadIdx.x & 63;
    const int lo = lane & 15, hi = lane >> 4;
    const int head = blockIdx.y;
    const int s = (NSLOT - 1) - blockIdx.x;   // long chunks (group 7) dispatched first
    // slot -> (qi, c): group g covers qi in [4g,4g+4), each with g+1 chunks of <=4 tiles
    int g = 0, base = 0;
    while (g < 7 && s >= base + 4 * (g + 1)) { base += 4 * (g + 1); ++g; }
    const int tt = s - base;
    const int qi = 4 * g + tt / (g + 1);
    const int c  = tt % (g + 1);
    const int t_beg = c * 4;
    const int t_end = min(t_beg + 4, qi + 1);
    const int q0 = qi * 64;
    const int kvh = head >> 2;

    f16x8 qf[2];
    {
        const short* qr = q16 + (size_t)(q0 + wid*16 + lo) * HID + head*HD;
        qf[0] = *(const f16x8*)(qr + hi*8);
        qf[1] = *(const f16x8*)(qr + 32 + hi*8);
    }

    f32x4 acc[4];
    float m[4], l[4];
    #pragma unroll
    for (int r = 0; r < 4; ++r) {
        m[r] = -1e30f; l[r] = 0.f;
        acc[0][r] = 0.f; acc[1][r] = 0.f; acc[2][r] = 0.f; acc[3][r] = 0.f;
    }

    const int skey = threadIdx.x >> 2;
    const int sdg  = (threadIdx.x & 3) * 16;

    s16x8 ka0, ka1, va0, va1;
    {
        const short* kr = k16 + (size_t)(t_beg*64 + skey)*(KVH*HD) + kvh*HD + sdg;
        ka0 = *(const s16x8*)kr; ka1 = *(const s16x8*)(kr + 8);
        const short* vr = vt16 + (size_t)(kvh*HD + skey)*S_LEN + t_beg*64 + sdg;
        va0 = *(const s16x8*)vr; va1 = *(const s16x8*)(vr + 8);
    }

    for (int t = t_beg; t < t_end; ++t) {
        __syncthreads();
        *(s16x8*)&Ks[skey][sdg]     = ka0;
        *(s16x8*)&Ks[skey][sdg + 8] = ka1;
        *(s16x8*)&Vt[skey][sdg]     = va0;
        *(s16x8*)&Vt[skey][sdg + 8] = va1;
        __syncthreads();
        if (t + 1 < t_end) {
            const short* kr = k16 + (size_t)((t+1)*64 + skey)*(KVH*HD) + kvh*HD + sdg;
            ka0 = *(const s16x8*)kr; ka1 = *(const s16x8*)(kr + 8);
            const short* vr = vt16 + (size_t)(kvh*HD + skey)*S_LEN + (t+1)*64 + sdg;
            va0 = *(const s16x8*)vr; va1 = *(const s16x8*)(vr + 8);
        }
        const int k0 = t * 64;
        f32x4 sc[4];
        #pragma unroll
        for (int f = 0; f < 4; ++f) {
            f32x4 sf; sf[0]=0.f; sf[1]=0.f; sf[2]=0.f; sf[3]=0.f;
            f16x8 bk0 = *(const f16x8*)&Ks[f*16 + lo][hi*8];
            sf = __builtin_amdgcn_mfma_f32_16x16x32_f16(qf[0], bk0, sf, 0, 0, 0);
            f16x8 bk1 = *(const f16x8*)&Ks[f*16 + lo][32 + hi*8];
            sf = __builtin_amdgcn_mfma_f32_16x16x32_f16(qf[1], bk1, sf, 0, 0, 0);
            sc[f] = sf;
        }
        if (t == qi) {   // diagonal tile: causal mask
            int qrow = q0 + wid*16 + hi*4;
            #pragma unroll
            for (int f = 0; f < 4; ++f)
                #pragma unroll
                for (int r = 0; r < 4; ++r)
                    if (k0 + f*16 + lo > qrow + r) sc[f][r] = -1e30f;
        }
        float pmax[4];
        #pragma unroll
        for (int r = 0; r < 4; ++r) {
            float x = fmaxf(fmaxf(sc[0][r], sc[1][r]), fmaxf(sc[2][r], sc[3][r]));
            x = fmaxf(x, __shfl_xor(x, 1));
            x = fmaxf(x, __shfl_xor(x, 2));
            x = fmaxf(x, __shfl_xor(x, 4));
            x = fmaxf(x, __shfl_xor(x, 8));
            pmax[r] = x;
        }
        bool ok = (pmax[0] <= m[0] + 8.f) && (pmax[1] <= m[1] + 8.f) &&
                  (pmax[2] <= m[2] + 8.f) && (pmax[3] <= m[3] + 8.f);
        if (!__all(ok)) {
            #pragma unroll
            for (int r = 0; r < 4; ++r) {
                float mn = fmaxf(m[r], pmax[r]);
                float sc_ = __expf(m[r] - mn);
                m[r] = mn;
                l[r] *= sc_;
                acc[0][r] *= sc_; acc[1][r] *= sc_;
                acc[2][r] *= sc_; acc[3][r] *= sc_;
            }
        }
        float rs[4] = {0.f, 0.f, 0.f, 0.f};
        #pragma unroll
        for (int f = 0; f < 4; ++f)
            #pragma unroll
            for (int r = 0; r < 4; ++r) {
                float e = __expf(sc[f][r] - m[r]);
                rs[r] += e;
                Ps[wid][hi*4 + r][f*16 + lo] = f2h(e);
            }
        #pragma unroll
        for (int r = 0; r < 4; ++r) {
            float x = rs[r];
            x += __shfl_xor(x, 1); x += __shfl_xor(x, 2);
            x += __shfl_xor(x, 4); x += __shfl_xor(x, 8);
            l[r] += x;
        }
        asm volatile("s_waitcnt lgkmcnt(0)" ::: "memory");
        __builtin_amdgcn_sched_barrier(0);
        f16x8 pa0 = *(const f16x8*)&Ps[wid][lo][hi*8];
        f16x8 pa1 = *(const f16x8*)&Ps[wid][lo][32 + hi*8];
        #pragma unroll
        for (int f = 0; f < 4; ++f) {
            f32x4 o = acc[f];
            f16x8 v0 = *(const f16x8*)&Vt[f*16 + lo][hi*8];
            o = __builtin_amdgcn_mfma_f32_16x16x32_f16(pa0, v0, o, 0, 0, 0);
            f16x8 v1 = *(const f16x8*)&Vt[f*16 + lo][32 + hi*8];
            o = __builtin_amdgcn_mfma_f32_16x16x32_f16(pa1, v1, o, 0, 0, 0);
            acc[f] = o;
        }
    }
    const int pbase = head * NSLOT + s;
    float* po = pO + (size_t)pbase * 4096;
    #pragma unroll
    for (int r = 0; r < 4; ++r)
        #pragma unroll
        for (int f = 0; f < 4; ++f)
            po[(wid*16 + hi*4 + r) * 64 + f*16 + lo] = acc[f][r];
    if (lo == 0) {
        #pragma unroll
        for (int r = 0; r < 4; ++r) {
            pm[pbase*64 + wid*16 + hi*4 + r] = m[r];
            pl[pbase*64 + wid*16 + hi*4 + r] = l[r];
        }
    }
}

// ---------------- combine partials (up to 8 chunks) -> fp16 attention output ----------
__global__ __launch_bounds__(256) void attn_combine_kernel(const float* __restrict__ pO,
        const float* __restrict__ pm, const float* __restrict__ pl,
        short* __restrict__ aoh) {
    const int qi = blockIdx.x, head = blockIdx.y;
    const int g = qi >> 2, rr = qi & 3;
    const int nch = g + 1;
    const int sbase = (g + 1) * (2 * g + rr);   // 2g(g+1) + r(g+1)
    const int row = threadIdx.x >> 2;
    const int d0 = (threadIdx.x & 3) * 16;
    float mv[8], lv[8];
    float mx = -1e30f;
    #pragma unroll
    for (int cd = 0; cd < 8; ++cd) {
        if (cd < nch) {
            int p = head * NSLOT + sbase + cd;
            mv[cd] = pm[p * 64 + row];
            lv[cd] = pl[p * 64 + row];
            mx = fmaxf(mx, mv[cd]);
        } else { mv[cd] = -1e30f; lv[cd] = 0.f; }
    }
    float w[8];
    float lsum = 0.f;
    #pragma unroll
    for (int cd = 0; cd < 8; ++cd) {
        w[cd] = (cd < nch) ? __expf(mv[cd] - mx) : 0.f;
        lsum += w[cd] * lv[cd];
    }
    float inv = 1.0f / lsum;
    float o[16] = {};
    #pragma unroll
    for (int cd = 0; cd < 8; ++cd) {
        if (cd < nch) {
            const float4* po = (const float4*)(pO + ((size_t)(head * NSLOT + sbase + cd)) * 4096 + row * 64 + d0);
            float wc = w[cd] * inv;
            #pragma unroll
            for (int j = 0; j < 4; ++j) {
                float4 vv = po[j];
                o[j*4+0] += wc * vv.x; o[j*4+1] += wc * vv.y;
                o[j*4+2] += wc * vv.z; o[j*4+3] += wc * vv.w;
            }
        }
    }
    size_t outb = (size_t)(qi * 64 + row) * HID + head * HD + d0;
    s16x8 w0, w1;
    #pragma unroll
    for (int i = 0; i < 8; ++i) { w0[i] = f2h(o[i]); w1[i] = f2h(o[8+i]); }
    *(s16x8*)(aoh + outb) = w0;
    *(s16x8*)(aoh + outb + 8) = w1;
}

// ---------------- MoE mlp1 (fp16, 64x64 tile, double-buffered 1-barrier loop) ----------
__global__ __launch_bounds__(256) void moe_mlp1_h16(const short* __restrict__ Xh,
        const short* __restrict__ W1h, const short* __restrict__ W3h,
        const int* __restrict__ cnt, const int* __restrict__ idx,
        short* __restrict__ abh) {
    int e = blockIdx.z;
    int ne = cnt[e];
    int m0 = blockIdx.y * 64;
    if (m0 >= ne) return;
    int f0 = blockIdx.x * 64;
    __shared__ __align__(16) short As[2*64*40];
    __shared__ __align__(16) short Gs[2*64*40], Us[2*64*40];
    __shared__ int rows[64];
    const int tid = threadIdx.x;
    if (tid < 64) {
        int slot = m0 + tid;
        rows[tid] = (slot < ne) ? idx[e * S_LEN + slot] : 0;
    }
    __syncthreads();
    const int lane = tid & 63, lo = lane & 15, hi = lane >> 4;
    const int wid = tid >> 6, wr = wid >> 1, wc = wid & 1;
    const int srow = tid >> 2, scol = (tid & 3) * 8;
    const short* pX0 = Xh + (size_t)rows[srow] * HID + scol;
    const short* p1 = W1h + ((size_t)e * FF + f0 + srow) * HID + scol;
    const short* p3 = W3h + ((size_t)e * FF + f0 + srow) * HID + scol;

    f32x4 ag[2][2], au[2][2];
    #pragma unroll
    for (int m = 0; m < 2; ++m)
        #pragma unroll
        for (int n = 0; n < 2; ++n) {
            ag[m][n][0]=0.f; ag[m][n][1]=0.f; ag[m][n][2]=0.f; ag[m][n][3]=0.f;
            au[m][n][0]=0.f; au[m][n][1]=0.f; au[m][n][2]=0.f; au[m][n][3]=0.f;
        }

    s16x8 a0 = *(const s16x8*)pX0;
    s16x8 g0 = *(const s16x8*)p1;
    s16x8 u0 = *(const s16x8*)p3;
    *(s16x8*)&As[srow*40 + scol] = a0;
    *(s16x8*)&Gs[srow*40 + scol] = g0;
    *(s16x8*)&Us[srow*40 + scol] = u0;
    __syncthreads();
    int p = 0;
    for (int k0 = 0; k0 < HID; k0 += 32) {
        const bool more = (k0 + 32 < HID);
        if (more) {
            a0 = *(const s16x8*)(pX0 + k0 + 32);
            g0 = *(const s16x8*)(p1 + k0 + 32);
            u0 = *(const s16x8*)(p3 + k0 + 32);
        }
        const short* Asp = As + p * (64*40);
        const short* Gsp = Gs + p * (64*40);
        const short* Usp = Us + p * (64*40);
        f16x8 aF[2], gF[2], uF[2];
        #pragma unroll
        for (int m = 0; m < 2; ++m) aF[m] = *(const f16x8*)&Asp[(wr*32 + m*16 + lo)*40 + hi*8];
        #pragma unroll
        for (int n = 0; n < 2; ++n) {
            gF[n] = *(const f16x8*)&Gsp[(wc*32 + n*16 + lo)*40 + hi*8];
            uF[n] = *(const f16x8*)&Usp[(wc*32 + n*16 + lo)*40 + hi*8];
        }
        #pragma unroll
        for (int m = 0; m < 2; ++m)
            #pragma unroll
            for (int n = 0; n < 2; ++n) {
                ag[m][n] = __builtin_amdgcn_mfma_f32_16x16x32_f16(aF[m], gF[n], ag[m][n], 0, 0, 0);
                au[m][n] = __builtin_amdgcn_mfma_f32_16x16x32_f16(aF[m], uF[n], au[m][n], 0, 0, 0);
            }
        if (more) {
            short* Asn = As + (p ^ 1) * (64*40);
            short* Gsn = Gs + (p ^ 1) * (64*40);
            short* Usn = Us + (p ^ 1) * (64*40);
            *(s16x8*)&Asn[srow*40 + scol] = a0;
            *(s16x8*)&Gsn[srow*40 + scol] = g0;
            *(s16x8*)&Usn[srow*40 + scol] = u0;
        }
        __syncthreads();
        p ^= 1;
    }
    #pragma unroll
    for (int m = 0; m < 2; ++m)
        #pragma unroll
        for (int n = 0; n < 2; ++n)
            #pragma unroll
            for (int r = 0; r < 4; ++r) {
                int slot = m0 + wr*32 + m*16 + hi*4 + r;
                if (slot >= ne) continue;
                float g = ag[m][n][r], u = au[m][n][r];
                float a = g * (1.0f / (1.0f + __expf(-g))) * u;
                abh[((size_t)e * S_LEN + slot) * FF + f0 + wc*32 + n*16 + lo] = f2h(a);
            }
}

// ------- MoE mlp2 (fp16, 64-row tile, dbuf, split-K over FF): h += wt*(a@w2^T) -------
__global__ __launch_bounds__(256) void moe_mlp2_h16(const short* __restrict__ abh,
        const short* __restrict__ W2h,
        const int* __restrict__ cnt, const int* __restrict__ idx,
        const float* __restrict__ wt, float* __restrict__ hbuf) {
    int e = blockIdx.z >> 1;
    int ks = blockIdx.z & 1;
    int ne = cnt[e];
    int m0 = blockIdx.y * 64;
    if (m0 >= ne) return;
    int n0 = blockIdx.x * 128;
    const int koff = ks * (FF / 2);
    __shared__ __align__(16) short As[2*64*40], Bs[2*128*40];
    const int tid = threadIdx.x;
    const int lane = tid & 63, lo = lane & 15, hi = lane >> 4;
    const int wid = tid >> 6, wr = wid >> 1, wc = wid & 1;
    const int srow = tid >> 2, scol = (tid & 3) * 8;
    f32x4 acc[2][4];
    #pragma unroll
    for (int m = 0; m < 2; ++m)
        #pragma unroll
        for (int n = 0; n < 4; ++n) { acc[m][n][0]=0.f; acc[m][n][1]=0.f; acc[m][n][2]=0.f; acc[m][n][3]=0.f; }
    gemm64_core(abh + ((size_t)e*S_LEN + m0 + srow)*FF + koff + scol,
                W2h + ((size_t)e*HID + n0 + srow)*FF + koff + scol,
                W2h + ((size_t)e*HID + n0 + 64 + srow)*FF + koff + scol,
                FF / 2, tid, As, Bs, acc);
    #pragma unroll
    for (int m = 0; m < 2; ++m) {
        #pragma unroll
        for (int r = 0; r < 4; ++r) {
            int slot = m0 + wr*32 + m*16 + hi*4 + r;
            if (slot >= ne) continue;
            int tok = idx[e * S_LEN + slot];
            float wv = wt[e * S_LEN + slot];
            #pragma unroll
            for (int n = 0; n < 4; ++n)
                atomicAdd(&hbuf[(size_t)tok * HID + n0 + wc*64 + n*16 + lo], acc[m][n][r] * wv);
        }
    }
}

extern "C" void kernel_launch(void* const* d_in, const int* in_sizes, int n_in,
                              void* d_out, int out_size, void* d_ws, size_t ws_size,
                              hipStream_t stream) {
    const float* emb = (const float*)d_in[0];
    const float* ln1 = (const float*)d_in[1];
    const float* ln2 = (const float*)d_in[2];
    const float* fln = (const float*)d_in[3];
    const float* qw  = (const float*)d_in[4];
    const float* kw  = (const float*)d_in[5];
    const float* vw  = (const float*)d_in[6];
    const float* ow  = (const float*)d_in[7];
    const float* gw  = (const float*)d_in[8];
    const float* w1  = (const float*)d_in[9];
    const float* w2  = (const float*)d_in[10];
    const float* w3  = (const float*)d_in[11];

    float* ws   = (float*)d_ws;
    float* h    = ws + OFF_H;
    float* q    = ws + OFF_Q;
    float* kb   = ws + OFF_K;
    float* vb   = ws + OFF_V;
    float* cosb = ws + OFF_COS;
    float* sinb = ws + OFF_SIN;
    float* wt   = ws + OFF_WT;
    int*   cnt  = (int*)(ws + OFF_INT);
    int*   idx  = cnt + 8;
    int*   tope = (int*)(ws + OFF_TOPE);
    float2* topw = (float2*)(ws + OFF_TOPW);
    short* xh   = (short*)(ws + OFF_XH);
    short* aoh  = (short*)(ws + OFF_AOH);
    short* abh  = (short*)(ws + OFF_ABH);
    short* q16  = (short*)(ws + OFF_Q16);
    short* k16  = (short*)(ws + OFF_K16);
    short* vt16 = (short*)(ws + OFF_VT16);
    float* pO   = ws + OFF_PO;
    float* pm   = ws + OFF_PM;
    float* pl   = ws + OFF_PL;
    short* WC   = (short*)(ws + OFF_WCVT);

    short* sq = WC;
    short* sk = sq + HID*HID;
    short* sv = sk + KVH*HD*HID;
    short* so = sv + KVH*HD*HID;
    short* s1 = so + HID*HID;
    short* s3 = s1 + (size_t)NE*FF*HID;
    short* s2 = s3 + (size_t)NE*FF*HID;

    hipMemcpyAsync(h, emb, (size_t)S_LEN * HID * sizeof(float), hipMemcpyDeviceToDevice, stream);
    rope_tables_kernel<<<S_LEN * 32 / 256, 256, 0, stream>>>(cosb, sinb);

    const int n8_qo = HID*HID/8, n8_kv = KVH*HD*HID/8, n8_w = NE*FF*HID/8;

    for (int l = 0; l < NL; ++l) {
        cvt16_kernel<<<n8_qo/256, 256, 0, stream>>>(qw + (size_t)l*HID*HID, sq, n8_qo);
        cvt16_kernel<<<n8_kv/256, 256, 0, stream>>>(kw + (size_t)l*KVH*HD*HID, sk, n8_kv);
        cvt16_kernel<<<n8_kv/256, 256, 0, stream>>>(vw + (size_t)l*KVH*HD*HID, sv, n8_kv);
        cvt16_kernel<<<n8_qo/256, 256, 0, stream>>>(ow + (size_t)l*HID*HID, so, n8_qo);

        rmsnorm_h16_kernel<<<S_LEN, 256, 0, stream>>>(h, ln1 + l * HID, xh);
        qkv_h16_kernel<<<dim3(12, 32), 256, 0, stream>>>(xh, sq, sk, sv, q, kb, vb);
        rope_cvt_kernel<<<(S_LEN * NHEAD * 32) / 256, 256, 0, stream>>>(q, cosb, sinb, q16, NHEAD, S_LEN * NHEAD * 32, 0.125f);
        rope_cvt_kernel<<<(S_LEN * KVH * 32) / 256, 256, 0, stream>>>(kb, cosb, sinb, k16, KVH, S_LEN * KVH * 32, 1.0f);
        vtrans_kernel<<<dim3(S_LEN/64, KVH*HD/64), 256, 0, stream>>>(vb, vt16);
        attn_mfma_kernel<<<dim3(NSLOT, NHEAD), 256, 0, stream>>>(q16, k16, vt16, pO, pm, pl);
        attn_combine_kernel<<<dim3(32, NHEAD), 256, 0, stream>>>(pO, pm, pl, aoh);
        gemm_h16_kernel<<<dim3(8, 32), 256, 0, stream>>>(aoh, so, h, h, HID, HID);

        rmsnorm_gate_kernel<<<S_LEN, 256, 0, stream>>>(h, ln2 + l * HID, gw + (size_t)l * NE * HID,
                                                       xh, tope, topw);
        route_build_kernel<<<NE, 1024, 0, stream>>>(tope, topw, cnt, idx, wt);

        cvt16_kernel<<<n8_w/256, 256, 0, stream>>>(w1 + (size_t)l*NE*FF*HID, s1, n8_w);
        cvt16_kernel<<<n8_w/256, 256, 0, stream>>>(w3 + (size_t)l*NE*FF*HID, s3, n8_w);
        moe_mlp1_h16<<<dim3(16, 32, 8), 256, 0, stream>>>(xh, s1, s3, cnt, idx, abh);

        cvt16_kernel<<<n8_w/256, 256, 0, stream>>>(w2 + (size_t)l*NE*HID*FF, s2, n8_w);
        moe_mlp2_h16<<<dim3(8, 32, 16), 256, 0, stream>>>(abh, s2, cnt, idx, wt, h);
    }
    rmsnorm_kernel<<<S_LEN, 256, 0, stream>>>(h, fln, (float*)d_out);
}

// Round 18
// 474.633 us; speedup vs baseline: 1.2090x; 1.0241x over previous
//
#include <hip/hip_runtime.h>
#include <hip/hip_bf16.h>
#include <math.h>

#define S_LEN 2048
#define HID   1024
#define NHEAD 16
#define KVH   4
#define HD    64
#define FF    1024
#define NE    8
#define NL    2
#define NSLOT 144   // sum over qi of ceil((qi+1)/4), qi in [0,32)

// ---- workspace layout (float offsets) ----
#define OFF_H    0
#define OFF_Q    (OFF_H + S_LEN*HID)
#define OFF_K    (OFF_Q + S_LEN*HID)
#define OFF_V    (OFF_K + S_LEN*KVH*HD)
#define OFF_COS  (OFF_V + S_LEN*KVH*HD)
#define OFF_SIN  (OFF_COS + S_LEN*32)
#define OFF_WT   (OFF_SIN + S_LEN*32)
#define OFF_INT  (OFF_WT + NE*S_LEN)
#define OFF_TOPE (OFF_INT + NE*S_LEN + 16)
#define OFF_TOPW (OFF_TOPE + S_LEN)
#define OFF_XH   (OFF_TOPW + 2*S_LEN)
#define OFF_AOH  (OFF_XH + S_LEN*HID/2)
#define OFF_ABH  (OFF_AOH + S_LEN*HID/2)
#define OFF_Q16  (OFF_ABH + NE*S_LEN*FF/2)
#define OFF_K16  (OFF_Q16 + S_LEN*HID/2)
#define OFF_VT16 (OFF_K16 + S_LEN*KVH*HD/2)
#define OFF_PO   (OFF_VT16 + S_LEN*KVH*HD/2)
#define OFF_PM   (OFF_PO + NSLOT*NHEAD*64*64)
#define OFF_PL   (OFF_PM + NSLOT*NHEAD*64)
#define OFF_WCVT (OFF_PL + NSLOT*NHEAD*64)

typedef __attribute__((ext_vector_type(8))) _Float16 f16x8;
typedef __attribute__((ext_vector_type(8))) short  s16x8;
typedef __attribute__((ext_vector_type(4))) float  f32x4;

__device__ __forceinline__ short f2h(float f) {
    union { _Float16 h; short s; } u;
    u.h = (_Float16)f;
    return u.s;
}

__device__ __forceinline__ s16x8 cvt8(float4 a, float4 b) {
    s16x8 w;
    w[0]=f2h(a.x); w[1]=f2h(a.y); w[2]=f2h(a.z); w[3]=f2h(a.w);
    w[4]=f2h(b.x); w[5]=f2h(b.y); w[6]=f2h(b.z); w[7]=f2h(b.w);
    return w;
}

// ---------------- fp32 -> fp16 convert ----------------
__global__ __launch_bounds__(256) void cvt16_kernel(const float* __restrict__ src,
                                                    short* __restrict__ dst, int n8) {
    int gid = blockIdx.x * 256 + threadIdx.x;
    if (gid >= n8) return;
    const float4* s = (const float4*)src + (size_t)gid * 2;
    *(s16x8*)(dst + (size_t)gid * 8) = cvt8(s[0], s[1]);
}

// ---------------- RoPE tables ----------------
__global__ void rope_tables_kernel(float* __restrict__ cosb, float* __restrict__ sinb) {
    int gid = blockIdx.x * 256 + threadIdx.x;
    int t = gid >> 5, i = gid & 31;
    float invf = powf(1.0e6f, -(float)i / 32.0f);
    float ang = (float)t * invf;
    cosb[gid] = cosf(ang);
    sinb[gid] = sinf(ang);
}

// ---------------- RMSNorm -> fp16 only ----------------
__global__ __launch_bounds__(256) void rmsnorm_h16_kernel(const float* __restrict__ x,
                                                          const float* __restrict__ w,
                                                          short* __restrict__ oh) {
    int row = blockIdx.x;
    const float4* xr = (const float4*)(x + (size_t)row * HID);
    float4 xv = xr[threadIdx.x];
    float ss = xv.x*xv.x + xv.y*xv.y + xv.z*xv.z + xv.w*xv.w;
    for (int off = 32; off; off >>= 1) ss += __shfl_xor(ss, off);
    __shared__ float sred[4];
    if ((threadIdx.x & 63) == 0) sred[threadIdx.x >> 6] = ss;
    __syncthreads();
    float tot = sred[0] + sred[1] + sred[2] + sred[3];
    float scale = rsqrtf(tot * (1.0f / (float)HID) + 1e-5f);
    float4 wv = ((const float4*)w)[threadIdx.x];
    float4 o;
    o.x = xv.x * scale * wv.x; o.y = xv.y * scale * wv.y;
    o.z = xv.z * scale * wv.z; o.w = xv.w * scale * wv.w;
    union { short s[4]; float2 f2; } hh;
    hh.s[0]=f2h(o.x); hh.s[1]=f2h(o.y); hh.s[2]=f2h(o.z); hh.s[3]=f2h(o.w);
    ((float2*)(oh + (size_t)row * HID))[threadIdx.x] = hh.f2;
}

// ---------------- RMSNorm + gate top-2 (NO atomics) ----------------
__global__ __launch_bounds__(256) void rmsnorm_gate_kernel(const float* __restrict__ x,
                                                           const float* __restrict__ w,
                                                           const float* __restrict__ gw,
                                                           short* __restrict__ oh,
                                                           int* __restrict__ tope,
                                                           float2* __restrict__ topw) {
    int row = blockIdx.x;
    const float4* xr = (const float4*)(x + (size_t)row * HID);
    float4 xv = xr[threadIdx.x];
    float ss = xv.x*xv.x + xv.y*xv.y + xv.z*xv.z + xv.w*xv.w;
    for (int off = 32; off; off >>= 1) ss += __shfl_xor(ss, off);
    __shared__ float sred[4];
    __shared__ float gred[4][NE];
    if ((threadIdx.x & 63) == 0) sred[threadIdx.x >> 6] = ss;
    __syncthreads();
    float tot = sred[0] + sred[1] + sred[2] + sred[3];
    float scale = rsqrtf(tot * (1.0f / (float)HID) + 1e-5f);
    float4 wv = ((const float4*)w)[threadIdx.x];
    float4 o;
    o.x = xv.x * scale * wv.x; o.y = xv.y * scale * wv.y;
    o.z = xv.z * scale * wv.z; o.w = xv.w * scale * wv.w;
    union { short s[4]; float2 f2; } hh;
    hh.s[0]=f2h(o.x); hh.s[1]=f2h(o.y); hh.s[2]=f2h(o.z); hh.s[3]=f2h(o.w);
    ((float2*)(oh + (size_t)row * HID))[threadIdx.x] = hh.f2;
    const float4* gr = (const float4*)gw;
    float acc[NE];
    #pragma unroll
    for (int e = 0; e < NE; ++e) {
        float4 g4 = gr[e * 256 + threadIdx.x];
        acc[e] = o.x*g4.x + o.y*g4.y + o.z*g4.z + o.w*g4.w;
    }
    #pragma unroll
    for (int e = 0; e < NE; ++e)
        for (int off = 32; off; off >>= 1) acc[e] += __shfl_xor(acc[e], off);
    if ((threadIdx.x & 63) == 0) {
        #pragma unroll
        for (int e = 0; e < NE; ++e) gred[threadIdx.x >> 6][e] = acc[e];
    }
    __syncthreads();
    if (threadIdx.x == 0) {
        float lg[NE];
        #pragma unroll
        for (int e = 0; e < NE; ++e)
            lg[e] = gred[0][e] + gred[1][e] + gred[2][e] + gred[3][e];
        float mx = lg[0];
        #pragma unroll
        for (int e = 1; e < NE; ++e) mx = fmaxf(mx, lg[e]);
        float p[NE];
        #pragma unroll
        for (int e = 0; e < NE; ++e) p[e] = __expf(lg[e] - mx);
        int i0 = 0;
        #pragma unroll
        for (int e = 1; e < NE; ++e) if (p[e] > p[i0]) i0 = e;
        int i1 = -1;
        #pragma unroll
        for (int e = 0; e < NE; ++e) if (e != i0 && (i1 < 0 || p[e] > p[i1])) i1 = e;
        float w0 = p[i0], w1 = p[i1];
        float inv = 1.0f / (w0 + w1);
        tope[row] = i0 | (i1 << 8);
        topw[row] = make_float2(w0 * inv, w1 * inv);
    }
}

// ---------------- build per-expert token lists (ballot prefix-scan, no atomics) ----------
__global__ __launch_bounds__(1024) void route_build_kernel(const int* __restrict__ tope,
                                                           const float2* __restrict__ topw,
                                                           int* __restrict__ cnt,
                                                           int* __restrict__ idx,
                                                           float* __restrict__ wt) {
    const int e = blockIdx.x;
    const int lane = threadIdx.x & 63, wv = threadIdx.x >> 6;
    __shared__ int wtot[16];
    __shared__ int sbase;
    if (threadIdx.x == 0) sbase = 0;
    __syncthreads();
    for (int t0 = 0; t0 < S_LEN; t0 += 1024) {
        int t = t0 + threadIdx.x;
        int pk = tope[t];
        int e0 = pk & 0xff, e1 = (pk >> 8) & 0xff;
        bool sel = (e0 == e) || (e1 == e);
        unsigned long long mask = __ballot(sel);
        int prefix = __popcll(mask & ((1ULL << lane) - 1ULL));
        if (lane == 0) wtot[wv] = __popcll(mask);
        __syncthreads();
        if (sel) {
            int off = sbase;
            for (int i = 0; i < wv; ++i) off += wtot[i];
            float2 wpair = topw[t];
            float wsel = (e0 == e) ? wpair.x : wpair.y;
            int slot = off + prefix;
            idx[e * S_LEN + slot] = t;
            wt[e * S_LEN + slot] = wsel;
        }
        __syncthreads();
        if (threadIdx.x == 0) {
            int s = 0;
            #pragma unroll
            for (int i = 0; i < 16; ++i) s += wtot[i];
            sbase += s;
        }
    }
    __syncthreads();
    if (threadIdx.x == 0) cnt[e] = sbase;
}

// plain rmsnorm for final output (fp32)
__global__ __launch_bounds__(256) void rmsnorm_kernel(const float* __restrict__ x,
                                                      const float* __restrict__ w,
                                                      float* __restrict__ out) {
    int row = blockIdx.x;
    const float4* xr = (const float4*)(x + (size_t)row * HID);
    float4 xv = xr[threadIdx.x];
    float ss = xv.x*xv.x + xv.y*xv.y + xv.z*xv.z + xv.w*xv.w;
    for (int off = 32; off; off >>= 1) ss += __shfl_xor(ss, off);
    __shared__ float sred[4];
    if ((threadIdx.x & 63) == 0) sred[threadIdx.x >> 6] = ss;
    __syncthreads();
    float tot = sred[0] + sred[1] + sred[2] + sred[3];
    float scale = rsqrtf(tot * (1.0f / (float)HID) + 1e-5f);
    float4 wv = ((const float4*)w)[threadIdx.x];
    float4 o;
    o.x = xv.x * scale * wv.x; o.y = xv.y * scale * wv.y;
    o.z = xv.z * scale * wv.z; o.w = xv.w * scale * wv.w;
    ((float4*)(out + (size_t)row * HID))[threadIdx.x] = o;
}

// ---------------- RoPE apply + fp16 convert (q scaled by 1/8, k unscaled) ------------
__global__ void rope_cvt_kernel(const float* __restrict__ p, const float* __restrict__ cosb,
                                const float* __restrict__ sinb, short* __restrict__ o16,
                                int nh, int total, float qscale) {
    int gid = blockIdx.x * 256 + threadIdx.x;
    if (gid >= total) return;
    int per = nh * 32;
    int t = gid / per, r = gid % per;
    int hh = r >> 5, i = r & 31;
    float c = cosb[t*32 + i], s = sinb[t*32 + i];
    const float* base = p + (size_t)t * (nh * HD) + hh * HD + i;
    float a = base[0], b = base[32];
    short* ob = o16 + (size_t)t * (nh * HD) + hh * HD + i;
    ob[0]  = f2h((a * c - b * s) * qscale);
    ob[32] = f2h((b * c + a * s) * qscale);
}

// ---------------- V transpose + fp16 ----------------
__global__ __launch_bounds__(256) void vtrans_kernel(const float* __restrict__ vb,
                                                     short* __restrict__ vt16) {
    __shared__ float tile[64][65];
    const int t0 = blockIdx.x * 64, d0 = blockIdx.y * 64;
    const int tr = threadIdx.x >> 2;
    const int dc = (threadIdx.x & 3) * 16;
    const float4* src = (const float4*)(vb + (size_t)(t0 + tr) * (KVH*HD) + d0 + dc);
    float4 v0 = src[0], v1 = src[1], v2 = src[2], v3 = src[3];
    tile[tr][dc+ 0]=v0.x; tile[tr][dc+ 1]=v0.y; tile[tr][dc+ 2]=v0.z; tile[tr][dc+ 3]=v0.w;
    tile[tr][dc+ 4]=v1.x; tile[tr][dc+ 5]=v1.y; tile[tr][dc+ 6]=v1.z; tile[tr][dc+ 7]=v1.w;
    tile[tr][dc+ 8]=v2.x; tile[tr][dc+ 9]=v2.y; tile[tr][dc+10]=v2.z; tile[tr][dc+11]=v2.w;
    tile[tr][dc+12]=v3.x; tile[tr][dc+13]=v3.y; tile[tr][dc+14]=v3.z; tile[tr][dc+15]=v3.w;
    __syncthreads();
    const int dr = threadIdx.x >> 2;
    const int tc = (threadIdx.x & 3) * 16;
    s16x8 w0, w1;
    #pragma unroll
    for (int i = 0; i < 8; ++i) {
        w0[i] = f2h(tile[tc + i][dr]);
        w1[i] = f2h(tile[tc + 8 + i][dr]);
    }
    short* dst = vt16 + (size_t)(d0 + dr) * S_LEN + t0 + tc;
    *(s16x8*)dst = w0;
    *(s16x8*)(dst + 8) = w1;
}

// ------ fp16 64x128 GEMM core: dbuf LDS, 2-deep register pipeline, 1 barrier/step ------
__device__ __forceinline__ void gemm64_core(
        const short* pA0, const short* pB0, const short* pB1,
        int Kd, int tid, short* As, short* Bs, f32x4 (&acc)[2][4]) {
    const int lane = tid & 63, lo = lane & 15, hi = lane >> 4;
    const int wid = tid >> 6, wr = wid >> 1, wc = wid & 1;
    const int srow = tid >> 2, scol = (tid & 3) * 8;
    const int aoff = srow*40 + scol;
    const int boff0 = srow*40 + scol, boff1 = (64+srow)*40 + scol;

    s16x8 a0_, b00_, b10_;   // register set 0
    s16x8 a1_, b01_, b11_;   // register set 1

    // tile 0 -> LDS buf0 directly
    a0_ = *(const s16x8*)pA0; b00_ = *(const s16x8*)pB0; b10_ = *(const s16x8*)pB1;
    *(s16x8*)&As[aoff]  = a0_;
    *(s16x8*)&Bs[boff0] = b00_;
    *(s16x8*)&Bs[boff1] = b10_;
    // tile 1 -> set0, tile 2 -> set1
    if (32 < Kd) { a0_ = *(const s16x8*)(pA0+32); b00_ = *(const s16x8*)(pB0+32); b10_ = *(const s16x8*)(pB1+32); }
    if (64 < Kd) { a1_ = *(const s16x8*)(pA0+64); b01_ = *(const s16x8*)(pB0+64); b11_ = *(const s16x8*)(pB1+64); }
    __syncthreads();
    int p = 0;
    for (int k0 = 0; k0 < Kd; k0 += 64) {
        // ---- sub-iter A: compute tile k0; write tile k0+32 (set0); load k0+96 -> set0
        {
            if (k0 + 32 < Kd) {
                short* Asn = As + (p ^ 1) * (64*40);
                short* Bsn = Bs + (p ^ 1) * (128*40);
                *(s16x8*)&Asn[aoff]  = a0_;
                *(s16x8*)&Bsn[boff0] = b00_;
                *(s16x8*)&Bsn[boff1] = b10_;
            }
            if (k0 + 96 < Kd) {
                a0_  = *(const s16x8*)(pA0 + k0 + 96);
                b00_ = *(const s16x8*)(pB0 + k0 + 96);
                b10_ = *(const s16x8*)(pB1 + k0 + 96);
            }
            const short* Asp = As + p * (64*40);
            const short* Bsp = Bs + p * (128*40);
            f16x8 aF[2], bF[4];
            #pragma unroll
            for (int m = 0; m < 2; ++m) aF[m] = *(const f16x8*)&Asp[(wr*32 + m*16 + lo)*40 + hi*8];
            #pragma unroll
            for (int n = 0; n < 4; ++n) bF[n] = *(const f16x8*)&Bsp[(wc*64 + n*16 + lo)*40 + hi*8];
            #pragma unroll
            for (int m = 0; m < 2; ++m)
                #pragma unroll
                for (int n = 0; n < 4; ++n)
                    acc[m][n] = __builtin_amdgcn_mfma_f32_16x16x32_f16(aF[m], bF[n], acc[m][n], 0, 0, 0);
            __syncthreads();
            p ^= 1;
        }
        // ---- sub-iter B: compute tile k0+32; write tile k0+64 (set1); load k0+128 -> set1
        if (k0 + 32 < Kd) {
            if (k0 + 64 < Kd) {
                short* Asn = As + (p ^ 1) * (64*40);
                short* Bsn = Bs + (p ^ 1) * (128*40);
                *(s16x8*)&Asn[aoff]  = a1_;
                *(s16x8*)&Bsn[boff0] = b01_;
                *(s16x8*)&Bsn[boff1] = b11_;
            }
            if (k0 + 128 < Kd) {
                a1_  = *(const s16x8*)(pA0 + k0 + 128);
                b01_ = *(const s16x8*)(pB0 + k0 + 128);
                b11_ = *(const s16x8*)(pB1 + k0 + 128);
            }
            const short* Asp = As + p * (64*40);
            const short* Bsp = Bs + p * (128*40);
            f16x8 aF[2], bF[4];
            #pragma unroll
            for (int m = 0; m < 2; ++m) aF[m] = *(const f16x8*)&Asp[(wr*32 + m*16 + lo)*40 + hi*8];
            #pragma unroll
            for (int n = 0; n < 4; ++n) bF[n] = *(const f16x8*)&Bsp[(wc*64 + n*16 + lo)*40 + hi*8];
            #pragma unroll
            for (int m = 0; m < 2; ++m)
                #pragma unroll
                for (int n = 0; n < 4; ++n)
                    acc[m][n] = __builtin_amdgcn_mfma_f32_16x16x32_f16(aF[m], bF[n], acc[m][n], 0, 0, 0);
            __syncthreads();
            p ^= 1;
        }
    }
}

// ---------------- generic fp16 GEMM: C = A@B^T (+resid), 64-row tiles ----------------
__global__ __launch_bounds__(256) void gemm_h16_kernel(const short* __restrict__ Ag,
        const short* __restrict__ Bg, float* __restrict__ C,
        const float* __restrict__ resid, int N, int Kd) {
    __shared__ __align__(16) short As[2*64*40], Bs[2*128*40];
    const int tid = threadIdx.x;
    const int lane = tid & 63, lo = lane & 15, hi = lane >> 4;
    const int wid = tid >> 6, wr = wid >> 1, wc = wid & 1;
    const int m0 = blockIdx.y * 64, n0 = blockIdx.x * 128;
    const int srow = tid >> 2, scol = (tid & 3) * 8;
    f32x4 acc[2][4];
    #pragma unroll
    for (int m = 0; m < 2; ++m)
        #pragma unroll
        for (int n = 0; n < 4; ++n) { acc[m][n][0]=0.f; acc[m][n][1]=0.f; acc[m][n][2]=0.f; acc[m][n][3]=0.f; }
    gemm64_core(Ag + (size_t)(m0+srow)*Kd + scol,
                Bg + (size_t)(n0+srow)*Kd + scol, Bg + (size_t)(n0+64+srow)*Kd + scol,
                Kd, tid, As, Bs, acc);
    #pragma unroll
    for (int m = 0; m < 2; ++m)
        #pragma unroll
        for (int n = 0; n < 4; ++n)
            #pragma unroll
            for (int r = 0; r < 4; ++r) {
                int row = m0 + wr*32 + m*16 + hi*4 + r;
                int col = n0 + wc*64 + n*16 + lo;
                float val = acc[m][n][r];
                if (resid) val += resid[(size_t)row * N + col];
                C[(size_t)row * N + col] = val;
            }
}

// ---------------- fused QKV GEMM (fp16, 64-row tiles) ----------------
__global__ __launch_bounds__(256) void qkv_h16_kernel(const short* __restrict__ Xh,
        const short* __restrict__ qw16, const short* __restrict__ kw16,
        const short* __restrict__ vw16,
        float* __restrict__ qo, float* __restrict__ ko, float* __restrict__ vo) {
    __shared__ __align__(16) short As[2*64*40], Bs[2*128*40];
    const int bx = blockIdx.x;
    const short* Bp; float* Cp; int Nc, n0;
    if (bx < 8)       { Bp = qw16; Cp = qo; Nc = 1024; n0 = bx * 128; }
    else if (bx < 10) { Bp = kw16; Cp = ko; Nc = 256;  n0 = (bx - 8) * 128; }
    else              { Bp = vw16; Cp = vo; Nc = 256;  n0 = (bx - 10) * 128; }
    const int tid = threadIdx.x;
    const int lane = tid & 63, lo = lane & 15, hi = lane >> 4;
    const int wid = tid >> 6, wr = wid >> 1, wc = wid & 1;
    const int m0 = blockIdx.y * 64;
    const int srow = tid >> 2, scol = (tid & 3) * 8;
    f32x4 acc[2][4];
    #pragma unroll
    for (int m = 0; m < 2; ++m)
        #pragma unroll
        for (int n = 0; n < 4; ++n) { acc[m][n][0]=0.f; acc[m][n][1]=0.f; acc[m][n][2]=0.f; acc[m][n][3]=0.f; }
    gemm64_core(Xh + (size_t)(m0+srow)*HID + scol,
                Bp + (size_t)(n0+srow)*HID + scol, Bp + (size_t)(n0+64+srow)*HID + scol,
                HID, tid, As, Bs, acc);
    #pragma unroll
    for (int m = 0; m < 2; ++m)
        #pragma unroll
        for (int n = 0; n < 4; ++n)
            #pragma unroll
            for (int r = 0; r < 4; ++r) {
                int row = m0 + wr*32 + m*16 + hi*4 + r;
                int col = n0 + wc*64 + n*16 + lo;
                Cp[(size_t)row * Nc + col] = acc[m][n][r];
            }
}

// -------- split-K fp16 flash attention (LDS-staged, uniform 4-tile chunks) --------
__global__ __launch_bounds__(256) void attn_mfma_kernel(const short* __restrict__ q16,
                                                        const short* __restrict__ k16,
                                                        const short* __restrict__ vt16,
                                                        float* __restrict__ pO,
                                                        float* __restrict__ pm,
                                                        float* __restrict__ pl) {
    __shared__ __align__(16) short Ks[64][72];
    __shared__ __align__(16) short Vt[64][72];
    __shared__ __align__(16) short Ps[4][16][72];
    const int wid = threadIdx.x >> 6, lane = threadIdx.x & 63;
    const int lo = lane & 15, hi = lane >> 4;
    const int head = blockIdx.y;
    const int s = (NSLOT - 1) - blockIdx.x;   // long chunks dispatched first
    int g = 0, base = 0;
    while (g < 7 && s >= base + 4 * (g + 1)) { base += 4 * (g + 1); ++g; }
    const int tt = s - base;
    const int qi = 4 * g + tt / (g + 1);
    const int c  = tt % (g + 1);
    const int t_beg = c * 4;
    const int t_end = min(t_beg + 4, qi + 1);
    const int q0 = qi * 64;
    const int kvh = head >> 2;

    f16x8 qf[2];
    {
        const short* qr = q16 + (size_t)(q0 + wid*16 + lo) * HID + head*HD;
        qf[0] = *(const f16x8*)(qr + hi*8);
        qf[1] = *(const f16x8*)(qr + 32 + hi*8);
    }

    f32x4 acc[4];
    float m[4], l[4];
    #pragma unroll
    for (int r = 0; r < 4; ++r) {
        m[r] = -1e30f; l[r] = 0.f;
        acc[0][r] = 0.f; acc[1][r] = 0.f; acc[2][r] = 0.f; acc[3][r] = 0.f;
    }

    const int skey = threadIdx.x >> 2;
    const int sdg  = (threadIdx.x & 3) * 16;

    s16x8 ka0, ka1, va0, va1;
    {
        const short* kr = k16 + (size_t)(t_beg*64 + skey)*(KVH*HD) + kvh*HD + sdg;
        ka0 = *(const s16x8*)kr; ka1 = *(const s16x8*)(kr + 8);
        const short* vr = vt16 + (size_t)(kvh*HD + skey)*S_LEN + t_beg*64 + sdg;
        va0 = *(const s16x8*)vr; va1 = *(const s16x8*)(vr + 8);
    }

    for (int t = t_beg; t < t_end; ++t) {
        __syncthreads();
        *(s16x8*)&Ks[skey][sdg]     = ka0;
        *(s16x8*)&Ks[skey][sdg + 8] = ka1;
        *(s16x8*)&Vt[skey][sdg]     = va0;
        *(s16x8*)&Vt[skey][sdg + 8] = va1;
        __syncthreads();
        if (t + 1 < t_end) {
            const short* kr = k16 + (size_t)((t+1)*64 + skey)*(KVH*HD) + kvh*HD + sdg;
            ka0 = *(const s16x8*)kr; ka1 = *(const s16x8*)(kr + 8);
            const short* vr = vt16 + (size_t)(kvh*HD + skey)*S_LEN + (t+1)*64 + sdg;
            va0 = *(const s16x8*)vr; va1 = *(const s16x8*)(vr + 8);
        }
        const int k0 = t * 64;
        f32x4 sc[4];
        #pragma unroll
        for (int f = 0; f < 4; ++f) {
            f32x4 sf; sf[0]=0.f; sf[1]=0.f; sf[2]=0.f; sf[3]=0.f;
            f16x8 bk0 = *(const f16x8*)&Ks[f*16 + lo][hi*8];
            sf = __builtin_amdgcn_mfma_f32_16x16x32_f16(qf[0], bk0, sf, 0, 0, 0);
            f16x8 bk1 = *(const f16x8*)&Ks[f*16 + lo][32 + hi*8];
            sf = __builtin_amdgcn_mfma_f32_16x16x32_f16(qf[1], bk1, sf, 0, 0, 0);
            sc[f] = sf;
        }
        if (t == qi) {
            int qrow = q0 + wid*16 + hi*4;
            #pragma unroll
            for (int f = 0; f < 4; ++f)
                #pragma unroll
                for (int r = 0; r < 4; ++r)
                    if (k0 + f*16 + lo > qrow + r) sc[f][r] = -1e30f;
        }
        float pmax[4];
        #pragma unroll
        for (int r = 0; r < 4; ++r) {
            float x = fmaxf(fmaxf(sc[0][r], sc[1][r]), fmaxf(sc[2][r], sc[3][r]));
            x = fmaxf(x, __shfl_xor(x, 1));
            x = fmaxf(x, __shfl_xor(x, 2));
            x = fmaxf(x, __shfl_xor(x, 4));
            x = fmaxf(x, __shfl_xor(x, 8));
            pmax[r] = x;
        }
        bool ok = (pmax[0] <= m[0] + 8.f) && (pmax[1] <= m[1] + 8.f) &&
                  (pmax[2] <= m[2] + 8.f) && (pmax[3] <= m[3] + 8.f);
        if (!__all(ok)) {
            #pragma unroll
            for (int r = 0; r < 4; ++r) {
                float mn = fmaxf(m[r], pmax[r]);
                float sc_ = __expf(m[r] - mn);
                m[r] = mn;
                l[r] *= sc_;
                acc[0][r] *= sc_; acc[1][r] *= sc_;
                acc[2][r] *= sc_; acc[3][r] *= sc_;
            }
        }
        float rs[4] = {0.f, 0.f, 0.f, 0.f};
        #pragma unroll
        for (int f = 0; f < 4; ++f)
            #pragma unroll
            for (int r = 0; r < 4; ++r) {
                float e = __expf(sc[f][r] - m[r]);
                rs[r] += e;
                Ps[wid][hi*4 + r][f*16 + lo] = f2h(e);
            }
        #pragma unroll
        for (int r = 0; r < 4; ++r) {
            float x = rs[r];
            x += __shfl_xor(x, 1); x += __shfl_xor(x, 2);
            x += __shfl_xor(x, 4); x += __shfl_xor(x, 8);
            l[r] += x;
        }
        asm volatile("s_waitcnt lgkmcnt(0)" ::: "memory");
        __builtin_amdgcn_sched_barrier(0);
        f16x8 pa0 = *(const f16x8*)&Ps[wid][lo][hi*8];
        f16x8 pa1 = *(const f16x8*)&Ps[wid][lo][32 + hi*8];
        #pragma unroll
        for (int f = 0; f < 4; ++f) {
            f32x4 o = acc[f];
            f16x8 v0 = *(const f16x8*)&Vt[f*16 + lo][hi*8];
            o = __builtin_amdgcn_mfma_f32_16x16x32_f16(pa0, v0, o, 0, 0, 0);
            f16x8 v1 = *(const f16x8*)&Vt[f*16 + lo][32 + hi*8];
            o = __builtin_amdgcn_mfma_f32_16x16x32_f16(pa1, v1, o, 0, 0, 0);
            acc[f] = o;
        }
    }
    const int pbase = head * NSLOT + s;
    float* po = pO + (size_t)pbase * 4096;
    #pragma unroll
    for (int r = 0; r < 4; ++r)
        #pragma unroll
        for (int f = 0; f < 4; ++f)
            po[(wid*16 + hi*4 + r) * 64 + f*16 + lo] = acc[f][r];
    if (lo == 0) {
        #pragma unroll
        for (int r = 0; r < 4; ++r) {
            pm[pbase*64 + wid*16 + hi*4 + r] = m[r];
            pl[pbase*64 + wid*16 + hi*4 + r] = l[r];
        }
    }
}

// ---------------- combine partials (up to 8 chunks) -> fp16 attention output ----------
__global__ __launch_bounds__(256) void attn_combine_kernel(const float* __restrict__ pO,
        const float* __restrict__ pm, const float* __restrict__ pl,
        short* __restrict__ aoh) {
    const int qi = blockIdx.x, head = blockIdx.y;
    const int g = qi >> 2, rr = qi & 3;
    const int nch = g + 1;
    const int sbase = (g + 1) * (2 * g + rr);
    const int row = threadIdx.x >> 2;
    const int d0 = (threadIdx.x & 3) * 16;
    float mv[8], lv[8];
    float mx = -1e30f;
    #pragma unroll
    for (int cd = 0; cd < 8; ++cd) {
        if (cd < nch) {
            int p = head * NSLOT + sbase + cd;
            mv[cd] = pm[p * 64 + row];
            lv[cd] = pl[p * 64 + row];
            mx = fmaxf(mx, mv[cd]);
        } else { mv[cd] = -1e30f; lv[cd] = 0.f; }
    }
    float w[8];
    float lsum = 0.f;
    #pragma unroll
    for (int cd = 0; cd < 8; ++cd) {
        w[cd] = (cd < nch) ? __expf(mv[cd] - mx) : 0.f;
        lsum += w[cd] * lv[cd];
    }
    float inv = 1.0f / lsum;
    float o[16] = {};
    #pragma unroll
    for (int cd = 0; cd < 8; ++cd) {
        if (cd < nch) {
            const float4* po = (const float4*)(pO + ((size_t)(head * NSLOT + sbase + cd)) * 4096 + row * 64 + d0);
            float wc = w[cd] * inv;
            #pragma unroll
            for (int j = 0; j < 4; ++j) {
                float4 vv = po[j];
                o[j*4+0] += wc * vv.x; o[j*4+1] += wc * vv.y;
                o[j*4+2] += wc * vv.z; o[j*4+3] += wc * vv.w;
            }
        }
    }
    size_t outb = (size_t)(qi * 64 + row) * HID + head * HD + d0;
    s16x8 w0, w1;
    #pragma unroll
    for (int i = 0; i < 8; ++i) { w0[i] = f2h(o[i]); w1[i] = f2h(o[8+i]); }
    *(s16x8*)(aoh + outb) = w0;
    *(s16x8*)(aoh + outb + 8) = w1;
}

// ---- MoE mlp1 (fp16, 64x64 tile, dbuf LDS + 2-deep register pipeline) ----
__global__ __launch_bounds__(256) void moe_mlp1_h16(const short* __restrict__ Xh,
        const short* __restrict__ W1h, const short* __restrict__ W3h,
        const int* __restrict__ cnt, const int* __restrict__ idx,
        short* __restrict__ abh) {
    int e = blockIdx.z;
    int ne = cnt[e];
    int m0 = blockIdx.y * 64;
    if (m0 >= ne) return;
    int f0 = blockIdx.x * 64;
    __shared__ __align__(16) short As[2*64*40];
    __shared__ __align__(16) short Gs[2*64*40], Us[2*64*40];
    __shared__ int rows[64];
    const int tid = threadIdx.x;
    if (tid < 64) {
        int slot = m0 + tid;
        rows[tid] = (slot < ne) ? idx[e * S_LEN + slot] : 0;
    }
    __syncthreads();
    const int lane = tid & 63, lo = lane & 15, hi = lane >> 4;
    const int wid = tid >> 6, wr = wid >> 1, wc = wid & 1;
    const int srow = tid >> 2, scol = (tid & 3) * 8;
    const int soff = srow*40 + scol;
    const short* pX0 = Xh + (size_t)rows[srow] * HID + scol;
    const short* p1 = W1h + ((size_t)e * FF + f0 + srow) * HID + scol;
    const short* p3 = W3h + ((size_t)e * FF + f0 + srow) * HID + scol;

    f32x4 ag[2][2], au[2][2];
    #pragma unroll
    for (int m = 0; m < 2; ++m)
        #pragma unroll
        for (int n = 0; n < 2; ++n) {
            ag[m][n][0]=0.f; ag[m][n][1]=0.f; ag[m][n][2]=0.f; ag[m][n][3]=0.f;
            au[m][n][0]=0.f; au[m][n][1]=0.f; au[m][n][2]=0.f; au[m][n][3]=0.f;
        }

    s16x8 a0_, g0_, u0_;   // set 0
    s16x8 a1_, g1_, u1_;   // set 1
    a0_ = *(const s16x8*)pX0; g0_ = *(const s16x8*)p1; u0_ = *(const s16x8*)p3;
    *(s16x8*)&As[soff] = a0_;
    *(s16x8*)&Gs[soff] = g0_;
    *(s16x8*)&Us[soff] = u0_;
    a0_ = *(const s16x8*)(pX0+32); g0_ = *(const s16x8*)(p1+32); u0_ = *(const s16x8*)(p3+32);
    a1_ = *(const s16x8*)(pX0+64); g1_ = *(const s16x8*)(p1+64); u1_ = *(const s16x8*)(p3+64);
    __syncthreads();
    int p = 0;
    for (int k0 = 0; k0 < HID; k0 += 64) {
        // sub-iter A: compute tile k0; write k0+32 (set0); load k0+96 -> set0
        {
            if (k0 + 32 < HID) {
                short* Asn = As + (p ^ 1) * (64*40);
                short* Gsn = Gs + (p ^ 1) * (64*40);
                short* Usn = Us + (p ^ 1) * (64*40);
                *(s16x8*)&Asn[soff] = a0_;
                *(s16x8*)&Gsn[soff] = g0_;
                *(s16x8*)&Usn[soff] = u0_;
            }
            if (k0 + 96 < HID) {
                a0_ = *(const s16x8*)(pX0 + k0 + 96);
                g0_ = *(const s16x8*)(p1 + k0 + 96);
                u0_ = *(const s16x8*)(p3 + k0 + 96);
            }
            const short* Asp = As + p * (64*40);
            const short* Gsp = Gs + p * (64*40);
            const short* Usp = Us + p * (64*40);
            f16x8 aF[2], gF[2], uF[2];
            #pragma unroll
            for (int m = 0; m < 2; ++m) aF[m] = *(const f16x8*)&Asp[(wr*32 + m*16 + lo)*40 + hi*8];
            #pragma unroll
            for (int n = 0; n < 2; ++n) {
                gF[n] = *(const f16x8*)&Gsp[(wc*32 + n*16 + lo)*40 + hi*8];
                uF[n] = *(const f16x8*)&Usp[(wc*32 + n*16 + lo)*40 + hi*8];
            }
            #pragma unroll
            for (int m = 0; m < 2; ++m)
                #pragma unroll
                for (int n = 0; n < 2; ++n) {
                    ag[m][n] = __builtin_amdgcn_mfma_f32_16x16x32_f16(aF[m], gF[n], ag[m][n], 0, 0, 0);
                    au[m][n] = __builtin_amdgcn_mfma_f32_16x16x32_f16(aF[m], uF[n], au[m][n], 0, 0, 0);
                }
            __syncthreads();
            p ^= 1;
        }
        // sub-iter B: compute tile k0+32; write k0+64 (set1); load k0+128 -> set1
        {
            if (k0 + 64 < HID) {
                short* Asn = As + (p ^ 1) * (64*40);
                short* Gsn = Gs + (p ^ 1) * (64*40);
                short* Usn = Us + (p ^ 1) * (64*40);
                *(s16x8*)&Asn[soff] = a1_;
                *(s16x8*)&Gsn[soff] = g1_;
                *(s16x8*)&Usn[soff] = u1_;
            }
            if (k0 + 128 < HID) {
                a1_ = *(const s16x8*)(pX0 + k0 + 128);
                g1_ = *(const s16x8*)(p1 + k0 + 128);
                u1_ = *(const s16x8*)(p3 + k0 + 128);
            }
            const short* Asp = As + p * (64*40);
            const short* Gsp = Gs + p * (64*40);
            const short* Usp = Us + p * (64*40);
            f16x8 aF[2], gF[2], uF[2];
            #pragma unroll
            for (int m = 0; m < 2; ++m) aF[m] = *(const f16x8*)&Asp[(wr*32 + m*16 + lo)*40 + hi*8];
            #pragma unroll
            for (int n = 0; n < 2; ++n) {
                gF[n] = *(const f16x8*)&Gsp[(wc*32 + n*16 + lo)*40 + hi*8];
                uF[n] = *(const f16x8*)&Usp[(wc*32 + n*16 + lo)*40 + hi*8];
            }
            #pragma unroll
            for (int m = 0; m < 2; ++m)
                #pragma unroll
                for (int n = 0; n < 2; ++n) {
                    ag[m][n] = __builtin_amdgcn_mfma_f32_16x16x32_f16(aF[m], gF[n], ag[m][n], 0, 0, 0);
                    au[m][n] = __builtin_amdgcn_mfma_f32_16x16x32_f16(aF[m], uF[n], au[m][n], 0, 0, 0);
                }
            __syncthreads();
            p ^= 1;
        }
    }
    #pragma unroll
    for (int m = 0; m < 2; ++m)
        #pragma unroll
        for (int n = 0; n < 2; ++n)
            #pragma unroll
            for (int r = 0; r < 4; ++r) {
                int slot = m0 + wr*32 + m*16 + hi*4 + r;
                if (slot >= ne) continue;
                float g = ag[m][n][r], u = au[m][n][r];
                float a = g * (1.0f / (1.0f + __expf(-g))) * u;
                abh[((size_t)e * S_LEN + slot) * FF + f0 + wc*32 + n*16 + lo] = f2h(a);
            }
}

// ------- MoE mlp2 (fp16, 64-row tile, dbuf+2-deep, split-K over FF) -------
__global__ __launch_bounds__(256) void moe_mlp2_h16(const short* __restrict__ abh,
        const short* __restrict__ W2h,
        const int* __restrict__ cnt, const int* __restrict__ idx,
        const float* __restrict__ wt, float* __restrict__ hbuf) {
    int e = blockIdx.z >> 1;
    int ks = blockIdx.z & 1;
    int ne = cnt[e];
    int m0 = blockIdx.y * 64;
    if (m0 >= ne) return;
    int n0 = blockIdx.x * 128;
    const int koff = ks * (FF / 2);
    __shared__ __align__(16) short As[2*64*40], Bs[2*128*40];
    const int tid = threadIdx.x;
    const int lane = tid & 63, lo = lane & 15, hi = lane >> 4;
    const int wid = tid >> 6, wr = wid >> 1, wc = wid & 1;
    const int srow = tid >> 2, scol = (tid & 3) * 8;
    f32x4 acc[2][4];
    #pragma unroll
    for (int m = 0; m < 2; ++m)
        #pragma unroll
        for (int n = 0; n < 4; ++n) { acc[m][n][0]=0.f; acc[m][n][1]=0.f; acc[m][n][2]=0.f; acc[m][n][3]=0.f; }
    gemm64_core(abh + ((size_t)e*S_LEN + m0 + srow)*FF + koff + scol,
                W2h + ((size_t)e*HID + n0 + srow)*FF + koff + scol,
                W2h + ((size_t)e*HID + n0 + 64 + srow)*FF + koff + scol,
                FF / 2, tid, As, Bs, acc);
    #pragma unroll
    for (int m = 0; m < 2; ++m) {
        #pragma unroll
        for (int r = 0; r < 4; ++r) {
            int slot = m0 + wr*32 + m*16 + hi*4 + r;
            if (slot >= ne) continue;
            int tok = idx[e * S_LEN + slot];
            float wv = wt[e * S_LEN + slot];
            #pragma unroll
            for (int n = 0; n < 4; ++n)
                atomicAdd(&hbuf[(size_t)tok * HID + n0 + wc*64 + n*16 + lo], acc[m][n][r] * wv);
        }
    }
}

extern "C" void kernel_launch(void* const* d_in, const int* in_sizes, int n_in,
                              void* d_out, int out_size, void* d_ws, size_t ws_size,
                              hipStream_t stream) {
    const float* emb = (const float*)d_in[0];
    const float* ln1 = (const float*)d_in[1];
    const float* ln2 = (const float*)d_in[2];
    const float* fln = (const float*)d_in[3];
    const float* qw  = (const float*)d_in[4];
    const float* kw  = (const float*)d_in[5];
    const float* vw  = (const float*)d_in[6];
    const float* ow  = (const float*)d_in[7];
    const float* gw  = (const float*)d_in[8];
    const float* w1  = (const float*)d_in[9];
    const float* w2  = (const float*)d_in[10];
    const float* w3  = (const float*)d_in[11];

    float* ws   = (float*)d_ws;
    float* h    = ws + OFF_H;
    float* q    = ws + OFF_Q;
    float* kb   = ws + OFF_K;
    float* vb   = ws + OFF_V;
    float* cosb = ws + OFF_COS;
    float* sinb = ws + OFF_SIN;
    float* wt   = ws + OFF_WT;
    int*   cnt  = (int*)(ws + OFF_INT);
    int*   idx  = cnt + 8;
    int*   tope = (int*)(ws + OFF_TOPE);
    float2* topw = (float2*)(ws + OFF_TOPW);
    short* xh   = (short*)(ws + OFF_XH);
    short* aoh  = (short*)(ws + OFF_AOH);
    short* abh  = (short*)(ws + OFF_ABH);
    short* q16  = (short*)(ws + OFF_Q16);
    short* k16  = (short*)(ws + OFF_K16);
    short* vt16 = (short*)(ws + OFF_VT16);
    float* pO   = ws + OFF_PO;
    float* pm   = ws + OFF_PM;
    float* pl   = ws + OFF_PL;
    short* WC   = (short*)(ws + OFF_WCVT);

    short* sq = WC;
    short* sk = sq + HID*HID;
    short* sv = sk + KVH*HD*HID;
    short* so = sv + KVH*HD*HID;
    short* s1 = so + HID*HID;
    short* s3 = s1 + (size_t)NE*FF*HID;
    short* s2 = s3 + (size_t)NE*FF*HID;

    hipMemcpyAsync(h, emb, (size_t)S_LEN * HID * sizeof(float), hipMemcpyDeviceToDevice, stream);
    rope_tables_kernel<<<S_LEN * 32 / 256, 256, 0, stream>>>(cosb, sinb);

    const int n8_qo = HID*HID/8, n8_kv = KVH*HD*HID/8, n8_w = NE*FF*HID/8;

    for (int l = 0; l < NL; ++l) {
        cvt16_kernel<<<n8_qo/256, 256, 0, stream>>>(qw + (size_t)l*HID*HID, sq, n8_qo);
        cvt16_kernel<<<n8_kv/256, 256, 0, stream>>>(kw + (size_t)l*KVH*HD*HID, sk, n8_kv);
        cvt16_kernel<<<n8_kv/256, 256, 0, stream>>>(vw + (size_t)l*KVH*HD*HID, sv, n8_kv);
        cvt16_kernel<<<n8_qo/256, 256, 0, stream>>>(ow + (size_t)l*HID*HID, so, n8_qo);

        rmsnorm_h16_kernel<<<S_LEN, 256, 0, stream>>>(h, ln1 + l * HID, xh);
        qkv_h16_kernel<<<dim3(12, 32), 256, 0, stream>>>(xh, sq, sk, sv, q, kb, vb);
        rope_cvt_kernel<<<(S_LEN * NHEAD * 32) / 256, 256, 0, stream>>>(q, cosb, sinb, q16, NHEAD, S_LEN * NHEAD * 32, 0.125f);
        rope_cvt_kernel<<<(S_LEN * KVH * 32) / 256, 256, 0, stream>>>(kb, cosb, sinb, k16, KVH, S_LEN * KVH * 32, 1.0f);
        vtrans_kernel<<<dim3(S_LEN/64, KVH*HD/64), 256, 0, stream>>>(vb, vt16);
        attn_mfma_kernel<<<dim3(NSLOT, NHEAD), 256, 0, stream>>>(q16, k16, vt16, pO, pm, pl);
        attn_combine_kernel<<<dim3(32, NHEAD), 256, 0, stream>>>(pO, pm, pl, aoh);
        gemm_h16_kernel<<<dim3(8, 32), 256, 0, stream>>>(aoh, so, h, h, HID, HID);

        rmsnorm_gate_kernel<<<S_LEN, 256, 0, stream>>>(h, ln2 + l * HID, gw + (size_t)l * NE * HID,
                                                       xh, tope, topw);
        route_build_kernel<<<NE, 1024, 0, stream>>>(tope, topw, cnt, idx, wt);

        cvt16_kernel<<<n8_w/256, 256, 0, stream>>>(w1 + (size_t)l*NE*FF*HID, s1, n8_w);
        cvt16_kernel<<<n8_w/256, 256, 0, stream>>>(w3 + (size_t)l*NE*FF*HID, s3, n8_w);
        moe_mlp1_h16<<<dim3(16, 32, 8), 256, 0, stream>>>(xh, s1, s3, cnt, idx, abh);

        cvt16_kernel<<<n8_w/256, 256, 0, stream>>>(w2 + (size_t)l*NE*HID*FF, s2, n8_w);
        moe_mlp2_h16<<<dim3(8, 32, 16), 256, 0, stream>>>(abh, s2, cnt, idx, wt, h);
    }
    rmsnorm_kernel<<<S_LEN, 256, 0, stream>>>(h, fln, (float*)d_out);
}

// Round 19
// 464.264 us; speedup vs baseline: 1.2360x; 1.0223x over previous
//
#include <hip/hip_runtime.h>
#include <hip/hip_bf16.h>
#include <math.h>

#define S_LEN 2048
#define HID   1024
#define NHEAD 16
#define KVH   4
#define HD    64
#define FF    1024
#define NE    8
#define NL    2
#define NSLOT 144   // sum over qi of ceil((qi+1)/4), qi in [0,32)

// ---- workspace layout (float offsets) ----
#define OFF_H    0
#define OFF_Q    (OFF_H + S_LEN*HID)
#define OFF_K    (OFF_Q + S_LEN*HID)
#define OFF_V    (OFF_K + S_LEN*KVH*HD)
#define OFF_COS  (OFF_V + S_LEN*KVH*HD)
#define OFF_SIN  (OFF_COS + S_LEN*32)
#define OFF_WT   (OFF_SIN + S_LEN*32)
#define OFF_INT  (OFF_WT + NE*S_LEN)
#define OFF_TOPE (OFF_INT + NE*S_LEN + 16)
#define OFF_TOPW (OFF_TOPE + S_LEN)
#define OFF_XH   (OFF_TOPW + 2*S_LEN)
#define OFF_AOH  (OFF_XH + S_LEN*HID/2)
#define OFF_ABH  (OFF_AOH + S_LEN*HID/2)
#define OFF_Q16  (OFF_ABH + NE*S_LEN*FF/2)
#define OFF_K16  (OFF_Q16 + S_LEN*HID/2)
#define OFF_VT16 (OFF_K16 + S_LEN*KVH*HD/2)
#define OFF_PO   (OFF_VT16 + S_LEN*KVH*HD/2)
#define OFF_PM   (OFF_PO + NSLOT*NHEAD*64*64)
#define OFF_PL   (OFF_PM + NSLOT*NHEAD*64)

typedef __attribute__((ext_vector_type(8))) _Float16 f16x8;
typedef __attribute__((ext_vector_type(8))) short  s16x8;
typedef __attribute__((ext_vector_type(4))) float  f32x4;

__device__ __forceinline__ short f2h(float f) {
    union { _Float16 h; short s; } u;
    u.h = (_Float16)f;
    return u.s;
}

__device__ __forceinline__ s16x8 cvt8(float4 a, float4 b) {
    s16x8 w;
    w[0]=f2h(a.x); w[1]=f2h(a.y); w[2]=f2h(a.z); w[3]=f2h(a.w);
    w[4]=f2h(b.x); w[5]=f2h(b.y); w[6]=f2h(b.z); w[7]=f2h(b.w);
    return w;
}

// ---------------- RoPE tables ----------------
__global__ void rope_tables_kernel(float* __restrict__ cosb, float* __restrict__ sinb) {
    int gid = blockIdx.x * 256 + threadIdx.x;
    int t = gid >> 5, i = gid & 31;
    float invf = powf(1.0e6f, -(float)i / 32.0f);
    float ang = (float)t * invf;
    cosb[gid] = cosf(ang);
    sinb[gid] = sinf(ang);
}

// ---------------- RMSNorm -> fp16 only ----------------
__global__ __launch_bounds__(256) void rmsnorm_h16_kernel(const float* __restrict__ x,
                                                          const float* __restrict__ w,
                                                          short* __restrict__ oh) {
    int row = blockIdx.x;
    const float4* xr = (const float4*)(x + (size_t)row * HID);
    float4 xv = xr[threadIdx.x];
    float ss = xv.x*xv.x + xv.y*xv.y + xv.z*xv.z + xv.w*xv.w;
    for (int off = 32; off; off >>= 1) ss += __shfl_xor(ss, off);
    __shared__ float sred[4];
    if ((threadIdx.x & 63) == 0) sred[threadIdx.x >> 6] = ss;
    __syncthreads();
    float tot = sred[0] + sred[1] + sred[2] + sred[3];
    float scale = rsqrtf(tot * (1.0f / (float)HID) + 1e-5f);
    float4 wv = ((const float4*)w)[threadIdx.x];
    float4 o;
    o.x = xv.x * scale * wv.x; o.y = xv.y * scale * wv.y;
    o.z = xv.z * scale * wv.z; o.w = xv.w * scale * wv.w;
    union { short s[4]; float2 f2; } hh;
    hh.s[0]=f2h(o.x); hh.s[1]=f2h(o.y); hh.s[2]=f2h(o.z); hh.s[3]=f2h(o.w);
    ((float2*)(oh + (size_t)row * HID))[threadIdx.x] = hh.f2;
}

// ---------------- RMSNorm + gate top-2 (NO atomics) ----------------
__global__ __launch_bounds__(256) void rmsnorm_gate_kernel(const float* __restrict__ x,
                                                           const float* __restrict__ w,
                                                           const float* __restrict__ gw,
                                                           short* __restrict__ oh,
                                                           int* __restrict__ tope,
                                                           float2* __restrict__ topw) {
    int row = blockIdx.x;
    const float4* xr = (const float4*)(x + (size_t)row * HID);
    float4 xv = xr[threadIdx.x];
    float ss = xv.x*xv.x + xv.y*xv.y + xv.z*xv.z + xv.w*xv.w;
    for (int off = 32; off; off >>= 1) ss += __shfl_xor(ss, off);
    __shared__ float sred[4];
    __shared__ float gred[4][NE];
    if ((threadIdx.x & 63) == 0) sred[threadIdx.x >> 6] = ss;
    __syncthreads();
    float tot = sred[0] + sred[1] + sred[2] + sred[3];
    float scale = rsqrtf(tot * (1.0f / (float)HID) + 1e-5f);
    float4 wv = ((const float4*)w)[threadIdx.x];
    float4 o;
    o.x = xv.x * scale * wv.x; o.y = xv.y * scale * wv.y;
    o.z = xv.z * scale * wv.z; o.w = xv.w * scale * wv.w;
    union { short s[4]; float2 f2; } hh;
    hh.s[0]=f2h(o.x); hh.s[1]=f2h(o.y); hh.s[2]=f2h(o.z); hh.s[3]=f2h(o.w);
    ((float2*)(oh + (size_t)row * HID))[threadIdx.x] = hh.f2;
    const float4* gr = (const float4*)gw;
    float acc[NE];
    #pragma unroll
    for (int e = 0; e < NE; ++e) {
        float4 g4 = gr[e * 256 + threadIdx.x];
        acc[e] = o.x*g4.x + o.y*g4.y + o.z*g4.z + o.w*g4.w;
    }
    #pragma unroll
    for (int e = 0; e < NE; ++e)
        for (int off = 32; off; off >>= 1) acc[e] += __shfl_xor(acc[e], off);
    if ((threadIdx.x & 63) == 0) {
        #pragma unroll
        for (int e = 0; e < NE; ++e) gred[threadIdx.x >> 6][e] = acc[e];
    }
    __syncthreads();
    if (threadIdx.x == 0) {
        float lg[NE];
        #pragma unroll
        for (int e = 0; e < NE; ++e)
            lg[e] = gred[0][e] + gred[1][e] + gred[2][e] + gred[3][e];
        float mx = lg[0];
        #pragma unroll
        for (int e = 1; e < NE; ++e) mx = fmaxf(mx, lg[e]);
        float p[NE];
        #pragma unroll
        for (int e = 0; e < NE; ++e) p[e] = __expf(lg[e] - mx);
        int i0 = 0;
        #pragma unroll
        for (int e = 1; e < NE; ++e) if (p[e] > p[i0]) i0 = e;
        int i1 = -1;
        #pragma unroll
        for (int e = 0; e < NE; ++e) if (e != i0 && (i1 < 0 || p[e] > p[i1])) i1 = e;
        float w0 = p[i0], w1 = p[i1];
        float inv = 1.0f / (w0 + w1);
        tope[row] = i0 | (i1 << 8);
        topw[row] = make_float2(w0 * inv, w1 * inv);
    }
}

// ---------------- build per-expert token lists (ballot prefix-scan, no atomics) ----------
__global__ __launch_bounds__(1024) void route_build_kernel(const int* __restrict__ tope,
                                                           const float2* __restrict__ topw,
                                                           int* __restrict__ cnt,
                                                           int* __restrict__ idx,
                                                           float* __restrict__ wt) {
    const int e = blockIdx.x;
    const int lane = threadIdx.x & 63, wv = threadIdx.x >> 6;
    __shared__ int wtot[16];
    __shared__ int sbase;
    if (threadIdx.x == 0) sbase = 0;
    __syncthreads();
    for (int t0 = 0; t0 < S_LEN; t0 += 1024) {
        int t = t0 + threadIdx.x;
        int pk = tope[t];
        int e0 = pk & 0xff, e1 = (pk >> 8) & 0xff;
        bool sel = (e0 == e) || (e1 == e);
        unsigned long long mask = __ballot(sel);
        int prefix = __popcll(mask & ((1ULL << lane) - 1ULL));
        if (lane == 0) wtot[wv] = __popcll(mask);
        __syncthreads();
        if (sel) {
            int off = sbase;
            for (int i = 0; i < wv; ++i) off += wtot[i];
            float2 wpair = topw[t];
            float wsel = (e0 == e) ? wpair.x : wpair.y;
            int slot = off + prefix;
            idx[e * S_LEN + slot] = t;
            wt[e * S_LEN + slot] = wsel;
        }
        __syncthreads();
        if (threadIdx.x == 0) {
            int s = 0;
            #pragma unroll
            for (int i = 0; i < 16; ++i) s += wtot[i];
            sbase += s;
        }
    }
    __syncthreads();
    if (threadIdx.x == 0) cnt[e] = sbase;
}

// plain rmsnorm for final output (fp32)
__global__ __launch_bounds__(256) void rmsnorm_kernel(const float* __restrict__ x,
                                                      const float* __restrict__ w,
                                                      float* __restrict__ out) {
    int row = blockIdx.x;
    const float4* xr = (const float4*)(x + (size_t)row * HID);
    float4 xv = xr[threadIdx.x];
    float ss = xv.x*xv.x + xv.y*xv.y + xv.z*xv.z + xv.w*xv.w;
    for (int off = 32; off; off >>= 1) ss += __shfl_xor(ss, off);
    __shared__ float sred[4];
    if ((threadIdx.x & 63) == 0) sred[threadIdx.x >> 6] = ss;
    __syncthreads();
    float tot = sred[0] + sred[1] + sred[2] + sred[3];
    float scale = rsqrtf(tot * (1.0f / (float)HID) + 1e-5f);
    float4 wv = ((const float4*)w)[threadIdx.x];
    float4 o;
    o.x = xv.x * scale * wv.x; o.y = xv.y * scale * wv.y;
    o.z = xv.z * scale * wv.z; o.w = xv.w * scale * wv.w;
    ((float4*)(out + (size_t)row * HID))[threadIdx.x] = o;
}

// ---------------- RoPE apply + fp16 convert (q scaled by 1/8, k unscaled) ------------
__global__ void rope_cvt_kernel(const float* __restrict__ p, const float* __restrict__ cosb,
                                const float* __restrict__ sinb, short* __restrict__ o16,
                                int nh, int total, float qscale) {
    int gid = blockIdx.x * 256 + threadIdx.x;
    if (gid >= total) return;
    int per = nh * 32;
    int t = gid / per, r = gid % per;
    int hh = r >> 5, i = r & 31;
    float c = cosb[t*32 + i], s = sinb[t*32 + i];
    const float* base = p + (size_t)t * (nh * HD) + hh * HD + i;
    float a = base[0], b = base[32];
    short* ob = o16 + (size_t)t * (nh * HD) + hh * HD + i;
    ob[0]  = f2h((a * c - b * s) * qscale);
    ob[32] = f2h((b * c + a * s) * qscale);
}

// ---------------- V transpose + fp16 ----------------
__global__ __launch_bounds__(256) void vtrans_kernel(const float* __restrict__ vb,
                                                     short* __restrict__ vt16) {
    __shared__ float tile[64][65];
    const int t0 = blockIdx.x * 64, d0 = blockIdx.y * 64;
    const int tr = threadIdx.x >> 2;
    const int dc = (threadIdx.x & 3) * 16;
    const float4* src = (const float4*)(vb + (size_t)(t0 + tr) * (KVH*HD) + d0 + dc);
    float4 v0 = src[0], v1 = src[1], v2 = src[2], v3 = src[3];
    tile[tr][dc+ 0]=v0.x; tile[tr][dc+ 1]=v0.y; tile[tr][dc+ 2]=v0.z; tile[tr][dc+ 3]=v0.w;
    tile[tr][dc+ 4]=v1.x; tile[tr][dc+ 5]=v1.y; tile[tr][dc+ 6]=v1.z; tile[tr][dc+ 7]=v1.w;
    tile[tr][dc+ 8]=v2.x; tile[tr][dc+ 9]=v2.y; tile[tr][dc+10]=v2.z; tile[tr][dc+11]=v2.w;
    tile[tr][dc+12]=v3.x; tile[tr][dc+13]=v3.y; tile[tr][dc+14]=v3.z; tile[tr][dc+15]=v3.w;
    __syncthreads();
    const int dr = threadIdx.x >> 2;
    const int tc = (threadIdx.x & 3) * 16;
    s16x8 w0, w1;
    #pragma unroll
    for (int i = 0; i < 8; ++i) {
        w0[i] = f2h(tile[tc + i][dr]);
        w1[i] = f2h(tile[tc + 8 + i][dr]);
    }
    short* dst = vt16 + (size_t)(d0 + dr) * S_LEN + t0 + tc;
    *(s16x8*)dst = w0;
    *(s16x8*)(dst + 8) = w1;
}

// ---- fp16-A / fp32-B 64x128 GEMM core: dbuf LDS, 2-deep reg pipeline, cvt-on-stage ----
__device__ __forceinline__ void gemm64_core_wf32(
        const short* pA0, const float* pB0, const float* pB1,
        int Kd, int tid, short* As, short* Bs, f32x4 (&acc)[2][4]) {
    const int lane = tid & 63, lo = lane & 15, hi = lane >> 4;
    const int wid = tid >> 6, wr = wid >> 1, wc = wid & 1;
    const int srow = tid >> 2, scol = (tid & 3) * 8;
    const int aoff = srow*40 + scol;
    const int boff0 = srow*40 + scol, boff1 = (64+srow)*40 + scol;

    s16x8 a0_; float4 b00a_, b00b_, b10a_, b10b_;   // set 0
    s16x8 a1_; float4 b01a_, b01b_, b11a_, b11b_;   // set 1

    // tile 0 -> LDS buf0 directly
    a0_ = *(const s16x8*)pA0;
    b00a_ = ((const float4*)pB0)[0]; b00b_ = ((const float4*)pB0)[1];
    b10a_ = ((const float4*)pB1)[0]; b10b_ = ((const float4*)pB1)[1];
    *(s16x8*)&As[aoff]  = a0_;
    *(s16x8*)&Bs[boff0] = cvt8(b00a_, b00b_);
    *(s16x8*)&Bs[boff1] = cvt8(b10a_, b10b_);
    if (32 < Kd) {
        a0_ = *(const s16x8*)(pA0+32);
        b00a_ = ((const float4*)(pB0+32))[0]; b00b_ = ((const float4*)(pB0+32))[1];
        b10a_ = ((const float4*)(pB1+32))[0]; b10b_ = ((const float4*)(pB1+32))[1];
    }
    if (64 < Kd) {
        a1_ = *(const s16x8*)(pA0+64);
        b01a_ = ((const float4*)(pB0+64))[0]; b01b_ = ((const float4*)(pB0+64))[1];
        b11a_ = ((const float4*)(pB1+64))[0]; b11b_ = ((const float4*)(pB1+64))[1];
    }
    __syncthreads();
    int p = 0;
    for (int k0 = 0; k0 < Kd; k0 += 64) {
        // sub-iter A: compute tile k0; write k0+32 (set0); load k0+96 -> set0
        {
            if (k0 + 32 < Kd) {
                short* Asn = As + (p ^ 1) * (64*40);
                short* Bsn = Bs + (p ^ 1) * (128*40);
                *(s16x8*)&Asn[aoff]  = a0_;
                *(s16x8*)&Bsn[boff0] = cvt8(b00a_, b00b_);
                *(s16x8*)&Bsn[boff1] = cvt8(b10a_, b10b_);
            }
            if (k0 + 96 < Kd) {
                a0_  = *(const s16x8*)(pA0 + k0 + 96);
                b00a_ = ((const float4*)(pB0 + k0 + 96))[0]; b00b_ = ((const float4*)(pB0 + k0 + 96))[1];
                b10a_ = ((const float4*)(pB1 + k0 + 96))[0]; b10b_ = ((const float4*)(pB1 + k0 + 96))[1];
            }
            const short* Asp = As + p * (64*40);
            const short* Bsp = Bs + p * (128*40);
            f16x8 aF[2], bF[4];
            #pragma unroll
            for (int m = 0; m < 2; ++m) aF[m] = *(const f16x8*)&Asp[(wr*32 + m*16 + lo)*40 + hi*8];
            #pragma unroll
            for (int n = 0; n < 4; ++n) bF[n] = *(const f16x8*)&Bsp[(wc*64 + n*16 + lo)*40 + hi*8];
            #pragma unroll
            for (int m = 0; m < 2; ++m)
                #pragma unroll
                for (int n = 0; n < 4; ++n)
                    acc[m][n] = __builtin_amdgcn_mfma_f32_16x16x32_f16(aF[m], bF[n], acc[m][n], 0, 0, 0);
            __syncthreads();
            p ^= 1;
        }
        // sub-iter B: compute tile k0+32; write k0+64 (set1); load k0+128 -> set1
        {
            if (k0 + 64 < Kd) {
                short* Asn = As + (p ^ 1) * (64*40);
                short* Bsn = Bs + (p ^ 1) * (128*40);
                *(s16x8*)&Asn[aoff]  = a1_;
                *(s16x8*)&Bsn[boff0] = cvt8(b01a_, b01b_);
                *(s16x8*)&Bsn[boff1] = cvt8(b11a_, b11b_);
            }
            if (k0 + 128 < Kd) {
                a1_  = *(const s16x8*)(pA0 + k0 + 128);
                b01a_ = ((const float4*)(pB0 + k0 + 128))[0]; b01b_ = ((const float4*)(pB0 + k0 + 128))[1];
                b11a_ = ((const float4*)(pB1 + k0 + 128))[0]; b11b_ = ((const float4*)(pB1 + k0 + 128))[1];
            }
            const short* Asp = As + p * (64*40);
            const short* Bsp = Bs + p * (128*40);
            f16x8 aF[2], bF[4];
            #pragma unroll
            for (int m = 0; m < 2; ++m) aF[m] = *(const f16x8*)&Asp[(wr*32 + m*16 + lo)*40 + hi*8];
            #pragma unroll
            for (int n = 0; n < 4; ++n) bF[n] = *(const f16x8*)&Bsp[(wc*64 + n*16 + lo)*40 + hi*8];
            #pragma unroll
            for (int m = 0; m < 2; ++m)
                #pragma unroll
                for (int n = 0; n < 4; ++n)
                    acc[m][n] = __builtin_amdgcn_mfma_f32_16x16x32_f16(aF[m], bF[n], acc[m][n], 0, 0, 0);
            __syncthreads();
            p ^= 1;
        }
    }
}

// ---------------- generic GEMM: C = A(fp16) @ B(fp32)^T (+resid), 64-row tiles --------
__global__ __launch_bounds__(256) void gemm_h16_kernel(const short* __restrict__ Ag,
        const float* __restrict__ Bg, float* __restrict__ C,
        const float* __restrict__ resid, int N, int Kd) {
    __shared__ __align__(16) short As[2*64*40], Bs[2*128*40];
    const int tid = threadIdx.x;
    const int lane = tid & 63, lo = lane & 15, hi = lane >> 4;
    const int wid = tid >> 6, wr = wid >> 1, wc = wid & 1;
    const int m0 = blockIdx.y * 64, n0 = blockIdx.x * 128;
    const int srow = tid >> 2, scol = (tid & 3) * 8;
    f32x4 acc[2][4];
    #pragma unroll
    for (int m = 0; m < 2; ++m)
        #pragma unroll
        for (int n = 0; n < 4; ++n) { acc[m][n][0]=0.f; acc[m][n][1]=0.f; acc[m][n][2]=0.f; acc[m][n][3]=0.f; }
    gemm64_core_wf32(Ag + (size_t)(m0+srow)*Kd + scol,
                     Bg + (size_t)(n0+srow)*Kd + scol, Bg + (size_t)(n0+64+srow)*Kd + scol,
                     Kd, tid, As, Bs, acc);
    #pragma unroll
    for (int m = 0; m < 2; ++m)
        #pragma unroll
        for (int n = 0; n < 4; ++n)
            #pragma unroll
            for (int r = 0; r < 4; ++r) {
                int row = m0 + wr*32 + m*16 + hi*4 + r;
                int col = n0 + wc*64 + n*16 + lo;
                float val = acc[m][n][r];
                if (resid) val += resid[(size_t)row * N + col];
                C[(size_t)row * N + col] = val;
            }
}

// ---------------- fused QKV GEMM (A fp16, W fp32) ----------------
__global__ __launch_bounds__(256) void qkv_h16_kernel(const short* __restrict__ Xh,
        const float* __restrict__ qw, const float* __restrict__ kw,
        const float* __restrict__ vw,
        float* __restrict__ qo, float* __restrict__ ko, float* __restrict__ vo) {
    __shared__ __align__(16) short As[2*64*40], Bs[2*128*40];
    const int bx = blockIdx.x;
    const float* Bp; float* Cp; int Nc, n0;
    if (bx < 8)       { Bp = qw; Cp = qo; Nc = 1024; n0 = bx * 128; }
    else if (bx < 10) { Bp = kw; Cp = ko; Nc = 256;  n0 = (bx - 8) * 128; }
    else              { Bp = vw; Cp = vo; Nc = 256;  n0 = (bx - 10) * 128; }
    const int tid = threadIdx.x;
    const int lane = tid & 63, lo = lane & 15, hi = lane >> 4;
    const int wid = tid >> 6, wr = wid >> 1, wc = wid & 1;
    const int m0 = blockIdx.y * 64;
    const int srow = tid >> 2, scol = (tid & 3) * 8;
    f32x4 acc[2][4];
    #pragma unroll
    for (int m = 0; m < 2; ++m)
        #pragma unroll
        for (int n = 0; n < 4; ++n) { acc[m][n][0]=0.f; acc[m][n][1]=0.f; acc[m][n][2]=0.f; acc[m][n][3]=0.f; }
    gemm64_core_wf32(Xh + (size_t)(m0+srow)*HID + scol,
                     Bp + (size_t)(n0+srow)*HID + scol, Bp + (size_t)(n0+64+srow)*HID + scol,
                     HID, tid, As, Bs, acc);
    #pragma unroll
    for (int m = 0; m < 2; ++m)
        #pragma unroll
        for (int n = 0; n < 4; ++n)
            #pragma unroll
            for (int r = 0; r < 4; ++r) {
                int row = m0 + wr*32 + m*16 + hi*4 + r;
                int col = n0 + wc*64 + n*16 + lo;
                Cp[(size_t)row * Nc + col] = acc[m][n][r];
            }
}

// -------- split-K fp16 flash attention (LDS-staged, uniform 4-tile chunks) --------
__global__ __launch_bounds__(256) void attn_mfma_kernel(const short* __restrict__ q16,
                                                        const short* __restrict__ k16,
                                                        const short* __restrict__ vt16,
                                                        float* __restrict__ pO,
                                                        float* __restrict__ pm,
                                                        float* __restrict__ pl) {
    __shared__ __align__(16) short Ks[64][72];
    __shared__ __align__(16) short Vt[64][72];
    __shared__ __align__(16) short Ps[4][16][72];
    const int wid = threadIdx.x >> 6, lane = threadIdx.x & 63;
    const int lo = lane & 15, hi = lane >> 4;
    const int head = blockIdx.y;
    const int s = (NSLOT - 1) - blockIdx.x;   // long chunks dispatched first
    int g = 0, base = 0;
    while (g < 7 && s >= base + 4 * (g + 1)) { base += 4 * (g + 1); ++g; }
    const int tt = s - base;
    const int qi = 4 * g + tt / (g + 1);
    const int c  = tt % (g + 1);
    const int t_beg = c * 4;
    const int t_end = min(t_beg + 4, qi + 1);
    const int q0 = qi * 64;
    const int kvh = head >> 2;

    f16x8 qf[2];
    {
        const short* qr = q16 + (size_t)(q0 + wid*16 + lo) * HID + head*HD;
        qf[0] = *(const f16x8*)(qr + hi*8);
        qf[1] = *(const f16x8*)(qr + 32 + hi*8);
    }

    f32x4 acc[4];
    float m[4], l[4];
    #pragma unroll
    for (int r = 0; r < 4; ++r) {
        m[r] = -1e30f; l[r] = 0.f;
        acc[0][r] = 0.f; acc[1][r] = 0.f; acc[2][r] = 0.f; acc[3][r] = 0.f;
    }

    const int skey = threadIdx.x >> 2;
    const int sdg  = (threadIdx.x & 3) * 16;

    s16x8 ka0, ka1, va0, va1;
    {
        const short* kr = k16 + (size_t)(t_beg*64 + skey)*(KVH*HD) + kvh*HD + sdg;
        ka0 = *(const s16x8*)kr; ka1 = *(const s16x8*)(kr + 8);
        const short* vr = vt16 + (size_t)(kvh*HD + skey)*S_LEN + t_beg*64 + sdg;
        va0 = *(const s16x8*)vr; va1 = *(const s16x8*)(vr + 8);
    }

    for (int t = t_beg; t < t_end; ++t) {
        __syncthreads();
        *(s16x8*)&Ks[skey][sdg]     = ka0;
        *(s16x8*)&Ks[skey][sdg + 8] = ka1;
        *(s16x8*)&Vt[skey][sdg]     = va0;
        *(s16x8*)&Vt[skey][sdg + 8] = va1;
        __syncthreads();
        if (t + 1 < t_end) {
            const short* kr = k16 + (size_t)((t+1)*64 + skey)*(KVH*HD) + kvh*HD + sdg;
            ka0 = *(const s16x8*)kr; ka1 = *(const s16x8*)(kr + 8);
            const short* vr = vt16 + (size_t)(kvh*HD + skey)*S_LEN + (t+1)*64 + sdg;
            va0 = *(const s16x8*)vr; va1 = *(const s16x8*)(vr + 8);
        }
        const int k0 = t * 64;
        f32x4 sc[4];
        #pragma unroll
        for (int f = 0; f < 4; ++f) {
            f32x4 sf; sf[0]=0.f; sf[1]=0.f; sf[2]=0.f; sf[3]=0.f;
            f16x8 bk0 = *(const f16x8*)&Ks[f*16 + lo][hi*8];
            sf = __builtin_amdgcn_mfma_f32_16x16x32_f16(qf[0], bk0, sf, 0, 0, 0);
            f16x8 bk1 = *(const f16x8*)&Ks[f*16 + lo][32 + hi*8];
            sf = __builtin_amdgcn_mfma_f32_16x16x32_f16(qf[1], bk1, sf, 0, 0, 0);
            sc[f] = sf;
        }
        if (t == qi) {
            int qrow = q0 + wid*16 + hi*4;
            #pragma unroll
            for (int f = 0; f < 4; ++f)
                #pragma unroll
                for (int r = 0; r < 4; ++r)
                    if (k0 + f*16 + lo > qrow + r) sc[f][r] = -1e30f;
        }
        float pmax[4];
        #pragma unroll
        for (int r = 0; r < 4; ++r) {
            float x = fmaxf(fmaxf(sc[0][r], sc[1][r]), fmaxf(sc[2][r], sc[3][r]));
            x = fmaxf(x, __shfl_xor(x, 1));
            x = fmaxf(x, __shfl_xor(x, 2));
            x = fmaxf(x, __shfl_xor(x, 4));
            x = fmaxf(x, __shfl_xor(x, 8));
            pmax[r] = x;
        }
        bool ok = (pmax[0] <= m[0] + 8.f) && (pmax[1] <= m[1] + 8.f) &&
                  (pmax[2] <= m[2] + 8.f) && (pmax[3] <= m[3] + 8.f);
        if (!__all(ok)) {
            #pragma unroll
            for (int r = 0; r < 4; ++r) {
                float mn = fmaxf(m[r], pmax[r]);
                float sc_ = __expf(m[r] - mn);
                m[r] = mn;
                l[r] *= sc_;
                acc[0][r] *= sc_; acc[1][r] *= sc_;
                acc[2][r] *= sc_; acc[3][r] *= sc_;
            }
        }
        float rs[4] = {0.f, 0.f, 0.f, 0.f};
        #pragma unroll
        for (int f = 0; f < 4; ++f)
            #pragma unroll
            for (int r = 0; r < 4; ++r) {
                float e = __expf(sc[f][r] - m[r]);
                rs[r] += e;
                Ps[wid][hi*4 + r][f*16 + lo] = f2h(e);
            }
        #pragma unroll
        for (int r = 0; r < 4; ++r) {
            float x = rs[r];
            x += __shfl_xor(x, 1); x += __shfl_xor(x, 2);
            x += __shfl_xor(x, 4); x += __shfl_xor(x, 8);
            l[r] += x;
        }
        asm volatile("s_waitcnt lgkmcnt(0)" ::: "memory");
        __builtin_amdgcn_sched_barrier(0);
        f16x8 pa0 = *(const f16x8*)&Ps[wid][lo][hi*8];
        f16x8 pa1 = *(const f16x8*)&Ps[wid][lo][32 + hi*8];
        #pragma unroll
        for (int f = 0; f < 4; ++f) {
            f32x4 o = acc[f];
            f16x8 v0 = *(const f16x8*)&Vt[f*16 + lo][hi*8];
            o = __builtin_amdgcn_mfma_f32_16x16x32_f16(pa0, v0, o, 0, 0, 0);
            f16x8 v1 = *(const f16x8*)&Vt[f*16 + lo][32 + hi*8];
            o = __builtin_amdgcn_mfma_f32_16x16x32_f16(pa1, v1, o, 0, 0, 0);
            acc[f] = o;
        }
    }
    const int pbase = head * NSLOT + s;
    float* po = pO + (size_t)pbase * 4096;
    #pragma unroll
    for (int r = 0; r < 4; ++r)
        #pragma unroll
        for (int f = 0; f < 4; ++f)
            po[(wid*16 + hi*4 + r) * 64 + f*16 + lo] = acc[f][r];
    if (lo == 0) {
        #pragma unroll
        for (int r = 0; r < 4; ++r) {
            pm[pbase*64 + wid*16 + hi*4 + r] = m[r];
            pl[pbase*64 + wid*16 + hi*4 + r] = l[r];
        }
    }
}

// ---------------- combine partials (up to 8 chunks) -> fp16 attention output ----------
__global__ __launch_bounds__(256) void attn_combine_kernel(const float* __restrict__ pO,
        const float* __restrict__ pm, const float* __restrict__ pl,
        short* __restrict__ aoh) {
    const int qi = blockIdx.x, head = blockIdx.y;
    const int g = qi >> 2, rr = qi & 3;
    const int nch = g + 1;
    const int sbase = (g + 1) * (2 * g + rr);
    const int row = threadIdx.x >> 2;
    const int d0 = (threadIdx.x & 3) * 16;
    float mv[8], lv[8];
    float mx = -1e30f;
    #pragma unroll
    for (int cd = 0; cd < 8; ++cd) {
        if (cd < nch) {
            int p = head * NSLOT + sbase + cd;
            mv[cd] = pm[p * 64 + row];
            lv[cd] = pl[p * 64 + row];
            mx = fmaxf(mx, mv[cd]);
        } else { mv[cd] = -1e30f; lv[cd] = 0.f; }
    }
    float w[8];
    float lsum = 0.f;
    #pragma unroll
    for (int cd = 0; cd < 8; ++cd) {
        w[cd] = (cd < nch) ? __expf(mv[cd] - mx) : 0.f;
        lsum += w[cd] * lv[cd];
    }
    float inv = 1.0f / lsum;
    float o[16] = {};
    #pragma unroll
    for (int cd = 0; cd < 8; ++cd) {
        if (cd < nch) {
            const float4* po = (const float4*)(pO + ((size_t)(head * NSLOT + sbase + cd)) * 4096 + row * 64 + d0);
            float wc = w[cd] * inv;
            #pragma unroll
            for (int j = 0; j < 4; ++j) {
                float4 vv = po[j];
                o[j*4+0] += wc * vv.x; o[j*4+1] += wc * vv.y;
                o[j*4+2] += wc * vv.z; o[j*4+3] += wc * vv.w;
            }
        }
    }
    size_t outb = (size_t)(qi * 64 + row) * HID + head * HD + d0;
    s16x8 w0, w1;
    #pragma unroll
    for (int i = 0; i < 8; ++i) { w0[i] = f2h(o[i]); w1[i] = f2h(o[8+i]); }
    *(s16x8*)(aoh + outb) = w0;
    *(s16x8*)(aoh + outb + 8) = w1;
}

// ---- MoE mlp1 (A fp16, W fp32, 64x64 tile, dbuf LDS + 2-deep register pipeline) ----
__global__ __launch_bounds__(256) void moe_mlp1_h16(const short* __restrict__ Xh,
        const float* __restrict__ W1, const float* __restrict__ W3,
        const int* __restrict__ cnt, const int* __restrict__ idx,
        short* __restrict__ abh) {
    int e = blockIdx.z;
    int ne = cnt[e];
    int m0 = blockIdx.y * 64;
    if (m0 >= ne) return;
    int f0 = blockIdx.x * 64;
    __shared__ __align__(16) short As[2*64*40];
    __shared__ __align__(16) short Gs[2*64*40], Us[2*64*40];
    __shared__ int rows[64];
    const int tid = threadIdx.x;
    if (tid < 64) {
        int slot = m0 + tid;
        rows[tid] = (slot < ne) ? idx[e * S_LEN + slot] : 0;
    }
    __syncthreads();
    const int lane = tid & 63, lo = lane & 15, hi = lane >> 4;
    const int wid = tid >> 6, wr = wid >> 1, wc = wid & 1;
    const int srow = tid >> 2, scol = (tid & 3) * 8;
    const int soff = srow*40 + scol;
    const short* pX0 = Xh + (size_t)rows[srow] * HID + scol;
    const float* p1 = W1 + ((size_t)e * FF + f0 + srow) * HID + scol;
    const float* p3 = W3 + ((size_t)e * FF + f0 + srow) * HID + scol;

    f32x4 ag[2][2], au[2][2];
    #pragma unroll
    for (int m = 0; m < 2; ++m)
        #pragma unroll
        for (int n = 0; n < 2; ++n) {
            ag[m][n][0]=0.f; ag[m][n][1]=0.f; ag[m][n][2]=0.f; ag[m][n][3]=0.f;
            au[m][n][0]=0.f; au[m][n][1]=0.f; au[m][n][2]=0.f; au[m][n][3]=0.f;
        }

    s16x8 a0_; float4 g0a_, g0b_, u0a_, u0b_;   // set 0
    s16x8 a1_; float4 g1a_, g1b_, u1a_, u1b_;   // set 1
    a0_ = *(const s16x8*)pX0;
    g0a_ = ((const float4*)p1)[0]; g0b_ = ((const float4*)p1)[1];
    u0a_ = ((const float4*)p3)[0]; u0b_ = ((const float4*)p3)[1];
    *(s16x8*)&As[soff] = a0_;
    *(s16x8*)&Gs[soff] = cvt8(g0a_, g0b_);
    *(s16x8*)&Us[soff] = cvt8(u0a_, u0b_);
    a0_ = *(const s16x8*)(pX0+32);
    g0a_ = ((const float4*)(p1+32))[0]; g0b_ = ((const float4*)(p1+32))[1];
    u0a_ = ((const float4*)(p3+32))[0]; u0b_ = ((const float4*)(p3+32))[1];
    a1_ = *(const s16x8*)(pX0+64);
    g1a_ = ((const float4*)(p1+64))[0]; g1b_ = ((const float4*)(p1+64))[1];
    u1a_ = ((const float4*)(p3+64))[0]; u1b_ = ((const float4*)(p3+64))[1];
    __syncthreads();
    int p = 0;
    for (int k0 = 0; k0 < HID; k0 += 64) {
        // sub-iter A
        {
            if (k0 + 32 < HID) {
                short* Asn = As + (p ^ 1) * (64*40);
                short* Gsn = Gs + (p ^ 1) * (64*40);
                short* Usn = Us + (p ^ 1) * (64*40);
                *(s16x8*)&Asn[soff] = a0_;
                *(s16x8*)&Gsn[soff] = cvt8(g0a_, g0b_);
                *(s16x8*)&Usn[soff] = cvt8(u0a_, u0b_);
            }
            if (k0 + 96 < HID) {
                a0_ = *(const s16x8*)(pX0 + k0 + 96);
                g0a_ = ((const float4*)(p1 + k0 + 96))[0]; g0b_ = ((const float4*)(p1 + k0 + 96))[1];
                u0a_ = ((const float4*)(p3 + k0 + 96))[0]; u0b_ = ((const float4*)(p3 + k0 + 96))[1];
            }
            const short* Asp = As + p * (64*40);
            const short* Gsp = Gs + p * (64*40);
            const short* Usp = Us + p * (64*40);
            f16x8 aF[2], gF[2], uF[2];
            #pragma unroll
            for (int m = 0; m < 2; ++m) aF[m] = *(const f16x8*)&Asp[(wr*32 + m*16 + lo)*40 + hi*8];
            #pragma unroll
            for (int n = 0; n < 2; ++n) {
                gF[n] = *(const f16x8*)&Gsp[(wc*32 + n*16 + lo)*40 + hi*8];
                uF[n] = *(const f16x8*)&Usp[(wc*32 + n*16 + lo)*40 + hi*8];
            }
            #pragma unroll
            for (int m = 0; m < 2; ++m)
                #pragma unroll
                for (int n = 0; n < 2; ++n) {
                    ag[m][n] = __builtin_amdgcn_mfma_f32_16x16x32_f16(aF[m], gF[n], ag[m][n], 0, 0, 0);
                    au[m][n] = __builtin_amdgcn_mfma_f32_16x16x32_f16(aF[m], uF[n], au[m][n], 0, 0, 0);
                }
            __syncthreads();
            p ^= 1;
        }
        // sub-iter B
        {
            if (k0 + 64 < HID) {
                short* Asn = As + (p ^ 1) * (64*40);
                short* Gsn = Gs + (p ^ 1) * (64*40);
                short* Usn = Us + (p ^ 1) * (64*40);
                *(s16x8*)&Asn[soff] = a1_;
                *(s16x8*)&Gsn[soff] = cvt8(g1a_, g1b_);
                *(s16x8*)&Usn[soff] = cvt8(u1a_, u1b_);
            }
            if (k0 + 128 < HID) {
                a1_ = *(const s16x8*)(pX0 + k0 + 128);
                g1a_ = ((const float4*)(p1 + k0 + 128))[0]; g1b_ = ((const float4*)(p1 + k0 + 128))[1];
                u1a_ = ((const float4*)(p3 + k0 + 128))[0]; u1b_ = ((const float4*)(p3 + k0 + 128))[1];
            }
            const short* Asp = As + p * (64*40);
            const short* Gsp = Gs + p * (64*40);
            const short* Usp = Us + p * (64*40);
            f16x8 aF[2], gF[2], uF[2];
            #pragma unroll
            for (int m = 0; m < 2; ++m) aF[m] = *(const f16x8*)&Asp[(wr*32 + m*16 + lo)*40 + hi*8];
            #pragma unroll
            for (int n = 0; n < 2; ++n) {
                gF[n] = *(const f16x8*)&Gsp[(wc*32 + n*16 + lo)*40 + hi*8];
                uF[n] = *(const f16x8*)&Usp[(wc*32 + n*16 + lo)*40 + hi*8];
            }
            #pragma unroll
            for (int m = 0; m < 2; ++m)
                #pragma unroll
                for (int n = 0; n < 2; ++n) {
                    ag[m][n] = __builtin_amdgcn_mfma_f32_16x16x32_f16(aF[m], gF[n], ag[m][n], 0, 0, 0);
                    au[m][n] = __builtin_amdgcn_mfma_f32_16x16x32_f16(aF[m], uF[n], au[m][n], 0, 0, 0);
                }
            __syncthreads();
            p ^= 1;
        }
    }
    #pragma unroll
    for (int m = 0; m < 2; ++m)
        #pragma unroll
        for (int n = 0; n < 2; ++n)
            #pragma unroll
            for (int r = 0; r < 4; ++r) {
                int slot = m0 + wr*32 + m*16 + hi*4 + r;
                if (slot >= ne) continue;
                float g = ag[m][n][r], u = au[m][n][r];
                float a = g * (1.0f / (1.0f + __expf(-g))) * u;
                abh[((size_t)e * S_LEN + slot) * FF + f0 + wc*32 + n*16 + lo] = f2h(a);
            }
}

// ------- MoE mlp2 (A fp16, W fp32, 64-row tile, dbuf+2-deep, split-K over FF) -------
__global__ __launch_bounds__(256) void moe_mlp2_h16(const short* __restrict__ abh,
        const float* __restrict__ W2,
        const int* __restrict__ cnt, const int* __restrict__ idx,
        const float* __restrict__ wt, float* __restrict__ hbuf) {
    int e = blockIdx.z >> 1;
    int ks = blockIdx.z & 1;
    int ne = cnt[e];
    int m0 = blockIdx.y * 64;
    if (m0 >= ne) return;
    int n0 = blockIdx.x * 128;
    const int koff = ks * (FF / 2);
    __shared__ __align__(16) short As[2*64*40], Bs[2*128*40];
    const int tid = threadIdx.x;
    const int lane = tid & 63, lo = lane & 15, hi = lane >> 4;
    const int wid = tid >> 6, wr = wid >> 1, wc = wid & 1;
    const int srow = tid >> 2, scol = (tid & 3) * 8;
    f32x4 acc[2][4];
    #pragma unroll
    for (int m = 0; m < 2; ++m)
        #pragma unroll
        for (int n = 0; n < 4; ++n) { acc[m][n][0]=0.f; acc[m][n][1]=0.f; acc[m][n][2]=0.f; acc[m][n][3]=0.f; }
    gemm64_core_wf32(abh + ((size_t)e*S_LEN + m0 + srow)*FF + koff + scol,
                     W2 + ((size_t)e*HID + n0 + srow)*FF + koff + scol,
                     W2 + ((size_t)e*HID + n0 + 64 + srow)*FF + koff + scol,
                     FF / 2, tid, As, Bs, acc);
    #pragma unroll
    for (int m = 0; m < 2; ++m) {
        #pragma unroll
        for (int r = 0; r < 4; ++r) {
            int slot = m0 + wr*32 + m*16 + hi*4 + r;
            if (slot >= ne) continue;
            int tok = idx[e * S_LEN + slot];
            float wv = wt[e * S_LEN + slot];
            #pragma unroll
            for (int n = 0; n < 4; ++n)
                atomicAdd(&hbuf[(size_t)tok * HID + n0 + wc*64 + n*16 + lo], acc[m][n][r] * wv);
        }
    }
}

extern "C" void kernel_launch(void* const* d_in, const int* in_sizes, int n_in,
                              void* d_out, int out_size, void* d_ws, size_t ws_size,
                              hipStream_t stream) {
    const float* emb = (const float*)d_in[0];
    const float* ln1 = (const float*)d_in[1];
    const float* ln2 = (const float*)d_in[2];
    const float* fln = (const float*)d_in[3];
    const float* qw  = (const float*)d_in[4];
    const float* kw  = (const float*)d_in[5];
    const float* vw  = (const float*)d_in[6];
    const float* ow  = (const float*)d_in[7];
    const float* gw  = (const float*)d_in[8];
    const float* w1  = (const float*)d_in[9];
    const float* w2  = (const float*)d_in[10];
    const float* w3  = (const float*)d_in[11];

    float* ws   = (float*)d_ws;
    float* h    = ws + OFF_H;
    float* q    = ws + OFF_Q;
    float* kb   = ws + OFF_K;
    float* vb   = ws + OFF_V;
    float* cosb = ws + OFF_COS;
    float* sinb = ws + OFF_SIN;
    float* wt   = ws + OFF_WT;
    int*   cnt  = (int*)(ws + OFF_INT);
    int*   idx  = cnt + 8;
    int*   tope = (int*)(ws + OFF_TOPE);
    float2* topw = (float2*)(ws + OFF_TOPW);
    short* xh   = (short*)(ws + OFF_XH);
    short* aoh  = (short*)(ws + OFF_AOH);
    short* abh  = (short*)(ws + OFF_ABH);
    short* q16  = (short*)(ws + OFF_Q16);
    short* k16  = (short*)(ws + OFF_K16);
    short* vt16 = (short*)(ws + OFF_VT16);
    float* pO   = ws + OFF_PO;
    float* pm   = ws + OFF_PM;
    float* pl   = ws + OFF_PL;

    hipMemcpyAsync(h, emb, (size_t)S_LEN * HID * sizeof(float), hipMemcpyDeviceToDevice, stream);
    rope_tables_kernel<<<S_LEN * 32 / 256, 256, 0, stream>>>(cosb, sinb);

    for (int l = 0; l < NL; ++l) {
        rmsnorm_h16_kernel<<<S_LEN, 256, 0, stream>>>(h, ln1 + l * HID, xh);
        qkv_h16_kernel<<<dim3(12, 32), 256, 0, stream>>>(xh,
            qw + (size_t)l*HID*HID, kw + (size_t)l*KVH*HD*HID, vw + (size_t)l*KVH*HD*HID,
            q, kb, vb);
        rope_cvt_kernel<<<(S_LEN * NHEAD * 32) / 256, 256, 0, stream>>>(q, cosb, sinb, q16, NHEAD, S_LEN * NHEAD * 32, 0.125f);
        rope_cvt_kernel<<<(S_LEN * KVH * 32) / 256, 256, 0, stream>>>(kb, cosb, sinb, k16, KVH, S_LEN * KVH * 32, 1.0f);
        vtrans_kernel<<<dim3(S_LEN/64, KVH*HD/64), 256, 0, stream>>>(vb, vt16);
        attn_mfma_kernel<<<dim3(NSLOT, NHEAD), 256, 0, stream>>>(q16, k16, vt16, pO, pm, pl);
        attn_combine_kernel<<<dim3(32, NHEAD), 256, 0, stream>>>(pO, pm, pl, aoh);
        gemm_h16_kernel<<<dim3(8, 32), 256, 0, stream>>>(aoh, ow + (size_t)l*HID*HID, h, h, HID, HID);

        rmsnorm_gate_kernel<<<S_LEN, 256, 0, stream>>>(h, ln2 + l * HID, gw + (size_t)l * NE * HID,
                                                       xh, tope, topw);
        route_build_kernel<<<NE, 1024, 0, stream>>>(tope, topw, cnt, idx, wt);

        moe_mlp1_h16<<<dim3(16, 32, 8), 256, 0, stream>>>(xh,
            w1 + (size_t)l*NE*FF*HID, w3 + (size_t)l*NE*FF*HID, cnt, idx, abh);
        moe_mlp2_h16<<<dim3(8, 32, 16), 256, 0, stream>>>(abh,
            w2 + (size_t)l*NE*HID*FF, cnt, idx, wt, h);
    }
    rmsnorm_kernel<<<S_LEN, 256, 0, stream>>>(h, fln, (float*)d_out);
}

// Round 20
// 444.607 us; speedup vs baseline: 1.2906x; 1.0442x over previous
//
#include <hip/hip_runtime.h>
#include <hip/hip_bf16.h>
#include <math.h>

#define S_LEN 2048
#define HID   1024
#define NHEAD 16
#define KVH   4
#define HD    64
#define FF    1024
#define NE    8
#define NL    2
#define NSLOT 144   // sum over qi of ceil((qi+1)/4), qi in [0,32)

// ---- workspace layout (float offsets) ----
#define OFF_H    0
#define OFF_Q    (OFF_H + S_LEN*HID)
#define OFF_K    (OFF_Q + S_LEN*HID)
#define OFF_V    (OFF_K + S_LEN*KVH*HD)
#define OFF_COS  (OFF_V + S_LEN*KVH*HD)
#define OFF_SIN  (OFF_COS + S_LEN*32)
#define OFF_WT   (OFF_SIN + S_LEN*32)
#define OFF_INT  (OFF_WT + NE*S_LEN)
#define OFF_TOPE (OFF_INT + NE*S_LEN + 16)
#define OFF_TOPW (OFF_TOPE + S_LEN)
#define OFF_XH   (OFF_TOPW + 2*S_LEN)
#define OFF_AOH  (OFF_XH + S_LEN*HID/2)
#define OFF_ABH  (OFF_AOH + S_LEN*HID/2)
#define OFF_Q16  (OFF_ABH + NE*S_LEN*FF/2)
#define OFF_K16  (OFF_Q16 + S_LEN*HID/2)
#define OFF_VT16 (OFF_K16 + S_LEN*KVH*HD/2)
#define OFF_PO   (OFF_VT16 + S_LEN*KVH*HD/2)
#define OFF_PM   (OFF_PO + NSLOT*NHEAD*64*64)
#define OFF_PL   (OFF_PM + NSLOT*NHEAD*64)

typedef __attribute__((ext_vector_type(8))) _Float16 f16x8;
typedef __attribute__((ext_vector_type(8))) short  s16x8;
typedef __attribute__((ext_vector_type(4))) float  f32x4;

__device__ __forceinline__ short f2h(float f) {
    union { _Float16 h; short s; } u;
    u.h = (_Float16)f;
    return u.s;
}

__device__ __forceinline__ s16x8 cvt8(float4 a, float4 b) {
    s16x8 w;
    w[0]=f2h(a.x); w[1]=f2h(a.y); w[2]=f2h(a.z); w[3]=f2h(a.w);
    w[4]=f2h(b.x); w[5]=f2h(b.y); w[6]=f2h(b.z); w[7]=f2h(b.w);
    return w;
}

// ---------------- RoPE tables ----------------
__global__ void rope_tables_kernel(float* __restrict__ cosb, float* __restrict__ sinb) {
    int gid = blockIdx.x * 256 + threadIdx.x;
    int t = gid >> 5, i = gid & 31;
    float invf = powf(1.0e6f, -(float)i / 32.0f);
    float ang = (float)t * invf;
    cosb[gid] = cosf(ang);
    sinb[gid] = sinf(ang);
}

// ---------------- RMSNorm -> fp16 only ----------------
__global__ __launch_bounds__(256) void rmsnorm_h16_kernel(const float* __restrict__ x,
                                                          const float* __restrict__ w,
                                                          short* __restrict__ oh) {
    int row = blockIdx.x;
    const float4* xr = (const float4*)(x + (size_t)row * HID);
    float4 xv = xr[threadIdx.x];
    float ss = xv.x*xv.x + xv.y*xv.y + xv.z*xv.z + xv.w*xv.w;
    for (int off = 32; off; off >>= 1) ss += __shfl_xor(ss, off);
    __shared__ float sred[4];
    if ((threadIdx.x & 63) == 0) sred[threadIdx.x >> 6] = ss;
    __syncthreads();
    float tot = sred[0] + sred[1] + sred[2] + sred[3];
    float scale = rsqrtf(tot * (1.0f / (float)HID) + 1e-5f);
    float4 wv = ((const float4*)w)[threadIdx.x];
    float4 o;
    o.x = xv.x * scale * wv.x; o.y = xv.y * scale * wv.y;
    o.z = xv.z * scale * wv.z; o.w = xv.w * scale * wv.w;
    union { short s[4]; float2 f2; } hh;
    hh.s[0]=f2h(o.x); hh.s[1]=f2h(o.y); hh.s[2]=f2h(o.z); hh.s[3]=f2h(o.w);
    ((float2*)(oh + (size_t)row * HID))[threadIdx.x] = hh.f2;
}

// ---------------- RMSNorm + gate top-2 (NO atomics) ----------------
__global__ __launch_bounds__(256) void rmsnorm_gate_kernel(const float* __restrict__ x,
                                                           const float* __restrict__ w,
                                                           const float* __restrict__ gw,
                                                           short* __restrict__ oh,
                                                           int* __restrict__ tope,
                                                           float2* __restrict__ topw) {
    int row = blockIdx.x;
    const float4* xr = (const float4*)(x + (size_t)row * HID);
    float4 xv = xr[threadIdx.x];
    float ss = xv.x*xv.x + xv.y*xv.y + xv.z*xv.z + xv.w*xv.w;
    for (int off = 32; off; off >>= 1) ss += __shfl_xor(ss, off);
    __shared__ float sred[4];
    __shared__ float gred[4][NE];
    if ((threadIdx.x & 63) == 0) sred[threadIdx.x >> 6] = ss;
    __syncthreads();
    float tot = sred[0] + sred[1] + sred[2] + sred[3];
    float scale = rsqrtf(tot * (1.0f / (float)HID) + 1e-5f);
    float4 wv = ((const float4*)w)[threadIdx.x];
    float4 o;
    o.x = xv.x * scale * wv.x; o.y = xv.y * scale * wv.y;
    o.z = xv.z * scale * wv.z; o.w = xv.w * scale * wv.w;
    union { short s[4]; float2 f2; } hh;
    hh.s[0]=f2h(o.x); hh.s[1]=f2h(o.y); hh.s[2]=f2h(o.z); hh.s[3]=f2h(o.w);
    ((float2*)(oh + (size_t)row * HID))[threadIdx.x] = hh.f2;
    const float4* gr = (const float4*)gw;
    float acc[NE];
    #pragma unroll
    for (int e = 0; e < NE; ++e) {
        float4 g4 = gr[e * 256 + threadIdx.x];
        acc[e] = o.x*g4.x + o.y*g4.y + o.z*g4.z + o.w*g4.w;
    }
    #pragma unroll
    for (int e = 0; e < NE; ++e)
        for (int off = 32; off; off >>= 1) acc[e] += __shfl_xor(acc[e], off);
    if ((threadIdx.x & 63) == 0) {
        #pragma unroll
        for (int e = 0; e < NE; ++e) gred[threadIdx.x >> 6][e] = acc[e];
    }
    __syncthreads();
    if (threadIdx.x == 0) {
        float lg[NE];
        #pragma unroll
        for (int e = 0; e < NE; ++e)
            lg[e] = gred[0][e] + gred[1][e] + gred[2][e] + gred[3][e];
        float mx = lg[0];
        #pragma unroll
        for (int e = 1; e < NE; ++e) mx = fmaxf(mx, lg[e]);
        float p[NE];
        #pragma unroll
        for (int e = 0; e < NE; ++e) p[e] = __expf(lg[e] - mx);
        int i0 = 0;
        #pragma unroll
        for (int e = 1; e < NE; ++e) if (p[e] > p[i0]) i0 = e;
        int i1 = -1;
        #pragma unroll
        for (int e = 0; e < NE; ++e) if (e != i0 && (i1 < 0 || p[e] > p[i1])) i1 = e;
        float w0 = p[i0], w1 = p[i1];
        float inv = 1.0f / (w0 + w1);
        tope[row] = i0 | (i1 << 8);
        topw[row] = make_float2(w0 * inv, w1 * inv);
    }
}

// ---------------- build per-expert token lists (ballot prefix-scan, no atomics) ----------
__global__ __launch_bounds__(1024) void route_build_kernel(const int* __restrict__ tope,
                                                           const float2* __restrict__ topw,
                                                           int* __restrict__ cnt,
                                                           int* __restrict__ idx,
                                                           float* __restrict__ wt) {
    const int e = blockIdx.x;
    const int lane = threadIdx.x & 63, wv = threadIdx.x >> 6;
    __shared__ int wtot[16];
    __shared__ int sbase;
    if (threadIdx.x == 0) sbase = 0;
    __syncthreads();
    for (int t0 = 0; t0 < S_LEN; t0 += 1024) {
        int t = t0 + threadIdx.x;
        int pk = tope[t];
        int e0 = pk & 0xff, e1 = (pk >> 8) & 0xff;
        bool sel = (e0 == e) || (e1 == e);
        unsigned long long mask = __ballot(sel);
        int prefix = __popcll(mask & ((1ULL << lane) - 1ULL));
        if (lane == 0) wtot[wv] = __popcll(mask);
        __syncthreads();
        if (sel) {
            int off = sbase;
            for (int i = 0; i < wv; ++i) off += wtot[i];
            float2 wpair = topw[t];
            float wsel = (e0 == e) ? wpair.x : wpair.y;
            int slot = off + prefix;
            idx[e * S_LEN + slot] = t;
            wt[e * S_LEN + slot] = wsel;
        }
        __syncthreads();
        if (threadIdx.x == 0) {
            int s = 0;
            #pragma unroll
            for (int i = 0; i < 16; ++i) s += wtot[i];
            sbase += s;
        }
    }
    __syncthreads();
    if (threadIdx.x == 0) cnt[e] = sbase;
}

// plain rmsnorm for final output (fp32)
__global__ __launch_bounds__(256) void rmsnorm_kernel(const float* __restrict__ x,
                                                      const float* __restrict__ w,
                                                      float* __restrict__ out) {
    int row = blockIdx.x;
    const float4* xr = (const float4*)(x + (size_t)row * HID);
    float4 xv = xr[threadIdx.x];
    float ss = xv.x*xv.x + xv.y*xv.y + xv.z*xv.z + xv.w*xv.w;
    for (int off = 32; off; off >>= 1) ss += __shfl_xor(ss, off);
    __shared__ float sred[4];
    if ((threadIdx.x & 63) == 0) sred[threadIdx.x >> 6] = ss;
    __syncthreads();
    float tot = sred[0] + sred[1] + sred[2] + sred[3];
    float scale = rsqrtf(tot * (1.0f / (float)HID) + 1e-5f);
    float4 wv = ((const float4*)w)[threadIdx.x];
    float4 o;
    o.x = xv.x * scale * wv.x; o.y = xv.y * scale * wv.y;
    o.z = xv.z * scale * wv.z; o.w = xv.w * scale * wv.w;
    ((float4*)(out + (size_t)row * HID))[threadIdx.x] = o;
}

// ---------------- RoPE apply + fp16 convert (q scaled by 1/8, k unscaled) ------------
__global__ void rope_cvt_kernel(const float* __restrict__ p, const float* __restrict__ cosb,
                                const float* __restrict__ sinb, short* __restrict__ o16,
                                int nh, int total, float qscale) {
    int gid = blockIdx.x * 256 + threadIdx.x;
    if (gid >= total) return;
    int per = nh * 32;
    int t = gid / per, r = gid % per;
    int hh = r >> 5, i = r & 31;
    float c = cosb[t*32 + i], s = sinb[t*32 + i];
    const float* base = p + (size_t)t * (nh * HD) + hh * HD + i;
    float a = base[0], b = base[32];
    short* ob = o16 + (size_t)t * (nh * HD) + hh * HD + i;
    ob[0]  = f2h((a * c - b * s) * qscale);
    ob[32] = f2h((b * c + a * s) * qscale);
}

// ---------------- V transpose + fp16 ----------------
__global__ __launch_bounds__(256) void vtrans_kernel(const float* __restrict__ vb,
                                                     short* __restrict__ vt16) {
    __shared__ float tile[64][65];
    const int t0 = blockIdx.x * 64, d0 = blockIdx.y * 64;
    const int tr = threadIdx.x >> 2;
    const int dc = (threadIdx.x & 3) * 16;
    const float4* src = (const float4*)(vb + (size_t)(t0 + tr) * (KVH*HD) + d0 + dc);
    float4 v0 = src[0], v1 = src[1], v2 = src[2], v3 = src[3];
    tile[tr][dc+ 0]=v0.x; tile[tr][dc+ 1]=v0.y; tile[tr][dc+ 2]=v0.z; tile[tr][dc+ 3]=v0.w;
    tile[tr][dc+ 4]=v1.x; tile[tr][dc+ 5]=v1.y; tile[tr][dc+ 6]=v1.z; tile[tr][dc+ 7]=v1.w;
    tile[tr][dc+ 8]=v2.x; tile[tr][dc+ 9]=v2.y; tile[tr][dc+10]=v2.z; tile[tr][dc+11]=v2.w;
    tile[tr][dc+12]=v3.x; tile[tr][dc+13]=v3.y; tile[tr][dc+14]=v3.z; tile[tr][dc+15]=v3.w;
    __syncthreads();
    const int dr = threadIdx.x >> 2;
    const int tc = (threadIdx.x & 3) * 16;
    s16x8 w0, w1;
    #pragma unroll
    for (int i = 0; i < 8; ++i) {
        w0[i] = f2h(tile[tc + i][dr]);
        w1[i] = f2h(tile[tc + 8 + i][dr]);
    }
    short* dst = vt16 + (size_t)(d0 + dr) * S_LEN + t0 + tc;
    *(s16x8*)dst = w0;
    *(s16x8*)(dst + 8) = w1;
}

// ---- fp16-A / fp32-B 64x128 GEMM core: dbuf LDS, 3-deep reg pipeline, cvt-on-stage ----
__device__ __forceinline__ void gemm64_core_wf32(
        const short* pA0, const float* pB0, const float* pB1,
        int Kd, int tid, short* As, short* Bs, f32x4 (&acc)[2][4]) {
    const int lane = tid & 63, lo = lane & 15, hi = lane >> 4;
    const int wid = tid >> 6, wr = wid >> 1, wc = wid & 1;
    const int srow = tid >> 2, scol = (tid & 3) * 8;
    const int aoff = srow*40 + scol;
    const int boff0 = srow*40 + scol, boff1 = (64+srow)*40 + scol;

    auto compute = [&](int pp) {
        const short* Asp = As + pp * (64*40);
        const short* Bsp = Bs + pp * (128*40);
        f16x8 aF[2], bF[4];
        #pragma unroll
        for (int m = 0; m < 2; ++m) aF[m] = *(const f16x8*)&Asp[(wr*32 + m*16 + lo)*40 + hi*8];
        #pragma unroll
        for (int n = 0; n < 4; ++n) bF[n] = *(const f16x8*)&Bsp[(wc*64 + n*16 + lo)*40 + hi*8];
        #pragma unroll
        for (int m = 0; m < 2; ++m)
            #pragma unroll
            for (int n = 0; n < 4; ++n)
                acc[m][n] = __builtin_amdgcn_mfma_f32_16x16x32_f16(aF[m], bF[n], acc[m][n], 0, 0, 0);
    };

    s16x8 a0_; float4 b00a_, b00b_, b10a_, b10b_;   // set 0
    s16x8 a1_; float4 b01a_, b01b_, b11a_, b11b_;   // set 1
    s16x8 a2_; float4 b02a_, b02b_, b12a_, b12b_;   // set 2

    {   // tile 0 -> LDS buf0 directly
        s16x8 at = *(const s16x8*)pA0;
        float4 t0 = ((const float4*)pB0)[0], t1 = ((const float4*)pB0)[1];
        float4 t2 = ((const float4*)pB1)[0], t3 = ((const float4*)pB1)[1];
        *(s16x8*)&As[aoff]  = at;
        *(s16x8*)&Bs[boff0] = cvt8(t0, t1);
        *(s16x8*)&Bs[boff1] = cvt8(t2, t3);
    }
    if (32 < Kd) {
        a0_ = *(const s16x8*)(pA0+32);
        b00a_ = ((const float4*)(pB0+32))[0]; b00b_ = ((const float4*)(pB0+32))[1];
        b10a_ = ((const float4*)(pB1+32))[0]; b10b_ = ((const float4*)(pB1+32))[1];
    }
    if (64 < Kd) {
        a1_ = *(const s16x8*)(pA0+64);
        b01a_ = ((const float4*)(pB0+64))[0]; b01b_ = ((const float4*)(pB0+64))[1];
        b11a_ = ((const float4*)(pB1+64))[0]; b11b_ = ((const float4*)(pB1+64))[1];
    }
    if (96 < Kd) {
        a2_ = *(const s16x8*)(pA0+96);
        b02a_ = ((const float4*)(pB0+96))[0]; b02b_ = ((const float4*)(pB0+96))[1];
        b12a_ = ((const float4*)(pB1+96))[0]; b12b_ = ((const float4*)(pB1+96))[1];
    }
    __syncthreads();
    int p = 0;
    for (int k0 = 0; k0 < Kd; k0 += 96) {
        // sub-iter 0: compute tile k0
        {
            if (k0 + 32 < Kd) {
                short* Asn = As + (p ^ 1) * (64*40);
                short* Bsn = Bs + (p ^ 1) * (128*40);
                *(s16x8*)&Asn[aoff]  = a0_;
                *(s16x8*)&Bsn[boff0] = cvt8(b00a_, b00b_);
                *(s16x8*)&Bsn[boff1] = cvt8(b10a_, b10b_);
            }
            if (k0 + 128 < Kd) {
                a0_  = *(const s16x8*)(pA0 + k0 + 128);
                b00a_ = ((const float4*)(pB0 + k0 + 128))[0]; b00b_ = ((const float4*)(pB0 + k0 + 128))[1];
                b10a_ = ((const float4*)(pB1 + k0 + 128))[0]; b10b_ = ((const float4*)(pB1 + k0 + 128))[1];
            }
            compute(p);
            __syncthreads();
            p ^= 1;
        }
        // sub-iter 1: compute tile k0+32
        if (k0 + 32 < Kd) {
            if (k0 + 64 < Kd) {
                short* Asn = As + (p ^ 1) * (64*40);
                short* Bsn = Bs + (p ^ 1) * (128*40);
                *(s16x8*)&Asn[aoff]  = a1_;
                *(s16x8*)&Bsn[boff0] = cvt8(b01a_, b01b_);
                *(s16x8*)&Bsn[boff1] = cvt8(b11a_, b11b_);
            }
            if (k0 + 160 < Kd) {
                a1_  = *(const s16x8*)(pA0 + k0 + 160);
                b01a_ = ((const float4*)(pB0 + k0 + 160))[0]; b01b_ = ((const float4*)(pB0 + k0 + 160))[1];
                b11a_ = ((const float4*)(pB1 + k0 + 160))[0]; b11b_ = ((const float4*)(pB1 + k0 + 160))[1];
            }
            compute(p);
            __syncthreads();
            p ^= 1;
        }
        // sub-iter 2: compute tile k0+64
        if (k0 + 64 < Kd) {
            if (k0 + 96 < Kd) {
                short* Asn = As + (p ^ 1) * (64*40);
                short* Bsn = Bs + (p ^ 1) * (128*40);
                *(s16x8*)&Asn[aoff]  = a2_;
                *(s16x8*)&Bsn[boff0] = cvt8(b02a_, b02b_);
                *(s16x8*)&Bsn[boff1] = cvt8(b12a_, b12b_);
            }
            if (k0 + 192 < Kd) {
                a2_  = *(const s16x8*)(pA0 + k0 + 192);
                b02a_ = ((const float4*)(pB0 + k0 + 192))[0]; b02b_ = ((const float4*)(pB0 + k0 + 192))[1];
                b12a_ = ((const float4*)(pB1 + k0 + 192))[0]; b12b_ = ((const float4*)(pB1 + k0 + 192))[1];
            }
            compute(p);
            __syncthreads();
            p ^= 1;
        }
    }
}

// ---------------- generic GEMM: C = A(fp16) @ B(fp32)^T (+resid), 64-row tiles --------
__global__ __launch_bounds__(256) void gemm_h16_kernel(const short* __restrict__ Ag,
        const float* __restrict__ Bg, float* __restrict__ C,
        const float* __restrict__ resid, int N, int Kd) {
    __shared__ __align__(16) short As[2*64*40], Bs[2*128*40];
    const int tid = threadIdx.x;
    const int lane = tid & 63, lo = lane & 15, hi = lane >> 4;
    const int wid = tid >> 6, wr = wid >> 1, wc = wid & 1;
    const int m0 = blockIdx.y * 64, n0 = blockIdx.x * 128;
    const int srow = tid >> 2, scol = (tid & 3) * 8;
    f32x4 acc[2][4];
    #pragma unroll
    for (int m = 0; m < 2; ++m)
        #pragma unroll
        for (int n = 0; n < 4; ++n) { acc[m][n][0]=0.f; acc[m][n][1]=0.f; acc[m][n][2]=0.f; acc[m][n][3]=0.f; }
    gemm64_core_wf32(Ag + (size_t)(m0+srow)*Kd + scol,
                     Bg + (size_t)(n0+srow)*Kd + scol, Bg + (size_t)(n0+64+srow)*Kd + scol,
                     Kd, tid, As, Bs, acc);
    #pragma unroll
    for (int m = 0; m < 2; ++m)
        #pragma unroll
        for (int n = 0; n < 4; ++n)
            #pragma unroll
            for (int r = 0; r < 4; ++r) {
                int row = m0 + wr*32 + m*16 + hi*4 + r;
                int col = n0 + wc*64 + n*16 + lo;
                float val = acc[m][n][r];
                if (resid) val += resid[(size_t)row * N + col];
                C[(size_t)row * N + col] = val;
            }
}

// ---------------- fused QKV GEMM (A fp16, W fp32) ----------------
__global__ __launch_bounds__(256) void qkv_h16_kernel(const short* __restrict__ Xh,
        const float* __restrict__ qw, const float* __restrict__ kw,
        const float* __restrict__ vw,
        float* __restrict__ qo, float* __restrict__ ko, float* __restrict__ vo) {
    __shared__ __align__(16) short As[2*64*40], Bs[2*128*40];
    const int bx = blockIdx.x;
    const float* Bp; float* Cp; int Nc, n0;
    if (bx < 8)       { Bp = qw; Cp = qo; Nc = 1024; n0 = bx * 128; }
    else if (bx < 10) { Bp = kw; Cp = ko; Nc = 256;  n0 = (bx - 8) * 128; }
    else              { Bp = vw; Cp = vo; Nc = 256;  n0 = (bx - 10) * 128; }
    const int tid = threadIdx.x;
    const int lane = tid & 63, lo = lane & 15, hi = lane >> 4;
    const int wid = tid >> 6, wr = wid >> 1, wc = wid & 1;
    const int m0 = blockIdx.y * 64;
    const int srow = tid >> 2, scol = (tid & 3) * 8;
    f32x4 acc[2][4];
    #pragma unroll
    for (int m = 0; m < 2; ++m)
        #pragma unroll
        for (int n = 0; n < 4; ++n) { acc[m][n][0]=0.f; acc[m][n][1]=0.f; acc[m][n][2]=0.f; acc[m][n][3]=0.f; }
    gemm64_core_wf32(Xh + (size_t)(m0+srow)*HID + scol,
                     Bp + (size_t)(n0+srow)*HID + scol, Bp + (size_t)(n0+64+srow)*HID + scol,
                     HID, tid, As, Bs, acc);
    #pragma unroll
    for (int m = 0; m < 2; ++m)
        #pragma unroll
        for (int n = 0; n < 4; ++n)
            #pragma unroll
            for (int r = 0; r < 4; ++r) {
                int row = m0 + wr*32 + m*16 + hi*4 + r;
                int col = n0 + wc*64 + n*16 + lo;
                Cp[(size_t)row * Nc + col] = acc[m][n][r];
            }
}

// -------- split-K fp16 flash attention (LDS-staged, uniform 4-tile chunks) --------
__global__ __launch_bounds__(256) void attn_mfma_kernel(const short* __restrict__ q16,
                                                        const short* __restrict__ k16,
                                                        const short* __restrict__ vt16,
                                                        float* __restrict__ pO,
                                                        float* __restrict__ pm,
                                                        float* __restrict__ pl) {
    __shared__ __align__(16) short Ks[64][72];
    __shared__ __align__(16) short Vt[64][72];
    __shared__ __align__(16) short Ps[4][16][72];
    const int wid = threadIdx.x >> 6, lane = threadIdx.x & 63;
    const int lo = lane & 15, hi = lane >> 4;
    const int head = blockIdx.y;
    const int s = (NSLOT - 1) - blockIdx.x;   // long chunks dispatched first
    int g = 0, base = 0;
    while (g < 7 && s >= base + 4 * (g + 1)) { base += 4 * (g + 1); ++g; }
    const int tt = s - base;
    const int qi = 4 * g + tt / (g + 1);
    const int c  = tt % (g + 1);
    const int t_beg = c * 4;
    const int t_end = min(t_beg + 4, qi + 1);
    const int q0 = qi * 64;
    const int kvh = head >> 2;

    f16x8 qf[2];
    {
        const short* qr = q16 + (size_t)(q0 + wid*16 + lo) * HID + head*HD;
        qf[0] = *(const f16x8*)(qr + hi*8);
        qf[1] = *(const f16x8*)(qr + 32 + hi*8);
    }

    f32x4 acc[4];
    float m[4], l[4];
    #pragma unroll
    for (int r = 0; r < 4; ++r) {
        m[r] = -1e30f; l[r] = 0.f;
        acc[0][r] = 0.f; acc[1][r] = 0.f; acc[2][r] = 0.f; acc[3][r] = 0.f;
    }

    const int skey = threadIdx.x >> 2;
    const int sdg  = (threadIdx.x & 3) * 16;

    s16x8 ka0, ka1, va0, va1;
    {
        const short* kr = k16 + (size_t)(t_beg*64 + skey)*(KVH*HD) + kvh*HD + sdg;
        ka0 = *(const s16x8*)kr; ka1 = *(const s16x8*)(kr + 8);
        const short* vr = vt16 + (size_t)(kvh*HD + skey)*S_LEN + t_beg*64 + sdg;
        va0 = *(const s16x8*)vr; va1 = *(const s16x8*)(vr + 8);
    }

    for (int t = t_beg; t < t_end; ++t) {
        __syncthreads();
        *(s16x8*)&Ks[skey][sdg]     = ka0;
        *(s16x8*)&Ks[skey][sdg + 8] = ka1;
        *(s16x8*)&Vt[skey][sdg]     = va0;
        *(s16x8*)&Vt[skey][sdg + 8] = va1;
        __syncthreads();
        if (t + 1 < t_end) {
            const short* kr = k16 + (size_t)((t+1)*64 + skey)*(KVH*HD) + kvh*HD + sdg;
            ka0 = *(const s16x8*)kr; ka1 = *(const s16x8*)(kr + 8);
            const short* vr = vt16 + (size_t)(kvh*HD + skey)*S_LEN + (t+1)*64 + sdg;
            va0 = *(const s16x8*)vr; va1 = *(const s16x8*)(vr + 8);
        }
        const int k0 = t * 64;
        f32x4 sc[4];
        #pragma unroll
        for (int f = 0; f < 4; ++f) {
            f32x4 sf; sf[0]=0.f; sf[1]=0.f; sf[2]=0.f; sf[3]=0.f;
            f16x8 bk0 = *(const f16x8*)&Ks[f*16 + lo][hi*8];
            sf = __builtin_amdgcn_mfma_f32_16x16x32_f16(qf[0], bk0, sf, 0, 0, 0);
            f16x8 bk1 = *(const f16x8*)&Ks[f*16 + lo][32 + hi*8];
            sf = __builtin_amdgcn_mfma_f32_16x16x32_f16(qf[1], bk1, sf, 0, 0, 0);
            sc[f] = sf;
        }
        if (t == qi) {
            int qrow = q0 + wid*16 + hi*4;
            #pragma unroll
            for (int f = 0; f < 4; ++f)
                #pragma unroll
                for (int r = 0; r < 4; ++r)
                    if (k0 + f*16 + lo > qrow + r) sc[f][r] = -1e30f;
        }
        float pmax[4];
        #pragma unroll
        for (int r = 0; r < 4; ++r) {
            float x = fmaxf(fmaxf(sc[0][r], sc[1][r]), fmaxf(sc[2][r], sc[3][r]));
            x = fmaxf(x, __shfl_xor(x, 1));
            x = fmaxf(x, __shfl_xor(x, 2));
            x = fmaxf(x, __shfl_xor(x, 4));
            x = fmaxf(x, __shfl_xor(x, 8));
            pmax[r] = x;
        }
        bool ok = (pmax[0] <= m[0] + 8.f) && (pmax[1] <= m[1] + 8.f) &&
                  (pmax[2] <= m[2] + 8.f) && (pmax[3] <= m[3] + 8.f);
        if (!__all(ok)) {
            #pragma unroll
            for (int r = 0; r < 4; ++r) {
                float mn = fmaxf(m[r], pmax[r]);
                float sc_ = __expf(m[r] - mn);
                m[r] = mn;
                l[r] *= sc_;
                acc[0][r] *= sc_; acc[1][r] *= sc_;
                acc[2][r] *= sc_; acc[3][r] *= sc_;
            }
        }
        float rs[4] = {0.f, 0.f, 0.f, 0.f};
        #pragma unroll
        for (int f = 0; f < 4; ++f)
            #pragma unroll
            for (int r = 0; r < 4; ++r) {
                float e = __expf(sc[f][r] - m[r]);
                rs[r] += e;
                Ps[wid][hi*4 + r][f*16 + lo] = f2h(e);
            }
        #pragma unroll
        for (int r = 0; r < 4; ++r) {
            float x = rs[r];
            x += __shfl_xor(x, 1); x += __shfl_xor(x, 2);
            x += __shfl_xor(x, 4); x += __shfl_xor(x, 8);
            l[r] += x;
        }
        asm volatile("s_waitcnt lgkmcnt(0)" ::: "memory");
        __builtin_amdgcn_sched_barrier(0);
        f16x8 pa0 = *(const f16x8*)&Ps[wid][lo][hi*8];
        f16x8 pa1 = *(const f16x8*)&Ps[wid][lo][32 + hi*8];
        #pragma unroll
        for (int f = 0; f < 4; ++f) {
            f32x4 o = acc[f];
            f16x8 v0 = *(const f16x8*)&Vt[f*16 + lo][hi*8];
            o = __builtin_amdgcn_mfma_f32_16x16x32_f16(pa0, v0, o, 0, 0, 0);
            f16x8 v1 = *(const f16x8*)&Vt[f*16 + lo][32 + hi*8];
            o = __builtin_amdgcn_mfma_f32_16x16x32_f16(pa1, v1, o, 0, 0, 0);
            acc[f] = o;
        }
    }
    const int pbase = head * NSLOT + s;
    float* po = pO + (size_t)pbase * 4096;
    #pragma unroll
    for (int r = 0; r < 4; ++r)
        #pragma unroll
        for (int f = 0; f < 4; ++f)
            po[(wid*16 + hi*4 + r) * 64 + f*16 + lo] = acc[f][r];
    if (lo == 0) {
        #pragma unroll
        for (int r = 0; r < 4; ++r) {
            pm[pbase*64 + wid*16 + hi*4 + r] = m[r];
            pl[pbase*64 + wid*16 + hi*4 + r] = l[r];
        }
    }
}

// ---------------- combine partials (up to 8 chunks) -> fp16 attention output ----------
__global__ __launch_bounds__(256) void attn_combine_kernel(const float* __restrict__ pO,
        const float* __restrict__ pm, const float* __restrict__ pl,
        short* __restrict__ aoh) {
    const int qi = blockIdx.x, head = blockIdx.y;
    const int g = qi >> 2, rr = qi & 3;
    const int nch = g + 1;
    const int sbase = (g + 1) * (2 * g + rr);
    const int row = threadIdx.x >> 2;
    const int d0 = (threadIdx.x & 3) * 16;
    float mv[8], lv[8];
    float mx = -1e30f;
    #pragma unroll
    for (int cd = 0; cd < 8; ++cd) {
        if (cd < nch) {
            int p = head * NSLOT + sbase + cd;
            mv[cd] = pm[p * 64 + row];
            lv[cd] = pl[p * 64 + row];
            mx = fmaxf(mx, mv[cd]);
        } else { mv[cd] = -1e30f; lv[cd] = 0.f; }
    }
    float w[8];
    float lsum = 0.f;
    #pragma unroll
    for (int cd = 0; cd < 8; ++cd) {
        w[cd] = (cd < nch) ? __expf(mv[cd] - mx) : 0.f;
        lsum += w[cd] * lv[cd];
    }
    float inv = 1.0f / lsum;
    float o[16] = {};
    #pragma unroll
    for (int cd = 0; cd < 8; ++cd) {
        if (cd < nch) {
            const float4* po = (const float4*)(pO + ((size_t)(head * NSLOT + sbase + cd)) * 4096 + row * 64 + d0);
            float wc = w[cd] * inv;
            #pragma unroll
            for (int j = 0; j < 4; ++j) {
                float4 vv = po[j];
                o[j*4+0] += wc * vv.x; o[j*4+1] += wc * vv.y;
                o[j*4+2] += wc * vv.z; o[j*4+3] += wc * vv.w;
            }
        }
    }
    size_t outb = (size_t)(qi * 64 + row) * HID + head * HD + d0;
    s16x8 w0, w1;
    #pragma unroll
    for (int i = 0; i < 8; ++i) { w0[i] = f2h(o[i]); w1[i] = f2h(o[8+i]); }
    *(s16x8*)(aoh + outb) = w0;
    *(s16x8*)(aoh + outb + 8) = w1;
}

// ---- MoE mlp1 (A fp16, W fp32, 64x64 tile, dbuf LDS + 3-deep register pipeline) ----
__global__ __launch_bounds__(256) void moe_mlp1_h16(const short* __restrict__ Xh,
        const float* __restrict__ W1, const float* __restrict__ W3,
        const int* __restrict__ cnt, const int* __restrict__ idx,
        short* __restrict__ abh) {
    int e = blockIdx.z;
    int ne = cnt[e];
    int m0 = blockIdx.y * 64;
    if (m0 >= ne) return;
    int f0 = blockIdx.x * 64;
    __shared__ __align__(16) short As[2*64*40];
    __shared__ __align__(16) short Gs[2*64*40], Us[2*64*40];
    __shared__ int rows[64];
    const int tid = threadIdx.x;
    if (tid < 64) {
        int slot = m0 + tid;
        rows[tid] = (slot < ne) ? idx[e * S_LEN + slot] : 0;
    }
    __syncthreads();
    const int lane = tid & 63, lo = lane & 15, hi = lane >> 4;
    const int wid = tid >> 6, wr = wid >> 1, wc = wid & 1;
    const int srow = tid >> 2, scol = (tid & 3) * 8;
    const int soff = srow*40 + scol;
    const short* pX0 = Xh + (size_t)rows[srow] * HID + scol;
    const float* p1 = W1 + ((size_t)e * FF + f0 + srow) * HID + scol;
    const float* p3 = W3 + ((size_t)e * FF + f0 + srow) * HID + scol;

    f32x4 ag[2][2], au[2][2];
    #pragma unroll
    for (int m = 0; m < 2; ++m)
        #pragma unroll
        for (int n = 0; n < 2; ++n) {
            ag[m][n][0]=0.f; ag[m][n][1]=0.f; ag[m][n][2]=0.f; ag[m][n][3]=0.f;
            au[m][n][0]=0.f; au[m][n][1]=0.f; au[m][n][2]=0.f; au[m][n][3]=0.f;
        }

    auto computeGU = [&](int pp) {
        const short* Asp = As + pp * (64*40);
        const short* Gsp = Gs + pp * (64*40);
        const short* Usp = Us + pp * (64*40);
        f16x8 aF[2], gF[2], uF[2];
        #pragma unroll
        for (int m = 0; m < 2; ++m) aF[m] = *(const f16x8*)&Asp[(wr*32 + m*16 + lo)*40 + hi*8];
        #pragma unroll
        for (int n = 0; n < 2; ++n) {
            gF[n] = *(const f16x8*)&Gsp[(wc*32 + n*16 + lo)*40 + hi*8];
            uF[n] = *(const f16x8*)&Usp[(wc*32 + n*16 + lo)*40 + hi*8];
        }
        #pragma unroll
        for (int m = 0; m < 2; ++m)
            #pragma unroll
            for (int n = 0; n < 2; ++n) {
                ag[m][n] = __builtin_amdgcn_mfma_f32_16x16x32_f16(aF[m], gF[n], ag[m][n], 0, 0, 0);
                au[m][n] = __builtin_amdgcn_mfma_f32_16x16x32_f16(aF[m], uF[n], au[m][n], 0, 0, 0);
            }
    };

    s16x8 a0_; float4 g0a_, g0b_, u0a_, u0b_;   // set 0
    s16x8 a1_; float4 g1a_, g1b_, u1a_, u1b_;   // set 1
    s16x8 a2_; float4 g2a_, g2b_, u2a_, u2b_;   // set 2
    {
        s16x8 at = *(const s16x8*)pX0;
        float4 t0 = ((const float4*)p1)[0], t1 = ((const float4*)p1)[1];
        float4 t2 = ((const float4*)p3)[0], t3 = ((const float4*)p3)[1];
        *(s16x8*)&As[soff] = at;
        *(s16x8*)&Gs[soff] = cvt8(t0, t1);
        *(s16x8*)&Us[soff] = cvt8(t2, t3);
    }
    a0_ = *(const s16x8*)(pX0+32);
    g0a_ = ((const float4*)(p1+32))[0]; g0b_ = ((const float4*)(p1+32))[1];
    u0a_ = ((const float4*)(p3+32))[0]; u0b_ = ((const float4*)(p3+32))[1];
    a1_ = *(const s16x8*)(pX0+64);
    g1a_ = ((const float4*)(p1+64))[0]; g1b_ = ((const float4*)(p1+64))[1];
    u1a_ = ((const float4*)(p3+64))[0]; u1b_ = ((const float4*)(p3+64))[1];
    a2_ = *(const s16x8*)(pX0+96);
    g2a_ = ((const float4*)(p1+96))[0]; g2b_ = ((const float4*)(p1+96))[1];
    u2a_ = ((const float4*)(p3+96))[0]; u2b_ = ((const float4*)(p3+96))[1];
    __syncthreads();
    int p = 0;
    for (int k0 = 0; k0 < HID; k0 += 96) {
        // sub-iter 0: compute tile k0
        {
            if (k0 + 32 < HID) {
                short* Asn = As + (p ^ 1) * (64*40);
                short* Gsn = Gs + (p ^ 1) * (64*40);
                short* Usn = Us + (p ^ 1) * (64*40);
                *(s16x8*)&Asn[soff] = a0_;
                *(s16x8*)&Gsn[soff] = cvt8(g0a_, g0b_);
                *(s16x8*)&Usn[soff] = cvt8(u0a_, u0b_);
            }
            if (k0 + 128 < HID) {
                a0_ = *(const s16x8*)(pX0 + k0 + 128);
                g0a_ = ((const float4*)(p1 + k0 + 128))[0]; g0b_ = ((const float4*)(p1 + k0 + 128))[1];
                u0a_ = ((const float4*)(p3 + k0 + 128))[0]; u0b_ = ((const float4*)(p3 + k0 + 128))[1];
            }
            computeGU(p);
            __syncthreads();
            p ^= 1;
        }
        // sub-iter 1: compute tile k0+32
        if (k0 + 32 < HID) {
            if (k0 + 64 < HID) {
                short* Asn = As + (p ^ 1) * (64*40);
                short* Gsn = Gs + (p ^ 1) * (64*40);
                short* Usn = Us + (p ^ 1) * (64*40);
                *(s16x8*)&Asn[soff] = a1_;
                *(s16x8*)&Gsn[soff] = cvt8(g1a_, g1b_);
                *(s16x8*)&Usn[soff] = cvt8(u1a_, u1b_);
            }
            if (k0 + 160 < HID) {
                a1_ = *(const s16x8*)(pX0 + k0 + 160);
                g1a_ = ((const float4*)(p1 + k0 + 160))[0]; g1b_ = ((const float4*)(p1 + k0 + 160))[1];
                u1a_ = ((const float4*)(p3 + k0 + 160))[0]; u1b_ = ((const float4*)(p3 + k0 + 160))[1];
            }
            computeGU(p);
            __syncthreads();
            p ^= 1;
        }
        // sub-iter 2: compute tile k0+64
        if (k0 + 64 < HID) {
            if (k0 + 96 < HID) {
                short* Asn = As + (p ^ 1) * (64*40);
                short* Gsn = Gs + (p ^ 1) * (64*40);
                short* Usn = Us + (p ^ 1) * (64*40);
                *(s16x8*)&Asn[soff] = a2_;
                *(s16x8*)&Gsn[soff] = cvt8(g2a_, g2b_);
                *(s16x8*)&Usn[soff] = cvt8(u2a_, u2b_);
            }
            if (k0 + 192 < HID) {
                a2_ = *(const s16x8*)(pX0 + k0 + 192);
                g2a_ = ((const float4*)(p1 + k0 + 192))[0]; g2b_ = ((const float4*)(p1 + k0 + 192))[1];
                u2a_ = ((const float4*)(p3 + k0 + 192))[0]; u2b_ = ((const float4*)(p3 + k0 + 192))[1];
            }
            computeGU(p);
            __syncthreads();
            p ^= 1;
        }
    }
    #pragma unroll
    for (int m = 0; m < 2; ++m)
        #pragma unroll
        for (int n = 0; n < 2; ++n)
            #pragma unroll
            for (int r = 0; r < 4; ++r) {
                int slot = m0 + wr*32 + m*16 + hi*4 + r;
                if (slot >= ne) continue;
                float g = ag[m][n][r], u = au[m][n][r];
                float a = g * (1.0f / (1.0f + __expf(-g))) * u;
                abh[((size_t)e * S_LEN + slot) * FF + f0 + wc*32 + n*16 + lo] = f2h(a);
            }
}

// ------- MoE mlp2 (A fp16, W fp32, 64-row tile, dbuf+3-deep, split-K over FF) -------
__global__ __launch_bounds__(256) void moe_mlp2_h16(const short* __restrict__ abh,
        const float* __restrict__ W2,
        const int* __restrict__ cnt, const int* __restrict__ idx,
        const float* __restrict__ wt, float* __restrict__ hbuf) {
    int e = blockIdx.z >> 1;
    int ks = blockIdx.z & 1;
    int ne = cnt[e];
    int m0 = blockIdx.y * 64;
    if (m0 >= ne) return;
    int n0 = blockIdx.x * 128;
    const int koff = ks * (FF / 2);
    __shared__ __align__(16) short As[2*64*40], Bs[2*128*40];
    const int tid = threadIdx.x;
    const int lane = tid & 63, lo = lane & 15, hi = lane >> 4;
    const int wid = tid >> 6, wr = wid >> 1, wc = wid & 1;
    const int srow = tid >> 2, scol = (tid & 3) * 8;
    f32x4 acc[2][4];
    #pragma unroll
    for (int m = 0; m < 2; ++m)
        #pragma unroll
        for (int n = 0; n < 4; ++n) { acc[m][n][0]=0.f; acc[m][n][1]=0.f; acc[m][n][2]=0.f; acc[m][n][3]=0.f; }
    gemm64_core_wf32(abh + ((size_t)e*S_LEN + m0 + srow)*FF + koff + scol,
                     W2 + ((size_t)e*HID + n0 + srow)*FF + koff + scol,
                     W2 + ((size_t)e*HID + n0 + 64 + srow)*FF + koff + scol,
                     FF / 2, tid, As, Bs, acc);
    #pragma unroll
    for (int m = 0; m < 2; ++m) {
        #pragma unroll
        for (int r = 0; r < 4; ++r) {
            int slot = m0 + wr*32 + m*16 + hi*4 + r;
            if (slot >= ne) continue;
            int tok = idx[e * S_LEN + slot];
            float wv = wt[e * S_LEN + slot];
            #pragma unroll
            for (int n = 0; n < 4; ++n)
                atomicAdd(&hbuf[(size_t)tok * HID + n0 + wc*64 + n*16 + lo], acc[m][n][r] * wv);
        }
    }
}

extern "C" void kernel_launch(void* const* d_in, const int* in_sizes, int n_in,
                              void* d_out, int out_size, void* d_ws, size_t ws_size,
                              hipStream_t stream) {
    const float* emb = (const float*)d_in[0];
    const float* ln1 = (const float*)d_in[1];
    const float* ln2 = (const float*)d_in[2];
    const float* fln = (const float*)d_in[3];
    const float* qw  = (const float*)d_in[4];
    const float* kw  = (const float*)d_in[5];
    const float* vw  = (const float*)d_in[6];
    const float* ow  = (const float*)d_in[7];
    const float* gw  = (const float*)d_in[8];
    const float* w1  = (const float*)d_in[9];
    const float* w2  = (const float*)d_in[10];
    const float* w3  = (const float*)d_in[11];

    float* ws   = (float*)d_ws;
    float* h    = ws + OFF_H;
    float* q    = ws + OFF_Q;
    float* kb   = ws + OFF_K;
    float* vb   = ws + OFF_V;
    float* cosb = ws + OFF_COS;
    float* sinb = ws + OFF_SIN;
    float* wt   = ws + OFF_WT;
    int*   cnt  = (int*)(ws + OFF_INT);
    int*   idx  = cnt + 8;
    int*   tope = (int*)(ws + OFF_TOPE);
    float2* topw = (float2*)(ws + OFF_TOPW);
    short* xh   = (short*)(ws + OFF_XH);
    short* aoh  = (short*)(ws + OFF_AOH);
    short* abh  = (short*)(ws + OFF_ABH);
    short* q16  = (short*)(ws + OFF_Q16);
    short* k16  = (short*)(ws + OFF_K16);
    short* vt16 = (short*)(ws + OFF_VT16);
    float* pO   = ws + OFF_PO;
    float* pm   = ws + OFF_PM;
    float* pl   = ws + OFF_PL;

    hipMemcpyAsync(h, emb, (size_t)S_LEN * HID * sizeof(float), hipMemcpyDeviceToDevice, stream);
    rope_tables_kernel<<<S_LEN * 32 / 256, 256, 0, stream>>>(cosb, sinb);

    for (int l = 0; l < NL; ++l) {
        rmsnorm_h16_kernel<<<S_LEN, 256, 0, stream>>>(h, ln1 + l * HID, xh);
        qkv_h16_kernel<<<dim3(12, 32), 256, 0, stream>>>(xh,
            qw + (size_t)l*HID*HID, kw + (size_t)l*KVH*HD*HID, vw + (size_t)l*KVH*HD*HID,
            q, kb, vb);
        rope_cvt_kernel<<<(S_LEN * NHEAD * 32) / 256, 256, 0, stream>>>(q, cosb, sinb, q16, NHEAD, S_LEN * NHEAD * 32, 0.125f);
        rope_cvt_kernel<<<(S_LEN * KVH * 32) / 256, 256, 0, stream>>>(kb, cosb, sinb, k16, KVH, S_LEN * KVH * 32, 1.0f);
        vtrans_kernel<<<dim3(S_LEN/64, KVH*HD/64), 256, 0, stream>>>(vb, vt16);
        attn_mfma_kernel<<<dim3(NSLOT, NHEAD), 256, 0, stream>>>(q16, k16, vt16, pO, pm, pl);
        attn_combine_kernel<<<dim3(32, NHEAD), 256, 0, stream>>>(pO, pm, pl, aoh);
        gemm_h16_kernel<<<dim3(8, 32), 256, 0, stream>>>(aoh, ow + (size_t)l*HID*HID, h, h, HID, HID);

        rmsnorm_gate_kernel<<<S_LEN, 256, 0, stream>>>(h, ln2 + l * HID, gw + (size_t)l * NE * HID,
                                                       xh, tope, topw);
        route_build_kernel<<<NE, 1024, 0, stream>>>(tope, topw, cnt, idx, wt);

        moe_mlp1_h16<<<dim3(16, 32, 8), 256, 0, stream>>>(xh,
            w1 + (size_t)l*NE*FF*HID, w3 + (size_t)l*NE*FF*HID, cnt, idx, abh);
        moe_mlp2_h16<<<dim3(8, 32, 16), 256, 0, stream>>>(abh,
            w2 + (size_t)l*NE*HID*FF, cnt, idx, wt, h);
    }
    rmsnorm_kernel<<<S_LEN, 256, 0, stream>>>(h, fln, (float*)d_out);
}